// Round 2
// baseline (20747.662 us; speedup 1.0000x reference)
//
#include <hip/hip_runtime.h>
#include <hip/hip_fp16.h>
#include <math.h>

#define B_    128
#define S_    256
#define WORD_ 300
#define HD_   384
#define M_    32768
#define STRU_ 256
#define SEMA_ 512

typedef __half half_t;

template<typename T> __device__ inline float4 ld4f(const T* p);
template<> __device__ inline float4 ld4f<float>(const float* p){ return *(const float4*)p; }
template<> __device__ inline float4 ld4f<__half>(const __half* p){
    __half2 a = *(const __half2*)p; __half2 b = *(const __half2*)(p+2);
    float2 fa = __half22float2(a), fb = __half22float2(b);
    return make_float4(fa.x, fa.y, fb.x, fb.y);
}

// ---------------- generic tiled GEMM, templated element types ----------------
// C = act( A(.T) @ B(.T) + bias + beta*C + d0[m]*root[n] ) [* mask[m]]
#define BM 64
#define BN 64
#define BK 16

template<bool TA, bool TB, typename AT, typename BT>
__global__ __launch_bounds__(256)
void gemm_k(const AT* __restrict__ Ag, const BT* __restrict__ Bg, void* __restrict__ Cg,
            int M, int N, int K, int lda, int ldb, int ldc,
            long sA, long sB, long sC,
            const float* __restrict__ bias, int beta, int act,
            const float* __restrict__ d0v, const float* __restrict__ rootv,
            const float* __restrict__ maskp, int cmode /*0=f32,1=f16*/)
{
    __shared__ float As[BK][BM + 4];
    __shared__ float Bs[BK][BN + 4];
    const int bz = blockIdx.z;
    const AT* A  = Ag + (long)bz * sA;
    const BT* Bp = Bg + (long)bz * sB;
    const int m0 = blockIdx.y * BM, n0 = blockIdx.x * BN;
    const int tid = threadIdx.x;
    const int tx = tid & 15, ty = tid >> 4;
    float acc[4][4] = {};

    for (int k0 = 0; k0 < K; k0 += BK) {
        if (!TA) {
            int lm = tid >> 2, lk = (tid & 3) << 2;
            float4 v = ld4f(A + (long)(m0 + lm) * lda + (k0 + lk));
            As[lk + 0][lm] = v.x; As[lk + 1][lm] = v.y;
            As[lk + 2][lm] = v.z; As[lk + 3][lm] = v.w;
        } else {
            int lk = tid >> 4, lm = (tid & 15) << 2;
            float4 v = ld4f(A + (long)(k0 + lk) * lda + (m0 + lm));
            *(float4*)&As[lk][lm] = v;
        }
        if (TB) {
            int ln = tid >> 2, lk = (tid & 3) << 2;
            float4 v = ld4f(Bp + (long)(n0 + ln) * ldb + (k0 + lk));
            Bs[lk + 0][ln] = v.x; Bs[lk + 1][ln] = v.y;
            Bs[lk + 2][ln] = v.z; Bs[lk + 3][ln] = v.w;
        } else {
            int lk = tid >> 4, ln = (tid & 15) << 2;
            float4 v = ld4f(Bp + (long)(k0 + lk) * ldb + (n0 + ln));
            *(float4*)&Bs[lk][ln] = v;
        }
        __syncthreads();
        #pragma unroll
        for (int kk = 0; kk < BK; kk++) {
            float4 a4 = *(const float4*)&As[kk][ty << 2];
            float4 b4 = *(const float4*)&Bs[kk][tx << 2];
            float av[4] = {a4.x, a4.y, a4.z, a4.w};
            float bv[4] = {b4.x, b4.y, b4.z, b4.w};
            #pragma unroll
            for (int i = 0; i < 4; i++)
                #pragma unroll
                for (int j = 0; j < 4; j++)
                    acc[i][j] += av[i] * bv[j];
        }
        __syncthreads();
    }

    #pragma unroll
    for (int i = 0; i < 4; i++) {
        int m = m0 + (ty << 2) + i;
        #pragma unroll
        for (int j = 0; j < 4; j++) {
            int n = n0 + (tx << 2) + j;
            float v = acc[i][j];
            long cidx = (long)bz * sC + (long)m * ldc + n;
            if (bias) v += bias[n];
            if (beta) v += ((const float*)Cg)[cidx];
            if (d0v)  v += d0v[(long)bz * M + m] * rootv[n];
            if (act == 1)      v = tanhf(v);
            else if (act == 2) v = (m == n) ? 0.f : expf(v);
            if (maskp) v *= maskp[m];
            if (cmode == 1) ((half_t*)Cg)[cidx] = __float2half(v);
            else            ((float*)Cg)[cidx]  = v;
        }
    }
}

// ---------------- LSTM step: 384 WGs = dir(2) x slice(48, 8 hdim) x btile(4, 32 rows) ----------------
// wave = gate quadrant; lane: b = l&31, gh = l>>5 -> 4 gate rows each.
__global__ __launch_bounds__(256)
void lstm_step(const float* __restrict__ x,
               const float* __restrict__ whh_f, const float* __restrict__ whh_b,
               const float* __restrict__ wih_f, const float* __restrict__ wih_b,
               const float* __restrict__ bia_f, const float* __restrict__ bia_b,
               half_t* __restrict__ Hbuf, float* __restrict__ Cbuf,
               half_t* __restrict__ vs, half_t* __restrict__ vst, int t)
{
    __shared__ __half hl[32 * 388];
    __shared__ float  gl[32 * 33];

    const int bid = blockIdx.x;
    const int d = bid / 192, rem = bid % 192;
    const int slice = rem >> 2, btile = rem & 3;
    const int tid = threadIdx.x;
    const int tsrc = d ? (S_ - 1 - t) : t;
    const int parity = t & 1;
    const float* whh = d ? whh_b : whh_f;
    const float* wih = d ? wih_b : wih_f;
    const float* bia = d ? bia_b : bia_f;

    // stage h tile (fp16) for this btile
    const half_t* hsrc = Hbuf + (long)((d * 2 + parity) * B_) * HD_;
    for (int e = tid; e < 32 * 96; e += 256) {
        int b = e / 96, c4 = (e % 96) << 2;
        short4 v;
        if (t == 0) v = make_short4(0, 0, 0, 0);
        else        v = *(const short4*)(hsrc + (long)(btile * 32 + b) * HD_ + c4);
        *(short4*)&hl[b * 388 + c4] = v;
    }
    __syncthreads();

    const int wv = tid >> 6, lane = tid & 63;
    const int b = lane & 31, gh = lane >> 5;
    const int bg = btile * 32 + b;
    const int grow0 = wv * HD_ + slice * 8 + gh * 4;   // gate row base within dir
    float acc[4];
    #pragma unroll
    for (int jj = 0; jj < 4; jj++) acc[jj] = bia[grow0 + jj];

    // recurrent part: h (LDS fp16) x W_hh (global f32, wave-uniform rows)
    const __half2* hrow = (const __half2*)&hl[b * 388];
    const float* wr0 = whh + (long)grow0 * HD_;
    #pragma unroll 2
    for (int k = 0; k < HD_; k += 8) {
        float2 f0 = __half22float2(hrow[(k >> 1) + 0]);
        float2 f1 = __half22float2(hrow[(k >> 1) + 1]);
        float2 f2 = __half22float2(hrow[(k >> 1) + 2]);
        float2 f3 = __half22float2(hrow[(k >> 1) + 3]);
        #pragma unroll
        for (int jj = 0; jj < 4; jj++) {
            const float* wp = wr0 + jj * HD_ + k;
            float4 wa = *(const float4*)wp;
            float4 wb = *(const float4*)(wp + 4);
            acc[jj] += f0.x * wa.x + f0.y * wa.y + f1.x * wa.z + f1.y * wa.w
                     + f2.x * wb.x + f2.y * wb.y + f3.x * wb.z + f3.y * wb.w;
        }
    }
    // input part: x (global f32) x W_ih (global f32)
    const float* xrow = x + ((long)bg * S_ + tsrc) * WORD_;
    const float* wx0 = wih + (long)grow0 * WORD_;
    #pragma unroll 2
    for (int k = 0; k < WORD_; k += 4) {
        float4 xv = *(const float4*)(xrow + k);
        #pragma unroll
        for (int jj = 0; jj < 4; jj++) {
            float4 w4 = *(const float4*)(wx0 + jj * WORD_ + k);
            acc[jj] += xv.x * w4.x + xv.y * w4.y + xv.z * w4.z + xv.w * w4.w;
        }
    }
    #pragma unroll
    for (int jj = 0; jj < 4; jj++)
        gl[b * 33 + wv * 8 + gh * 4 + jj] = acc[jj];
    __syncthreads();

    // pointwise cell: 256 items = 32 b x 8 hdim
    {
        int bb = tid >> 3, j = tid & 7;
        float gi = gl[bb * 33 + 0  + j];
        float gf = gl[bb * 33 + 8  + j];
        float gg = gl[bb * 33 + 16 + j];
        float go = gl[bb * 33 + 24 + j];
        int bg2 = btile * 32 + bb;
        int hd  = slice * 8 + j;
        long cidx = (long)(d * B_ + bg2) * HD_ + hd;
        float c = (t == 0) ? 0.f : Cbuf[cidx];
        float si = 1.f / (1.f + expf(-gi));
        float sf = 1.f / (1.f + expf(-gf));
        float so = 1.f / (1.f + expf(-go));
        c = sf * c + si * tanhf(gg);
        float h = so * tanhf(c);
        Cbuf[cidx] = c;
        Hbuf[(long)((d * 2 + (parity ^ 1)) * B_ + bg2) * HD_ + hd] = __float2half(h);
        long m = (long)bg2 * S_ + tsrc;
        if (hd < 256) vs [m * SEMA_ + d * 256 + hd]         = __float2half(h);
        else          vst[m * STRU_ + d * 128 + (hd - 256)] = __float2half(h);
    }
}

// ---------------- f_r = exp(vst @ w_root^T) ----------------
__global__ __launch_bounds__(256)
void frow_kernel(const half_t* __restrict__ vst, const float* __restrict__ wroot,
                 float* __restrict__ fr)
{
    int row  = blockIdx.x * 4 + (threadIdx.x >> 6);
    int lane = threadIdx.x & 63;
    const half_t* v = vst + (long)row * 256;
    float s = 0.f;
    for (int k = lane; k < 256; k += 64) s += __half2float(v[k]) * wroot[k];
    #pragma unroll
    for (int off = 32; off; off >>= 1) s += __shfl_down(s, off);
    if (lane == 0) fr[row] = expf(s);
}

// ---------------- register-resident Gauss-Jordan inverse (256x256) ----------------
__global__ __launch_bounds__(512)
void invert_gj(const half_t* __restrict__ fA, const float* __restrict__ fr,
               half_t* __restrict__ LLinv)
{
    __shared__ float colbuf[256];
    __shared__ float rowbuf[256];
    __shared__ float csum[2][256];
    const int bz = blockIdx.x;
    const half_t* A = fA + (long)bz * 65536;
    const int tid = threadIdx.x;
    const int c = tid & 255, rh = tid >> 8;
    float m[128];

    float s = 0.f;
    #pragma unroll
    for (int i = 0; i < 128; i++) {
        float v = __half2float(A[(long)(rh * 128 + i) * 256 + c]);
        m[i] = v; s += v;
    }
    csum[rh][c] = s;
    __syncthreads();
    float diag = csum[0][c] + csum[1][c];
    const float frv = fr[bz * 256 + c];
    #pragma unroll
    for (int i = 0; i < 128; i++) {
        int r = rh * 128 + i;
        float v = (r == c) ? ((diag == 0.f) ? 1.f : diag) : -m[i];
        if (i == 0 && rh == 0) {
            v = frv;
            if (c == 0 && v == 0.f) v = 1.f;
        }
        m[i] = v;
    }
    __syncthreads();

    for (int k = 0; k < 256; k++) {
        const int kh = k >> 7, kl = k & 127;
        if (c == k) {
            #pragma unroll
            for (int i = 0; i < 128; i++) colbuf[rh * 128 + i] = m[i];
        }
        if (rh == kh) {
            float pv = 0.f;
            #pragma unroll
            for (int i = 0; i < 128; i++) pv = (i == kl) ? m[i] : pv;
            rowbuf[c] = pv;
        }
        __syncthreads();
        const float p    = colbuf[k];
        const float pinv = 1.f / p;
        const float rv   = rowbuf[c] * pinv;
        if (c == k) {
            #pragma unroll
            for (int i = 0; i < 128; i++) {
                int r = rh * 128 + i;
                m[i] = (r == k) ? pinv : -colbuf[r] * pinv;
            }
        } else {
            #pragma unroll
            for (int i = 0; i < 128; i++) {
                int r = rh * 128 + i;
                float nv = m[i] - colbuf[r] * rv;
                m[i] = (r == k) ? rv : nv;
            }
        }
        __syncthreads();
    }

    #pragma unroll
    for (int i = 0; i < 128; i++)
        LLinv[(long)bz * 65536 + (long)(rh * 128 + i) * 256 + c] = __float2half(m[i]);
}

// ---------------- diag(LLinv) and d0 ----------------
__global__ void diag_d0_k(const half_t* __restrict__ LLinv, const float* __restrict__ fr,
                          float* __restrict__ diagv, float* __restrict__ d0)
{
    int i = blockIdx.x * 256 + threadIdx.x;
    if (i >= 32768) return;
    int b = i >> 8, s = i & 255;
    diagv[i] = __half2float(LLinv[(long)b * 65536 + s * 257]);
    d0[i]    = fr[i] * __half2float(LLinv[(long)b * 65536 + s * 256]);
}

// ---------------- a = A*(diag - LLinv^T), in place over fA ----------------
__global__ __launch_bounds__(256)
void assemble_a(half_t* __restrict__ fA, const half_t* __restrict__ LLinv,
                const float* __restrict__ diagv)
{
    __shared__ float ll[32][33];
    const int bz = blockIdx.z;
    const int s0 = (blockIdx.x >> 3) * 32, t0 = (blockIdx.x & 7) * 32;
    const int tid = threadIdx.x;
    const long base = (long)bz * 65536;
    #pragma unroll
    for (int it = 0; it < 4; it++) {
        int i = (tid >> 5) + it * 8, j = tid & 31;
        ll[i][j] = __half2float(LLinv[base + (long)(t0 + i) * 256 + (s0 + j)]);
    }
    __syncthreads();
    #pragma unroll
    for (int it = 0; it < 4; it++) {
        int si = (tid >> 5) + it * 8, tj = tid & 31;
        int s = s0 + si, t = t0 + tj;
        long idx = base + (long)s * 256 + t;
        float Av = __half2float(fA[idx]);
        float t1 = (t > 0) ? diagv[(bz << 8) + t] : 0.f;
        float t2 = (s > 0) ? ll[tj][si] : 0.f;
        fA[idx] = __float2half(Av * (t1 - t2));
    }
}

// ---------------- emb = max over sequence ----------------
__global__ __launch_bounds__(256)
void emb_max(const float* __restrict__ outp, float* __restrict__ emb)
{
    int i = blockIdx.x * 256 + threadIdx.x;
    int b = i >> 9, n = i & 511;
    const float* p = outp + (long)b * S_ * SEMA_ + n;
    float mx = -3.4e38f;
    for (int t = 0; t < S_; t++) mx = fmaxf(mx, p[(long)t * SEMA_]);
    emb[i] = mx;
}

// ---------------- diagnostic: encode ws_size if workspace too small ----------------
__global__ void diag_ws(float* out, int n, float v)
{
    int i = blockIdx.x * 256 + threadIdx.x;
    if (i < n) out[i] = v;
}

// ======================= host launch =======================
extern "C" void kernel_launch(void* const* d_in, const int* in_sizes, int n_in,
                              void* d_out, int out_size, void* d_ws, size_t ws_size,
                              hipStream_t stream)
{
    const float* x     = (const float*)d_in[0];
    const float* mask  = (const float*)d_in[1];
    const float* wihf  = (const float*)d_in[2];
    const float* whhf  = (const float*)d_in[3];
    const float* bf    = (const float*)d_in[4];
    const float* wihb  = (const float*)d_in[5];
    const float* whhb  = (const float*)d_in[6];
    const float* bb    = (const float*)d_in[7];
    const float* wtp   = (const float*)d_in[8];
    const float* btp   = (const float*)d_in[9];
    const float* wtc   = (const float*)d_in[10];
    const float* btc   = (const float*)d_in[11];
    const float* wa    = (const float*)d_in[12];
    const float* wroot = (const float*)d_in[13];
    const float* remb  = (const float*)d_in[14];
    const float* wr    = (const float*)d_in[15];
    const float* br    = (const float*)d_in[16];

    if (ws_size < 134217728ULL) {   // need exactly 128 MiB; encode size for diagnosis
        float enc = 100.0f + (float)((double)ws_size * 1e-9);
        diag_ws<<<dim3((out_size + 255) / 256), 256, 0, stream>>>((float*)d_out, out_size, enc);
        return;
    }

    char* ws = (char*)d_ws;
    half_t* vs   = (half_t*)(ws + 0);            // 32768 x 512
    half_t* vst  = (half_t*)(ws + 33554432);     // 32768 x 256
    half_t* tp   = (half_t*)(ws + 50331648);     // 32768 x 256
    half_t* pbuf = (half_t*)(ws + 33554432);     // over vst+tp after they die
    half_t* tc   = (half_t*)(ws + 67108864);     // 32768 x 256
    half_t* tmp  = (half_t*)(ws + 83886080);     // 32768 x 256
    half_t* cbuf = (half_t*)(ws + 67108864);     // over tc+tmp after they die
    half_t* fA   = (half_t*)(ws + 100663296);    // 128 x 256 x 256 (aM in place)
    half_t* LL   = (half_t*)(ws + 117440512);    // 128 x 256 x 256

    // small state lives in the tail of d_out's `output` region (dead until finals)
    float* tail  = (float*)d_out + 16547840;
    float*  fr    = tail;                // 32768
    float*  d0    = tail + 32768;        // 32768
    float*  diagv = tail + 65536;        // 32768
    float*  Cbuf  = tail + 98304;        // 2*128*384 f32
    half_t* Hbuf  = (half_t*)(tail + 196608);   // 2*2*128*384 fp16

    float* emb  = (float*)d_out;
    float* outp = (float*)d_out + 65536;

    // 1. BiLSTM recurrence (x-projection folded in), 256 steps
    for (int t = 0; t < S_; t++)
        lstm_step<<<dim3(384), 256, 0, stream>>>(
            x, whhf, whhb, wihf, wihb, bf, bb, Hbuf, Cbuf, vs, vst, t);

    // 2. f_r
    frow_kernel<<<dim3(8192), 256, 0, stream>>>(vst, wroot, fr);

    // 3. tp / tc = tanh(vst @ W^T + b)
    gemm_k<false, true, half_t, float><<<dim3(4, 512, 1), 256, 0, stream>>>(
        vst, wtp, tp, M_, STRU_, STRU_, STRU_, STRU_, STRU_, 0, 0, 0,
        btp, 0, 1, nullptr, nullptr, nullptr, 1);
    gemm_k<false, true, half_t, float><<<dim3(4, 512, 1), 256, 0, stream>>>(
        vst, wtc, tc, M_, STRU_, STRU_, STRU_, STRU_, STRU_, 0, 0, 0,
        btc, 0, 1, nullptr, nullptr, nullptr, 1);

    // 4. tmp = tp @ w_a
    gemm_k<false, false, half_t, float><<<dim3(4, 512, 1), 256, 0, stream>>>(
        tp, wa, tmp, M_, STRU_, STRU_, STRU_, STRU_, STRU_, 0, 0, 0,
        nullptr, 0, 0, nullptr, nullptr, nullptr, 1);

    // 5. f = exp(tmp @ tc^T), diag zeroed (batched over B)
    gemm_k<false, true, half_t, half_t><<<dim3(4, 4, 128), 256, 0, stream>>>(
        tmp, tc, fA, S_, S_, STRU_, STRU_, STRU_, S_, 65536, 65536, 65536,
        nullptr, 0, 2, nullptr, nullptr, nullptr, 1);

    // 6. batched matrix-tree Laplacian inverse
    invert_gj<<<dim3(128), 512, 0, stream>>>(fA, fr, LL);

    // 7. diag/d0
    diag_d0_k<<<dim3(128), 256, 0, stream>>>(LL, fr, diagv, d0);

    // 8. a = A*(diag - LLinv^T), in place
    assemble_a<<<dim3(64, 1, 128), 256, 0, stream>>>(fA, LL, diagv);

    // 9. c = a @ vs
    gemm_k<false, false, half_t, half_t><<<dim3(8, 4, 128), 256, 0, stream>>>(
        fA, vs, cbuf, S_, SEMA_, S_, S_, SEMA_, SEMA_, 65536, 131072, 131072,
        nullptr, 0, 0, nullptr, nullptr, nullptr, 1);

    // 10. p = a^T @ vs + d0 (x) root_emb
    gemm_k<true, false, half_t, half_t><<<dim3(8, 4, 128), 256, 0, stream>>>(
        fA, vs, pbuf, S_, SEMA_, S_, S_, SEMA_, SEMA_, 65536, 131072, 131072,
        nullptr, 0, 0, d0, remb, nullptr, 1);

    // 11-13. output = tanh(vs@W1^T + p@W2^T + c@W3^T + b_r) * mask
    gemm_k<false, true, half_t, float><<<dim3(8, 512, 1), 256, 0, stream>>>(
        vs, wr, outp, M_, SEMA_, SEMA_, SEMA_, 1536, SEMA_, 0, 0, 0,
        br, 0, 0, nullptr, nullptr, nullptr, 0);
    gemm_k<false, true, half_t, float><<<dim3(8, 512, 1), 256, 0, stream>>>(
        pbuf, wr + 512, outp, M_, SEMA_, SEMA_, SEMA_, 1536, SEMA_, 0, 0, 0,
        nullptr, 1, 0, nullptr, nullptr, nullptr, 0);
    gemm_k<false, true, half_t, float><<<dim3(8, 512, 1), 256, 0, stream>>>(
        cbuf, wr + 1024, outp, M_, SEMA_, SEMA_, SEMA_, 1536, SEMA_, 0, 0, 0,
        nullptr, 1, 1, nullptr, nullptr, mask, 0);

    // 14. emb = max over sequence
    emb_max<<<dim3(256), 256, 0, stream>>>(outp, emb);
}

// Round 3
// 19851.810 us; speedup vs baseline: 1.0451x; 1.0451x over previous
//
#include <hip/hip_runtime.h>
#include <hip/hip_fp16.h>
#include <math.h>

#define B_    128
#define S_    256
#define WORD_ 300
#define HD_   384
#define M_    32768
#define STRU_ 256
#define SEMA_ 512

typedef __half half_t;
typedef _Float16 f16x8 __attribute__((ext_vector_type(8)));
typedef float    f32x4 __attribute__((ext_vector_type(4)));

// ================= MFMA GEMM: C(f16) = act(A @ B(.T) + bias + d0*root) =================
// A: f16 [m][k] (lda). B: !BNN -> f16 [n][k] (NT, ldb); BNN -> f16 [k][n] (NN, ldb).
// Tile 128x64x32, 4 waves (2m x 2n), per wave 4x2 frags of 16x16x32 MFMA.
template<bool BNN>
__global__ __launch_bounds__(256)
void mgemm(const half_t* __restrict__ Ag, const half_t* __restrict__ Bg,
           half_t* __restrict__ Cg,
           int M, int N, int K, int lda, int ldb, int ldc,
           long sA, long sB, long sC,
           const float* __restrict__ bias, int act,
           const float* __restrict__ d0v, const float* __restrict__ rootv)
{
    __shared__ __half As[128][40];
    __shared__ __half Bs[64][40];
    const int bz = blockIdx.z;
    const half_t* A  = Ag + (long)bz * sA;
    const half_t* Bp = Bg + (long)bz * sB;
    const int m0 = blockIdx.y * 128, n0 = blockIdx.x * 64;
    const int tid = threadIdx.x;
    const int l = tid & 63, w = tid >> 6;
    const int wm = w & 1, wn = w >> 1;
    const int lr = l & 15, lq = l >> 4;       // frag row/col, k-quad

    f32x4 acc[4][2] = {};

    for (int k0 = 0; k0 < K; k0 += 32) {
        // stage A: 512 16B-chunks, 2 per thread
        #pragma unroll
        for (int i = 0; i < 2; i++) {
            int ch = tid + i * 256;
            int r = ch >> 2, j = ch & 3;
            *(float4*)&As[r][j * 8] = *(const float4*)(A + (long)(m0 + r) * lda + k0 + j * 8);
        }
        if (!BNN) {
            int r = tid >> 2, j = tid & 3;
            *(float4*)&Bs[r][j * 8] = *(const float4*)(Bp + (long)(n0 + r) * ldb + k0 + j * 8);
        } else {
            int k = tid & 31, nc = tid >> 5;
            float4 v = *(const float4*)(Bp + (long)(k0 + k) * ldb + n0 + nc * 8);
            const __half* hv = (const __half*)&v;
            #pragma unroll
            for (int jj = 0; jj < 8; jj++) Bs[nc * 8 + jj][k] = hv[jj];
        }
        __syncthreads();

        f16x8 af[4], bf[2];
        #pragma unroll
        for (int mf = 0; mf < 4; mf++)
            af[mf] = *(const f16x8*)&As[wm * 64 + mf * 16 + lr][lq * 8];
        #pragma unroll
        for (int nf = 0; nf < 2; nf++)
            bf[nf] = *(const f16x8*)&Bs[wn * 32 + nf * 16 + lr][lq * 8];
        #pragma unroll
        for (int mf = 0; mf < 4; mf++)
            #pragma unroll
            for (int nf = 0; nf < 2; nf++)
                acc[mf][nf] = __builtin_amdgcn_mfma_f32_16x16x32_f16(af[mf], bf[nf], acc[mf][nf], 0, 0, 0);
        __syncthreads();
    }

    #pragma unroll
    for (int mf = 0; mf < 4; mf++) {
        #pragma unroll
        for (int nf = 0; nf < 2; nf++) {
            #pragma unroll
            for (int j = 0; j < 4; j++) {
                int m = m0 + wm * 64 + mf * 16 + lq * 4 + j;
                int n = n0 + wn * 32 + nf * 16 + lr;
                float v = acc[mf][nf][j];
                if (bias) v += bias[n];
                if (d0v)  v += d0v[(long)bz * M + m] * rootv[n];
                if (act == 1)      v = tanhf(v);
                else if (act == 2) v = (m == n) ? 0.f : expf(v);
                Cg[(long)bz * sC + (long)m * ldc + n] = __float2half(v);
            }
        }
    }
}

// ============ final: out = tanh(vs@W1^T + p@W2^T + c@W3^T + br) * mask, f32 ============
// K=1536 in three 512-sections with A = A0/A1/A2. B = wr16 [512][1536] NT.
__global__ __launch_bounds__(256)
void mgemm_final(const half_t* __restrict__ A0, const half_t* __restrict__ A1,
                 const half_t* __restrict__ A2, const half_t* __restrict__ Bw,
                 float* __restrict__ Cout, const float* __restrict__ bias,
                 const float* __restrict__ maskp)
{
    __shared__ __half As[128][40];
    __shared__ __half Bs[64][40];
    const int m0 = blockIdx.y * 128, n0 = blockIdx.x * 64;
    const int tid = threadIdx.x;
    const int l = tid & 63, w = tid >> 6;
    const int wm = w & 1, wn = w >> 1;
    const int lr = l & 15, lq = l >> 4;

    f32x4 acc[4][2] = {};

    for (int k0 = 0; k0 < 1536; k0 += 32) {
        const half_t* A = (k0 < 512) ? A0 : (k0 < 1024) ? A1 : A2;
        const int kk = k0 & 511;
        #pragma unroll
        for (int i = 0; i < 2; i++) {
            int ch = tid + i * 256;
            int r = ch >> 2, j = ch & 3;
            *(float4*)&As[r][j * 8] = *(const float4*)(A + (long)(m0 + r) * 512 + kk + j * 8);
        }
        {
            int r = tid >> 2, j = tid & 3;
            *(float4*)&Bs[r][j * 8] = *(const float4*)(Bw + (long)(n0 + r) * 1536 + k0 + j * 8);
        }
        __syncthreads();
        f16x8 af[4], bf[2];
        #pragma unroll
        for (int mf = 0; mf < 4; mf++)
            af[mf] = *(const f16x8*)&As[wm * 64 + mf * 16 + lr][lq * 8];
        #pragma unroll
        for (int nf = 0; nf < 2; nf++)
            bf[nf] = *(const f16x8*)&Bs[wn * 32 + nf * 16 + lr][lq * 8];
        #pragma unroll
        for (int mf = 0; mf < 4; mf++)
            #pragma unroll
            for (int nf = 0; nf < 2; nf++)
                acc[mf][nf] = __builtin_amdgcn_mfma_f32_16x16x32_f16(af[mf], bf[nf], acc[mf][nf], 0, 0, 0);
        __syncthreads();
    }

    #pragma unroll
    for (int mf = 0; mf < 4; mf++) {
        #pragma unroll
        for (int nf = 0; nf < 2; nf++) {
            #pragma unroll
            for (int j = 0; j < 4; j++) {
                int m = m0 + wm * 64 + mf * 16 + lq * 4 + j;
                int n = n0 + wn * 32 + nf * 16 + lr;
                float v = tanhf(acc[mf][nf][j] + bias[n]) * maskp[m];
                Cout[(long)m * 512 + n] = v;
            }
        }
    }
}

// ---------------- converts ----------------
__global__ void conv16(const float* __restrict__ s, half_t* __restrict__ d, long n)
{
    long i = (long)blockIdx.x * 256 + threadIdx.x;
    if (i < n) d[i] = __float2half(s[i]);
}
__global__ void convT16(const float* __restrict__ s, half_t* __restrict__ d, int R, int C)
{
    int i = blockIdx.x * 256 + threadIdx.x;
    if (i >= R * C) return;
    int r = i / C, c = i % C;
    d[(long)c * R + r] = __float2half(s[i]);
}

// ---------------- batched 256x256 f16 transpose (for aT) ----------------
__global__ __launch_bounds__(256)
void transpose256h(const half_t* __restrict__ in, half_t* __restrict__ out)
{
    __shared__ __half tb[32][33];
    const int bz = blockIdx.z;
    const half_t* ip = in  + (long)bz * 65536;
    half_t*       op = out + (long)bz * 65536;
    int x0 = blockIdx.x * 32, y0 = blockIdx.y * 32;
    int tx = threadIdx.x, ty = threadIdx.y;
    #pragma unroll
    for (int r = 0; r < 4; r++)
        tb[ty + 8 * r][tx] = ip[(long)(y0 + ty + 8 * r) * 256 + x0 + tx];
    __syncthreads();
    #pragma unroll
    for (int r = 0; r < 4; r++)
        op[(long)(x0 + ty + 8 * r) * 256 + y0 + tx] = tb[tx][ty + 8 * r];
}

// ---------------- LSTM step: 384 WGs = dir(2) x slice(48, 8 hdim) x btile(4, 32 rows) ----------------
__global__ __launch_bounds__(256)
void lstm_step(const float* __restrict__ x,
               const float* __restrict__ whh_f, const float* __restrict__ whh_b,
               const float* __restrict__ wih_f, const float* __restrict__ wih_b,
               const float* __restrict__ bia_f, const float* __restrict__ bia_b,
               half_t* __restrict__ Hbuf, float* __restrict__ Cbuf,
               half_t* __restrict__ vs, half_t* __restrict__ vst, int t)
{
    __shared__ __half hl[32 * 388];
    __shared__ float  gl[32 * 33];

    const int bid = blockIdx.x;
    const int d = bid / 192, rem = bid % 192;
    const int slice = rem >> 2, btile = rem & 3;
    const int tid = threadIdx.x;
    const int tsrc = d ? (S_ - 1 - t) : t;
    const int parity = t & 1;
    const float* whh = d ? whh_b : whh_f;
    const float* wih = d ? wih_b : wih_f;
    const float* bia = d ? bia_b : bia_f;

    const half_t* hsrc = Hbuf + (long)((d * 2 + parity) * B_) * HD_;
    for (int e = tid; e < 32 * 96; e += 256) {
        int b = e / 96, c4 = (e % 96) << 2;
        short4 v;
        if (t == 0) v = make_short4(0, 0, 0, 0);
        else        v = *(const short4*)(hsrc + (long)(btile * 32 + b) * HD_ + c4);
        *(short4*)&hl[b * 388 + c4] = v;
    }
    __syncthreads();

    const int wv = tid >> 6, lane = tid & 63;
    const int b = lane & 31, gh = lane >> 5;
    const int bg = btile * 32 + b;
    const int grow0 = wv * HD_ + slice * 8 + gh * 4;
    float acc[4];
    #pragma unroll
    for (int jj = 0; jj < 4; jj++) acc[jj] = bia[grow0 + jj];

    const __half2* hrow = (const __half2*)&hl[b * 388];
    const float* wr0 = whh + (long)grow0 * HD_;
    #pragma unroll 2
    for (int k = 0; k < HD_; k += 8) {
        float2 f0 = __half22float2(hrow[(k >> 1) + 0]);
        float2 f1 = __half22float2(hrow[(k >> 1) + 1]);
        float2 f2 = __half22float2(hrow[(k >> 1) + 2]);
        float2 f3 = __half22float2(hrow[(k >> 1) + 3]);
        #pragma unroll
        for (int jj = 0; jj < 4; jj++) {
            const float* wp = wr0 + jj * HD_ + k;
            float4 wa = *(const float4*)wp;
            float4 wb = *(const float4*)(wp + 4);
            acc[jj] += f0.x * wa.x + f0.y * wa.y + f1.x * wa.z + f1.y * wa.w
                     + f2.x * wb.x + f2.y * wb.y + f3.x * wb.z + f3.y * wb.w;
        }
    }
    const float* xrow = x + ((long)bg * S_ + tsrc) * WORD_;
    const float* wx0 = wih + (long)grow0 * WORD_;
    #pragma unroll 2
    for (int k = 0; k < WORD_; k += 4) {
        float4 xv = *(const float4*)(xrow + k);
        #pragma unroll
        for (int jj = 0; jj < 4; jj++) {
            float4 w4 = *(const float4*)(wx0 + jj * WORD_ + k);
            acc[jj] += xv.x * w4.x + xv.y * w4.y + xv.z * w4.z + xv.w * w4.w;
        }
    }
    #pragma unroll
    for (int jj = 0; jj < 4; jj++)
        gl[b * 33 + wv * 8 + gh * 4 + jj] = acc[jj];
    __syncthreads();

    {
        int bb = tid >> 3, j = tid & 7;
        float gi = gl[bb * 33 + 0  + j];
        float gf = gl[bb * 33 + 8  + j];
        float gg = gl[bb * 33 + 16 + j];
        float go = gl[bb * 33 + 24 + j];
        int bg2 = btile * 32 + bb;
        int hd  = slice * 8 + j;
        long cidx = (long)(d * B_ + bg2) * HD_ + hd;
        float c = (t == 0) ? 0.f : Cbuf[cidx];
        float si = 1.f / (1.f + expf(-gi));
        float sf = 1.f / (1.f + expf(-gf));
        float so = 1.f / (1.f + expf(-go));
        c = sf * c + si * tanhf(gg);
        float h = so * tanhf(c);
        Cbuf[cidx] = c;
        Hbuf[(long)((d * 2 + (parity ^ 1)) * B_ + bg2) * HD_ + hd] = __float2half(h);
        long m = (long)bg2 * S_ + tsrc;
        if (hd < 256) vs [m * SEMA_ + d * 256 + hd]         = __float2half(h);
        else          vst[m * STRU_ + d * 128 + (hd - 256)] = __float2half(h);
    }
}

// ---------------- f_r = exp(vst @ w_root^T) ----------------
__global__ __launch_bounds__(256)
void frow_kernel(const half_t* __restrict__ vst, const float* __restrict__ wroot,
                 float* __restrict__ fr)
{
    int row  = blockIdx.x * 4 + (threadIdx.x >> 6);
    int lane = threadIdx.x & 63;
    const half_t* v = vst + (long)row * 256;
    float s = 0.f;
    for (int k = lane; k < 256; k += 64) s += __half2float(v[k]) * wroot[k];
    #pragma unroll
    for (int off = 32; off; off >>= 1) s += __shfl_down(s, off);
    if (lane == 0) fr[row] = expf(s);
}

// ---------------- register-resident Gauss-Jordan inverse (256x256) ----------------
__global__ __launch_bounds__(512)
void invert_gj(const half_t* __restrict__ fA, const float* __restrict__ fr,
               half_t* __restrict__ LLinv)
{
    __shared__ float colbuf[256];
    __shared__ float rowbuf[256];
    __shared__ float csum[2][256];
    const int bz = blockIdx.x;
    const half_t* A = fA + (long)bz * 65536;
    const int tid = threadIdx.x;
    const int c = tid & 255, rh = tid >> 8;
    float m[128];

    float s = 0.f;
    #pragma unroll
    for (int i = 0; i < 128; i++) {
        float v = __half2float(A[(long)(rh * 128 + i) * 256 + c]);
        m[i] = v; s += v;
    }
    csum[rh][c] = s;
    __syncthreads();
    float diag = csum[0][c] + csum[1][c];
    const float frv = fr[bz * 256 + c];
    #pragma unroll
    for (int i = 0; i < 128; i++) {
        int r = rh * 128 + i;
        float v = (r == c) ? ((diag == 0.f) ? 1.f : diag) : -m[i];
        if (i == 0 && rh == 0) {
            v = frv;
            if (c == 0 && v == 0.f) v = 1.f;
        }
        m[i] = v;
    }
    __syncthreads();

    for (int k = 0; k < 256; k++) {
        const int kh = k >> 7, kl = k & 127;
        if (c == k) {
            #pragma unroll
            for (int i = 0; i < 128; i++) colbuf[rh * 128 + i] = m[i];
        }
        if (rh == kh) {
            float pv = 0.f;
            #pragma unroll
            for (int i = 0; i < 128; i++) pv = (i == kl) ? m[i] : pv;
            rowbuf[c] = pv;
        }
        __syncthreads();
        const float p    = colbuf[k];
        const float pinv = 1.f / p;
        const float rv   = rowbuf[c] * pinv;
        if (c == k) {
            #pragma unroll
            for (int i = 0; i < 128; i++) {
                int r = rh * 128 + i;
                m[i] = (r == k) ? pinv : -colbuf[r] * pinv;
            }
        } else {
            #pragma unroll
            for (int i = 0; i < 128; i++) {
                int r = rh * 128 + i;
                float nv = m[i] - colbuf[r] * rv;
                m[i] = (r == k) ? rv : nv;
            }
        }
        __syncthreads();
    }

    #pragma unroll
    for (int i = 0; i < 128; i++)
        LLinv[(long)bz * 65536 + (long)(rh * 128 + i) * 256 + c] = __float2half(m[i]);
}

// ---------------- diag(LLinv) and d0 ----------------
__global__ void diag_d0_k(const half_t* __restrict__ LLinv, const float* __restrict__ fr,
                          float* __restrict__ diagv, float* __restrict__ d0)
{
    int i = blockIdx.x * 256 + threadIdx.x;
    if (i >= 32768) return;
    int b = i >> 8, s = i & 255;
    diagv[i] = __half2float(LLinv[(long)b * 65536 + s * 257]);
    d0[i]    = fr[i] * __half2float(LLinv[(long)b * 65536 + s * 256]);
}

// ---------------- a = A*(diag - LLinv^T), in place over fA ----------------
__global__ __launch_bounds__(256)
void assemble_a(half_t* __restrict__ fA, const half_t* __restrict__ LLinv,
                const float* __restrict__ diagv)
{
    __shared__ float ll[32][33];
    const int bz = blockIdx.z;
    const int s0 = (blockIdx.x >> 3) * 32, t0 = (blockIdx.x & 7) * 32;
    const int tid = threadIdx.x;
    const long base = (long)bz * 65536;
    #pragma unroll
    for (int it = 0; it < 4; it++) {
        int i = (tid >> 5) + it * 8, j = tid & 31;
        ll[i][j] = __half2float(LLinv[base + (long)(t0 + i) * 256 + (s0 + j)]);
    }
    __syncthreads();
    #pragma unroll
    for (int it = 0; it < 4; it++) {
        int si = (tid >> 5) + it * 8, tj = tid & 31;
        int s = s0 + si, t = t0 + tj;
        long idx = base + (long)s * 256 + t;
        float Av = __half2float(fA[idx]);
        float t1 = (t > 0) ? diagv[(bz << 8) + t] : 0.f;
        float t2 = (s > 0) ? ll[tj][si] : 0.f;
        fA[idx] = __float2half(Av * (t1 - t2));
    }
}

// ---------------- emb = max over sequence ----------------
__global__ __launch_bounds__(256)
void emb_max(const float* __restrict__ outp, float* __restrict__ emb)
{
    int i = blockIdx.x * 256 + threadIdx.x;
    int b = i >> 9, n = i & 511;
    const float* p = outp + (long)b * S_ * SEMA_ + n;
    float mx = -3.4e38f;
    for (int t = 0; t < S_; t++) mx = fmaxf(mx, p[(long)t * SEMA_]);
    emb[i] = mx;
}

// ---------------- diagnostic ----------------
__global__ void diag_ws(float* out, int n, float v)
{
    int i = blockIdx.x * 256 + threadIdx.x;
    if (i < n) out[i] = v;
}

// ======================= host launch =======================
extern "C" void kernel_launch(void* const* d_in, const int* in_sizes, int n_in,
                              void* d_out, int out_size, void* d_ws, size_t ws_size,
                              hipStream_t stream)
{
    const float* x     = (const float*)d_in[0];
    const float* mask  = (const float*)d_in[1];
    const float* wihf  = (const float*)d_in[2];
    const float* whhf  = (const float*)d_in[3];
    const float* bf    = (const float*)d_in[4];
    const float* wihb  = (const float*)d_in[5];
    const float* whhb  = (const float*)d_in[6];
    const float* bb    = (const float*)d_in[7];
    const float* wtp   = (const float*)d_in[8];
    const float* btp   = (const float*)d_in[9];
    const float* wtc   = (const float*)d_in[10];
    const float* btc   = (const float*)d_in[11];
    const float* wa    = (const float*)d_in[12];
    const float* wroot = (const float*)d_in[13];
    const float* remb  = (const float*)d_in[14];
    const float* wr    = (const float*)d_in[15];
    const float* br    = (const float*)d_in[16];

    if (ws_size < 134217728ULL) {
        float enc = 100.0f + (float)((double)ws_size * 1e-9);
        diag_ws<<<dim3((out_size + 255) / 256), 256, 0, stream>>>((float*)d_out, out_size, enc);
        return;
    }

    char* ws = (char*)d_ws;
    half_t* vs    = (half_t*)(ws + 0);            // 32768 x 512
    half_t* vst   = (half_t*)(ws + 33554432);     // 32768 x 256 (dead after tc GEMM)
    half_t* wr16  = (half_t*)(ws + 33554432);     // 512 x 1536, converted after tc GEMM
    half_t* tp    = (half_t*)(ws + 50331648);     // dead after tmp GEMM
    half_t* aT    = (half_t*)(ws + 50331648);     // over tp
    half_t* tc    = (half_t*)(ws + 67108864);     // dead after f GEMM
    half_t* cbuf  = (half_t*)(ws + 67108864);     // 33.5MB over tc+tmp
    half_t* tmp   = (half_t*)(ws + 83886080);     // dead after f GEMM
    half_t* fA    = (half_t*)(ws + 100663296);    // dead after c GEMM
    half_t* pbuf  = (half_t*)(ws + 100663296);    // 33.5MB over fA+LL
    half_t* LL    = (half_t*)(ws + 117440512);    // dead after assemble
    half_t* wtp16 = (half_t*)(ws + 117440512);    // early weights in LL region (pre-invert)
    half_t* wtc16 = (half_t*)(ws + 117440512 + 131072);
    half_t* wa16T = (half_t*)(ws + 117440512 + 262144);

    // small state in the tail of d_out's output region (dead until finals)
    float* tail  = (float*)d_out + 16547840;
    float*  fr    = tail;
    float*  d0    = tail + 32768;
    float*  diagv = tail + 65536;
    float*  Cbuf  = tail + 98304;
    half_t* Hbuf  = (half_t*)(tail + 196608);

    float* emb  = (float*)d_out;
    float* outp = (float*)d_out + 65536;

    // 1. BiLSTM recurrence, 256 steps
    for (int t = 0; t < S_; t++)
        lstm_step<<<dim3(384), 256, 0, stream>>>(
            x, whhf, whhb, wihf, wihb, bf, bb, Hbuf, Cbuf, vs, vst, t);

    // 2. f_r
    frow_kernel<<<dim3(8192), 256, 0, stream>>>(vst, wroot, fr);

    // 3. convert small weights (into LL region, dead until invert)
    conv16<<<dim3(256), 256, 0, stream>>>(wtp, wtp16, 65536);
    conv16<<<dim3(256), 256, 0, stream>>>(wtc, wtc16, 65536);
    convT16<<<dim3(256), 256, 0, stream>>>(wa, wa16T, 256, 256);

    // 4. tp / tc = tanh(vst @ W^T + b)
    mgemm<false><<<dim3(4, 256, 1), 256, 0, stream>>>(
        vst, wtp16, tp, M_, 256, 256, 256, 256, 256, 0, 0, 0, btp, 1, nullptr, nullptr);
    mgemm<false><<<dim3(4, 256, 1), 256, 0, stream>>>(
        vst, wtc16, tc, M_, 256, 256, 256, 256, 256, 0, 0, 0, btc, 1, nullptr, nullptr);

    // 5. wr -> f16 (vst now dead)
    conv16<<<dim3(3072), 256, 0, stream>>>(wr, wr16, 786432);

    // 6. tmp = tp @ w_a
    mgemm<false><<<dim3(4, 256, 1), 256, 0, stream>>>(
        tp, wa16T, tmp, M_, 256, 256, 256, 256, 256, 0, 0, 0, nullptr, 0, nullptr, nullptr);

    // 7. f = exp(tmp @ tc^T), diag zeroed (batched)
    mgemm<false><<<dim3(4, 2, 128), 256, 0, stream>>>(
        tmp, tc, fA, 256, 256, 256, 256, 256, 256, 65536, 65536, 65536,
        nullptr, 2, nullptr, nullptr);

    // 8. inverse
    invert_gj<<<dim3(128), 512, 0, stream>>>(fA, fr, LL);

    // 9. diag/d0
    diag_d0_k<<<dim3(128), 256, 0, stream>>>(LL, fr, diagv, d0);

    // 10. a = A*(diag - LLinv^T), in place
    assemble_a<<<dim3(64, 1, 128), 256, 0, stream>>>(fA, LL, diagv);

    // 11. aT
    transpose256h<<<dim3(8, 8, 128), dim3(32, 8), 0, stream>>>(fA, aT);

    // 12. c = a @ vs  (B is NN)
    mgemm<true><<<dim3(8, 2, 128), 256, 0, stream>>>(
        fA, vs, cbuf, 256, 512, 256, 256, 512, 512, 65536, 131072, 131072,
        nullptr, 0, nullptr, nullptr);

    // 13. p = aT @ vs + d0 (x) root_emb
    mgemm<true><<<dim3(8, 2, 128), 256, 0, stream>>>(
        aT, vs, pbuf, 256, 512, 256, 256, 512, 512, 65536, 131072, 131072,
        nullptr, 0, d0, remb);

    // 14. out = tanh([vs|p|c] @ wr^T + br) * mask
    mgemm_final<<<dim3(8, 256, 1), 256, 0, stream>>>(vs, pbuf, cbuf, wr16, outp, br, mask);

    // 15. emb
    emb_max<<<dim3(256), 256, 0, stream>>>(outp, emb);
}

// Round 4
// 8237.823 us; speedup vs baseline: 2.5186x; 2.4098x over previous
//
#include <hip/hip_runtime.h>
#include <hip/hip_fp16.h>
#include <math.h>

#define B_    128
#define S_    256
#define WORD_ 300
#define HD_   384
#define M_    32768
#define STRU_ 256
#define SEMA_ 512
#define SEG   16777216L

typedef __half half_t;
typedef _Float16 f16x8 __attribute__((ext_vector_type(8)));
typedef float    f32x4 __attribute__((ext_vector_type(4)));

// ================= MFMA GEMM: C(f16) = act(A @ B(.T) + bias + d0*root) =================
template<bool BNN>
__global__ __launch_bounds__(256)
void mgemm(const half_t* __restrict__ Ag, const half_t* __restrict__ Bg,
           half_t* __restrict__ Cg,
           int M, int N, int K, int lda, int ldb, int ldc,
           long sA, long sB, long sC,
           const float* __restrict__ bias, int act,
           const float* __restrict__ d0v, const float* __restrict__ rootv)
{
    __shared__ __half As[128][40];
    __shared__ __half Bs[64][40];
    const int bz = blockIdx.z;
    const half_t* A  = Ag + (long)bz * sA;
    const half_t* Bp = Bg + (long)bz * sB;
    const int m0 = blockIdx.y * 128, n0 = blockIdx.x * 64;
    const int tid = threadIdx.x;
    const int l = tid & 63, w = tid >> 6;
    const int wm = w & 1, wn = w >> 1;
    const int lr = l & 15, lq = l >> 4;

    f32x4 acc[4][2] = {};

    for (int k0 = 0; k0 < K; k0 += 32) {
        #pragma unroll
        for (int i = 0; i < 2; i++) {
            int ch = tid + i * 256;
            int r = ch >> 2, j = ch & 3;
            *(float4*)&As[r][j * 8] = *(const float4*)(A + (long)(m0 + r) * lda + k0 + j * 8);
        }
        if (!BNN) {
            int r = tid >> 2, j = tid & 3;
            *(float4*)&Bs[r][j * 8] = *(const float4*)(Bp + (long)(n0 + r) * ldb + k0 + j * 8);
        } else {
            int k = tid & 31, nc = tid >> 5;
            float4 v = *(const float4*)(Bp + (long)(k0 + k) * ldb + n0 + nc * 8);
            const __half* hv = (const __half*)&v;
            #pragma unroll
            for (int jj = 0; jj < 8; jj++) Bs[nc * 8 + jj][k] = hv[jj];
        }
        __syncthreads();

        f16x8 af[4], bf[2];
        #pragma unroll
        for (int mf = 0; mf < 4; mf++)
            af[mf] = *(const f16x8*)&As[wm * 64 + mf * 16 + lr][lq * 8];
        #pragma unroll
        for (int nf = 0; nf < 2; nf++)
            bf[nf] = *(const f16x8*)&Bs[wn * 32 + nf * 16 + lr][lq * 8];
        #pragma unroll
        for (int mf = 0; mf < 4; mf++)
            #pragma unroll
            for (int nf = 0; nf < 2; nf++)
                acc[mf][nf] = __builtin_amdgcn_mfma_f32_16x16x32_f16(af[mf], bf[nf], acc[mf][nf], 0, 0, 0);
        __syncthreads();
    }

    #pragma unroll
    for (int mf = 0; mf < 4; mf++) {
        #pragma unroll
        for (int nf = 0; nf < 2; nf++) {
            #pragma unroll
            for (int j = 0; j < 4; j++) {
                int m = m0 + wm * 64 + mf * 16 + lq * 4 + j;
                int n = n0 + wn * 32 + nf * 16 + lr;
                float v = acc[mf][nf][j];
                if (bias) v += bias[n];
                if (d0v)  v += d0v[(long)bz * M + m] * rootv[n];
                if (act == 1)      v = tanhf(v);
                else if (act == 2) v = (m == n) ? 0.f : expf(v);
                Cg[(long)bz * sC + (long)m * ldc + n] = __float2half(v);
            }
        }
    }
}

// ============ final: out = tanh(vs@W1^T + p@W2^T + c@W3^T + br) * mask ============
__global__ __launch_bounds__(256)
void mgemm_final(const half_t* __restrict__ A0, const half_t* __restrict__ A1,
                 const half_t* __restrict__ A2, const half_t* __restrict__ Bw,
                 float* __restrict__ Cout, const float* __restrict__ bias,
                 const float* __restrict__ maskp)
{
    __shared__ __half As[128][40];
    __shared__ __half Bs[64][40];
    const int m0 = blockIdx.y * 128, n0 = blockIdx.x * 64;
    const int tid = threadIdx.x;
    const int l = tid & 63, w = tid >> 6;
    const int wm = w & 1, wn = w >> 1;
    const int lr = l & 15, lq = l >> 4;

    f32x4 acc[4][2] = {};

    for (int k0 = 0; k0 < 1536; k0 += 32) {
        const half_t* A = (k0 < 512) ? A0 : (k0 < 1024) ? A1 : A2;
        const int kk = k0 & 511;
        #pragma unroll
        for (int i = 0; i < 2; i++) {
            int ch = tid + i * 256;
            int r = ch >> 2, j = ch & 3;
            *(float4*)&As[r][j * 8] = *(const float4*)(A + (long)(m0 + r) * 512 + kk + j * 8);
        }
        {
            int r = tid >> 2, j = tid & 3;
            *(float4*)&Bs[r][j * 8] = *(const float4*)(Bw + (long)(n0 + r) * 1536 + k0 + j * 8);
        }
        __syncthreads();
        f16x8 af[4], bf[2];
        #pragma unroll
        for (int mf = 0; mf < 4; mf++)
            af[mf] = *(const f16x8*)&As[wm * 64 + mf * 16 + lr][lq * 8];
        #pragma unroll
        for (int nf = 0; nf < 2; nf++)
            bf[nf] = *(const f16x8*)&Bs[wn * 32 + nf * 16 + lr][lq * 8];
        #pragma unroll
        for (int mf = 0; mf < 4; mf++)
            #pragma unroll
            for (int nf = 0; nf < 2; nf++)
                acc[mf][nf] = __builtin_amdgcn_mfma_f32_16x16x32_f16(af[mf], bf[nf], acc[mf][nf], 0, 0, 0);
        __syncthreads();
    }

    #pragma unroll
    for (int mf = 0; mf < 4; mf++) {
        #pragma unroll
        for (int nf = 0; nf < 2; nf++) {
            #pragma unroll
            for (int j = 0; j < 4; j++) {
                int m = m0 + wm * 64 + mf * 16 + lq * 4 + j;
                int n = n0 + wn * 32 + nf * 16 + lr;
                float v = tanhf(acc[mf][nf][j] + bias[n]) * maskp[m];
                Cout[(long)m * 512 + n] = v;
            }
        }
    }
}

// ================ G = x @ Wih_packed^T + b : M-tile = 128 batch rows at ts=by ================
__global__ __launch_bounds__(256)
void ggemm(const float* __restrict__ x, const half_t* __restrict__ Wp,
           const float* __restrict__ bp, half_t* __restrict__ G, int chunk)
{
    __shared__ __half As[128][40];
    __shared__ __half Bs[64][40];
    const int d = blockIdx.z;
    const int ts = blockIdx.y;                 // step-in-chunk 0..127
    const int n0 = blockIdx.x * 64;
    const int t_orig = d ? (255 - (chunk * 128 + ts)) : (chunk * 128 + ts);
    const int tid = threadIdx.x;
    const int l = tid & 63, w = tid >> 6;
    const int wm = w & 1, wn = w >> 1;
    const int lr = l & 15, lq = l >> 4;

    f32x4 acc[4][2] = {};

    for (int k0 = 0; k0 < 320; k0 += 32) {
        #pragma unroll
        for (int i = 0; i < 4; i++) {
            int e = tid + i * 256;             // 1024 groups of 4 floats
            int r = e >> 3, j = (e & 7) * 4;
            int k = k0 + j;
            float4 v = make_float4(0.f, 0.f, 0.f, 0.f);
            if (k < 300) {
                const float* xp = x + ((long)r * 256 + t_orig) * 300 + k;
                if (k + 4 <= 300) v = *(const float4*)xp;
                else { v.x = xp[0]; v.y = (k+1<300)?xp[1]:0.f; v.z = (k+2<300)?xp[2]:0.f; }
            }
            __half* dst = &As[r][j];
            dst[0] = __float2half(v.x); dst[1] = __float2half(v.y);
            dst[2] = __float2half(v.z); dst[3] = __float2half(v.w);
        }
        {
            int r = tid >> 2, j = (tid & 3) * 8;
            *(float4*)&Bs[r][j] = *(const float4*)(Wp + ((long)d * 1536 + n0 + r) * 320 + k0 + j);
        }
        __syncthreads();
        f16x8 af[4], bf[2];
        #pragma unroll
        for (int mf = 0; mf < 4; mf++)
            af[mf] = *(const f16x8*)&As[wm * 64 + mf * 16 + lr][lq * 8];
        #pragma unroll
        for (int nf = 0; nf < 2; nf++)
            bf[nf] = *(const f16x8*)&Bs[wn * 32 + nf * 16 + lr][lq * 8];
        #pragma unroll
        for (int mf = 0; mf < 4; mf++)
            #pragma unroll
            for (int nf = 0; nf < 2; nf++)
                acc[mf][nf] = __builtin_amdgcn_mfma_f32_16x16x32_f16(af[mf], bf[nf], acc[mf][nf], 0, 0, 0);
        __syncthreads();
    }

    #pragma unroll
    for (int mf = 0; mf < 4; mf++) {
        #pragma unroll
        for (int nf = 0; nf < 2; nf++) {
            #pragma unroll
            for (int j = 0; j < 4; j++) {
                int b = wm * 64 + mf * 16 + lq * 4 + j;     // batch row
                int n = n0 + wn * 32 + nf * 16 + lr;         // packed gate
                float v = acc[mf][nf][j] + bp[d * 1536 + n];
                G[((long)(d * 128 + ts) * 128 + b) * 1536 + n] = __float2half(v);
            }
        }
    }
}

// ================ MFMA LSTM step: 48 WGs = d(2) x ntile(24, 64 packed gates) ================
__global__ __launch_bounds__(256)
void lstm_step_m(const half_t* __restrict__ G, const half_t* __restrict__ Whh,
                 half_t* __restrict__ Hbuf, float* __restrict__ Cbuf,
                 half_t* __restrict__ vs, half_t* __restrict__ vst, int step)
{
    __shared__ char smem[34816];                // staging (15,360B) / gl 128x68 f32
    __half (*As)[40] = (__half(*)[40])smem;     // 128x40
    __half (*Bs)[40] = (__half(*)[40])(smem + 10240);
    float* gl = (float*)smem;

    const int bid = blockIdx.x;
    const int d = bid / 24, ntile = bid % 24;
    const int n0 = ntile * 64;
    const int ts = step & 127;
    const int parity = step & 1;
    const int tid = threadIdx.x;
    const int l = tid & 63, w = tid >> 6;
    const int wm = w & 1, wn = w >> 1;
    const int lr = l & 15, lq = l >> 4;

    const half_t* hsrc = Hbuf + (long)(d * 2 + parity) * 128 * 384;
    const half_t* wsl  = Whh + ((long)d * 1536 + n0) * 384;

    f32x4 acc[4][2] = {};
    for (int k0 = 0; k0 < 384; k0 += 32) {
        #pragma unroll
        for (int i = 0; i < 2; i++) {
            int e = tid + i * 256;
            int r = e >> 2, j = (e & 3) * 8;
            *(float4*)&As[r][j] = *(const float4*)(hsrc + (long)r * 384 + k0 + j);
        }
        {
            int r = tid >> 2, j = (tid & 3) * 8;
            *(float4*)&Bs[r][j] = *(const float4*)(wsl + (long)r * 384 + k0 + j);
        }
        __syncthreads();
        f16x8 af[4], bf[2];
        #pragma unroll
        for (int mf = 0; mf < 4; mf++)
            af[mf] = *(const f16x8*)&As[wm * 64 + mf * 16 + lr][lq * 8];
        #pragma unroll
        for (int nf = 0; nf < 2; nf++)
            bf[nf] = *(const f16x8*)&Bs[wn * 32 + nf * 16 + lr][lq * 8];
        #pragma unroll
        for (int mf = 0; mf < 4; mf++)
            #pragma unroll
            for (int nf = 0; nf < 2; nf++)
                acc[mf][nf] = __builtin_amdgcn_mfma_f32_16x16x32_f16(af[mf], bf[nf], acc[mf][nf], 0, 0, 0);
        __syncthreads();
    }

    // gates += G ; publish to LDS
    const half_t* gp = G + (long)(d * 128 + ts) * 128 * 1536;
    #pragma unroll
    for (int mf = 0; mf < 4; mf++) {
        #pragma unroll
        for (int nf = 0; nf < 2; nf++) {
            #pragma unroll
            for (int j = 0; j < 4; j++) {
                int m = wm * 64 + mf * 16 + lq * 4 + j;
                int n = wn * 32 + nf * 16 + lr;
                gl[m * 68 + n] = acc[mf][nf][j] + __half2float(gp[(long)m * 1536 + n0 + n]);
            }
        }
    }
    __syncthreads();

    const int t_orig = d ? (255 - step) : step;
    for (int it = tid; it < 2048; it += 256) {
        int b = it >> 4, lhd = it & 15;
        float gi = gl[b * 68 + lhd * 4 + 0];
        float gf = gl[b * 68 + lhd * 4 + 1];
        float gg = gl[b * 68 + lhd * 4 + 2];
        float go = gl[b * 68 + lhd * 4 + 3];
        int hd = (n0 >> 2) + lhd;
        long cidx = ((long)d * 128 + b) * 384 + hd;
        float c = Cbuf[cidx];
        float si = 1.f / (1.f + expf(-gi));
        float sf = 1.f / (1.f + expf(-gf));
        float so = 1.f / (1.f + expf(-go));
        c = sf * c + si * tanhf(gg);
        float h = so * tanhf(c);
        Cbuf[cidx] = c;
        Hbuf[((long)(d * 2 + (parity ^ 1)) * 128 + b) * 384 + hd] = __float2half(h);
        long mrow = (long)b * 256 + t_orig;
        if (hd < 256) vs [mrow * 512 + d * 256 + hd]         = __float2half(h);
        else          vst[mrow * 256 + d * 128 + (hd - 256)] = __float2half(h);
    }
}

// ---------------- packs / converts ----------------
__global__ void pack_wih(const float* __restrict__ wf, const float* __restrict__ wb,
                         const float* __restrict__ bfv, const float* __restrict__ bbv,
                         half_t* __restrict__ Wp, float* __restrict__ bp)
{
    int i = blockIdx.x * 256 + threadIdx.x;
    if (i < 983040) {
        int k = i % 320, pr = (i / 320) % 1536, d = i / 491520;
        int q = pr & 3, hd = pr >> 2;
        float v = (k < 300) ? (d ? wb : wf)[(q * 384 + hd) * 300 + k] : 0.f;
        Wp[i] = __float2half(v);
    }
    if (i < 3072) {
        int d = i / 1536, pr = i % 1536;
        int q = pr & 3, hd = pr >> 2;
        bp[i] = (d ? bbv : bfv)[q * 384 + hd];
    }
}
__global__ void pack_whh(const float* __restrict__ wf, const float* __restrict__ wb,
                         half_t* __restrict__ Wh)
{
    int i = blockIdx.x * 256 + threadIdx.x;
    if (i >= 1179648) return;
    int k = i % 384, pr = (i / 384) % 1536, d = i / 589824;
    int q = pr & 3, hd = pr >> 2;
    Wh[i] = __float2half((d ? wb : wf)[(q * 384 + hd) * 384 + k]);
}
__global__ void conv16(const float* __restrict__ s, half_t* __restrict__ d, long n)
{
    long i = (long)blockIdx.x * 256 + threadIdx.x;
    if (i < n) d[i] = __float2half(s[i]);
}
__global__ void convT16(const float* __restrict__ s, half_t* __restrict__ d, int R, int C)
{
    int i = blockIdx.x * 256 + threadIdx.x;
    if (i >= R * C) return;
    int r = i / C, c = i % C;
    d[(long)c * R + r] = __float2half(s[i]);
}

// ---------------- f_r = exp(vst @ w_root^T) ----------------
__global__ __launch_bounds__(256)
void frow_kernel(const half_t* __restrict__ vst, const float* __restrict__ wroot,
                 float* __restrict__ fr)
{
    int row  = blockIdx.x * 4 + (threadIdx.x >> 6);
    int lane = threadIdx.x & 63;
    const half_t* v = vst + (long)row * 256;
    float s = 0.f;
    for (int k = lane; k < 256; k += 64) s += __half2float(v[k]) * wroot[k];
    #pragma unroll
    for (int off = 32; off; off >>= 1) s += __shfl_down(s, off);
    if (lane == 0) fr[row] = expf(s);
}

// ---------------- register-resident Gauss-Jordan inverse (256x256) ----------------
__global__ __launch_bounds__(512)
void invert_gj(const half_t* __restrict__ fA, const float* __restrict__ fr,
               half_t* __restrict__ LLinv)
{
    __shared__ float colbuf[256];
    __shared__ float rowbuf[256];
    __shared__ float csum[2][256];
    const int bz = blockIdx.x;
    const half_t* A = fA + (long)bz * 65536;
    const int tid = threadIdx.x;
    const int c = tid & 255, rh = tid >> 8;
    float m[128];

    float s = 0.f;
    #pragma unroll
    for (int i = 0; i < 128; i++) {
        float v = __half2float(A[(long)(rh * 128 + i) * 256 + c]);
        m[i] = v; s += v;
    }
    csum[rh][c] = s;
    __syncthreads();
    float diag = csum[0][c] + csum[1][c];
    const float frv = fr[bz * 256 + c];
    #pragma unroll
    for (int i = 0; i < 128; i++) {
        int r = rh * 128 + i;
        float v = (r == c) ? ((diag == 0.f) ? 1.f : diag) : -m[i];
        if (i == 0 && rh == 0) {
            v = frv;
            if (c == 0 && v == 0.f) v = 1.f;
        }
        m[i] = v;
    }
    __syncthreads();

    for (int k = 0; k < 256; k++) {
        const int kh = k >> 7, kl = k & 127;
        if (c == k) {
            #pragma unroll
            for (int i = 0; i < 128; i++) colbuf[rh * 128 + i] = m[i];
        }
        if (rh == kh) {
            float pv = 0.f;
            #pragma unroll
            for (int i = 0; i < 128; i++) pv = (i == kl) ? m[i] : pv;
            rowbuf[c] = pv;
        }
        __syncthreads();
        const float p    = colbuf[k];
        const float pinv = 1.f / p;
        const float rv   = rowbuf[c] * pinv;
        if (c == k) {
            #pragma unroll
            for (int i = 0; i < 128; i++) {
                int r = rh * 128 + i;
                m[i] = (r == k) ? pinv : -colbuf[r] * pinv;
            }
        } else {
            #pragma unroll
            for (int i = 0; i < 128; i++) {
                int r = rh * 128 + i;
                float nv = m[i] - colbuf[r] * rv;
                m[i] = (r == k) ? rv : nv;
            }
        }
        __syncthreads();
    }

    #pragma unroll
    for (int i = 0; i < 128; i++)
        LLinv[(long)bz * 65536 + (long)(rh * 128 + i) * 256 + c] = __float2half(m[i]);
}

// ---------------- diag(LLinv) and d0 ----------------
__global__ void diag_d0_k(const half_t* __restrict__ LLinv, const float* __restrict__ fr,
                          float* __restrict__ diagv, float* __restrict__ d0)
{
    int i = blockIdx.x * 256 + threadIdx.x;
    if (i >= 32768) return;
    int b = i >> 8, s = i & 255;
    diagv[i] = __half2float(LLinv[(long)b * 65536 + s * 257]);
    d0[i]    = fr[i] * __half2float(LLinv[(long)b * 65536 + s * 256]);
}

// ---------------- a = A*(diag - LLinv^T), in place ----------------
__global__ __launch_bounds__(256)
void assemble_a(half_t* __restrict__ fA, const half_t* __restrict__ LLinv,
                const float* __restrict__ diagv)
{
    __shared__ float ll[32][33];
    const int bz = blockIdx.z;
    const int s0 = (blockIdx.x >> 3) * 32, t0 = (blockIdx.x & 7) * 32;
    const int tid = threadIdx.x;
    const long base = (long)bz * 65536;
    #pragma unroll
    for (int it = 0; it < 4; it++) {
        int i = (tid >> 5) + it * 8, j = tid & 31;
        ll[i][j] = __half2float(LLinv[base + (long)(t0 + i) * 256 + (s0 + j)]);
    }
    __syncthreads();
    #pragma unroll
    for (int it = 0; it < 4; it++) {
        int si = (tid >> 5) + it * 8, tj = tid & 31;
        int s = s0 + si, t = t0 + tj;
        long idx = base + (long)s * 256 + t;
        float Av = __half2float(fA[idx]);
        float t1 = (t > 0) ? diagv[(bz << 8) + t] : 0.f;
        float t2 = (s > 0) ? ll[tj][si] : 0.f;
        fA[idx] = __float2half(Av * (t1 - t2));
    }
}

// ---------------- batched 256x256 f16 transpose ----------------
__global__ __launch_bounds__(256)
void transpose256h(const half_t* __restrict__ in, half_t* __restrict__ out)
{
    __shared__ __half tb[32][33];
    const int bz = blockIdx.z;
    const half_t* ip = in  + (long)bz * 65536;
    half_t*       op = out + (long)bz * 65536;
    int x0 = blockIdx.x * 32, y0 = blockIdx.y * 32;
    int tx = threadIdx.x, ty = threadIdx.y;
    #pragma unroll
    for (int r = 0; r < 4; r++)
        tb[ty + 8 * r][tx] = ip[(long)(y0 + ty + 8 * r) * 256 + x0 + tx];
    __syncthreads();
    #pragma unroll
    for (int r = 0; r < 4; r++)
        op[(long)(x0 + ty + 8 * r) * 256 + y0 + tx] = tb[tx][ty + 8 * r];
}

// ---------------- emb = max over sequence ----------------
__global__ __launch_bounds__(256)
void emb_max(const float* __restrict__ outp, float* __restrict__ emb)
{
    int i = blockIdx.x * 256 + threadIdx.x;
    int b = i >> 9, n = i & 511;
    const float* p = outp + (long)b * S_ * SEMA_ + n;
    float mx = -3.4e38f;
    for (int t = 0; t < S_; t++) mx = fmaxf(mx, p[(long)t * SEMA_]);
    emb[i] = mx;
}

__global__ void diag_ws(float* out, int n, float v)
{
    int i = blockIdx.x * 256 + threadIdx.x;
    if (i < n) out[i] = v;
}

// ======================= host launch =======================
extern "C" void kernel_launch(void* const* d_in, const int* in_sizes, int n_in,
                              void* d_out, int out_size, void* d_ws, size_t ws_size,
                              hipStream_t stream)
{
    const float* x     = (const float*)d_in[0];
    const float* mask  = (const float*)d_in[1];
    const float* wihf  = (const float*)d_in[2];
    const float* whhf  = (const float*)d_in[3];
    const float* bf    = (const float*)d_in[4];
    const float* wihb  = (const float*)d_in[5];
    const float* whhb  = (const float*)d_in[6];
    const float* bb    = (const float*)d_in[7];
    const float* wtp   = (const float*)d_in[8];
    const float* btp   = (const float*)d_in[9];
    const float* wtc   = (const float*)d_in[10];
    const float* btc   = (const float*)d_in[11];
    const float* wa    = (const float*)d_in[12];
    const float* wroot = (const float*)d_in[13];
    const float* remb  = (const float*)d_in[14];
    const float* wr    = (const float*)d_in[15];
    const float* br    = (const float*)d_in[16];

    if (ws_size < 134217728ULL) {
        float enc = 100.0f + (float)((double)ws_size * 1e-9);
        diag_ws<<<dim3((out_size + 255) / 256), 256, 0, stream>>>((float*)d_out, out_size, enc);
        return;
    }

    char* ws = (char*)d_ws;
    half_t* G     = (half_t*)(ws + 0);              // 100,663,296 B (chunked gates)
    half_t* vs    = (half_t*)(ws + 100663296);      // 33,554,432 B
    half_t* tp    = (half_t*)(ws + 0 * SEG);        // post-scan overlays of G region
    half_t* tc    = (half_t*)(ws + 1 * SEG);
    half_t* tmp   = (half_t*)(ws + 2 * SEG);
    half_t* fA    = (half_t*)(ws + 3 * SEG);
    half_t* LL    = (half_t*)(ws + 4 * SEG);
    half_t* aT    = (half_t*)(ws + 5 * SEG);
    half_t* cbuf  = (half_t*)(ws + 0 * SEG);        // 33.5MB over tp+tc
    half_t* pbuf  = (half_t*)(ws + 2 * SEG);        // 33.5MB over tmp+fA
    half_t* wr16  = (half_t*)(ws + 4 * SEG);        // over LL after assemble

    // dead-until-final region of d_out hosts scan state + small weights
    float* ob = (float*)d_out;
    half_t* Wp16  = (half_t*)(ob + 11000000);   // 983,040 f16
    half_t* Whh16 = (half_t*)(ob + 11491520);   // 1,179,648 f16
    float*  bp    = ob + 12081344;              // 3,072
    half_t* wtp16 = (half_t*)(ob + 12084416);   // 65,536 f16
    half_t* wtc16 = (half_t*)(ob + 12117184);
    half_t* wa16T = (half_t*)(ob + 12149952);
    float*  fr    = ob + 12182720;
    float*  d0    = ob + 12215488;
    float*  diagv = ob + 12248256;
    float*  Cbuf  = ob + 12281024;              // 98,304 f32
    half_t* Hbuf  = (half_t*)(ob + 12379328);   // 196,608 f16
    half_t* vst   = (half_t*)(ob + 12648448);   // 8,388,608 f16 -> ends at 16,842,752

    float* emb  = (float*)d_out;
    float* outp = (float*)d_out + 65536;

    // 0. init state + pack weights
    hipMemsetAsync(Cbuf, 0, 393216, stream);
    hipMemsetAsync(Hbuf, 0, 393216, stream);
    pack_wih<<<dim3(3840), 256, 0, stream>>>(wihf, wihb, bf, bb, Wp16, bp);
    pack_whh<<<dim3(4608), 256, 0, stream>>>(whhf, whhb, Whh16);
    conv16<<<dim3(256), 256, 0, stream>>>(wtp, wtp16, 65536);
    conv16<<<dim3(256), 256, 0, stream>>>(wtc, wtc16, 65536);
    convT16<<<dim3(256), 256, 0, stream>>>(wa, wa16T, 256, 256);

    // 1. chunked: G GEMM + 128 MFMA LSTM steps, twice
    for (int c = 0; c < 2; c++) {
        ggemm<<<dim3(24, 128, 2), 256, 0, stream>>>(x, Wp16, bp, G, c);
        for (int ts = 0; ts < 128; ts++)
            lstm_step_m<<<dim3(48), 256, 0, stream>>>(G, Whh16, Hbuf, Cbuf, vs, vst, c * 128 + ts);
    }

    // 2. f_r
    frow_kernel<<<dim3(8192), 256, 0, stream>>>(vst, wroot, fr);

    // 3. tp / tc = tanh(vst @ W^T + b)
    mgemm<false><<<dim3(4, 256, 1), 256, 0, stream>>>(
        vst, wtp16, tp, M_, 256, 256, 256, 256, 256, 0, 0, 0, btp, 1, nullptr, nullptr);
    mgemm<false><<<dim3(4, 256, 1), 256, 0, stream>>>(
        vst, wtc16, tc, M_, 256, 256, 256, 256, 256, 0, 0, 0, btc, 1, nullptr, nullptr);

    // 4. tmp = tp @ w_a
    mgemm<false><<<dim3(4, 256, 1), 256, 0, stream>>>(
        tp, wa16T, tmp, M_, 256, 256, 256, 256, 256, 0, 0, 0, nullptr, 0, nullptr, nullptr);

    // 5. f = exp(tmp @ tc^T), diag zeroed (batched)
    mgemm<false><<<dim3(4, 2, 128), 256, 0, stream>>>(
        tmp, tc, fA, 256, 256, 256, 256, 256, 256, 65536, 65536, 65536,
        nullptr, 2, nullptr, nullptr);

    // 6-8. inverse, diag/d0, assemble
    invert_gj<<<dim3(128), 512, 0, stream>>>(fA, fr, LL);
    diag_d0_k<<<dim3(128), 256, 0, stream>>>(LL, fr, diagv, d0);
    assemble_a<<<dim3(64, 1, 128), 256, 0, stream>>>(fA, LL, diagv);

    // 9. wr -> f16 (LL dead now)
    conv16<<<dim3(3072), 256, 0, stream>>>(wr, wr16, 786432);

    // 10. aT
    transpose256h<<<dim3(8, 8, 128), dim3(32, 8), 0, stream>>>(fA, aT);

    // 11. c = a @ vs
    mgemm<true><<<dim3(8, 2, 128), 256, 0, stream>>>(
        fA, vs, cbuf, 256, 512, 256, 256, 512, 512, 65536, 131072, 131072,
        nullptr, 0, nullptr, nullptr);

    // 12. p = aT @ vs + d0 (x) root_emb
    mgemm<true><<<dim3(8, 2, 128), 256, 0, stream>>>(
        aT, vs, pbuf, 256, 512, 256, 256, 512, 512, 65536, 131072, 131072,
        nullptr, 0, d0, remb);

    // 13. out = tanh([vs|p|c] @ wr^T + br) * mask
    mgemm_final<<<dim3(8, 256, 1), 256, 0, stream>>>(vs, pbuf, cbuf, wr16, outp, br, mask);

    // 14. emb
    emb_max<<<dim3(256), 256, 0, stream>>>(outp, emb);
}

// Round 5
// 7663.733 us; speedup vs baseline: 2.7073x; 1.0749x over previous
//
#include <hip/hip_runtime.h>
#include <hip/hip_fp16.h>
#include <math.h>

#define B_    128
#define S_    256
#define WORD_ 300
#define HD_   384
#define M_    32768
#define STRU_ 256
#define SEMA_ 512
#define SEG   16777216L

typedef __half half_t;
typedef _Float16 f16x8 __attribute__((ext_vector_type(8)));
typedef float    f32x4 __attribute__((ext_vector_type(4)));

// ================= MFMA GEMM: C(f16) = act(A @ B(.T) + bias + d0*root) =================
template<bool BNN>
__global__ __launch_bounds__(256)
void mgemm(const half_t* __restrict__ Ag, const half_t* __restrict__ Bg,
           half_t* __restrict__ Cg,
           int M, int N, int K, int lda, int ldb, int ldc,
           long sA, long sB, long sC,
           const float* __restrict__ bias, int act,
           const float* __restrict__ d0v, const float* __restrict__ rootv)
{
    __shared__ __half As[128][40];
    __shared__ __half Bs[64][40];
    const int bz = blockIdx.z;
    const half_t* A  = Ag + (long)bz * sA;
    const half_t* Bp = Bg + (long)bz * sB;
    const int m0 = blockIdx.y * 128, n0 = blockIdx.x * 64;
    const int tid = threadIdx.x;
    const int l = tid & 63, w = tid >> 6;
    const int wm = w & 1, wn = w >> 1;
    const int lr = l & 15, lq = l >> 4;

    f32x4 acc[4][2] = {};

    for (int k0 = 0; k0 < K; k0 += 32) {
        #pragma unroll
        for (int i = 0; i < 2; i++) {
            int ch = tid + i * 256;
            int r = ch >> 2, j = ch & 3;
            *(float4*)&As[r][j * 8] = *(const float4*)(A + (long)(m0 + r) * lda + k0 + j * 8);
        }
        if (!BNN) {
            int r = tid >> 2, j = tid & 3;
            *(float4*)&Bs[r][j * 8] = *(const float4*)(Bp + (long)(n0 + r) * ldb + k0 + j * 8);
        } else {
            int k = tid & 31, nc = tid >> 5;
            float4 v = *(const float4*)(Bp + (long)(k0 + k) * ldb + n0 + nc * 8);
            const __half* hv = (const __half*)&v;
            #pragma unroll
            for (int jj = 0; jj < 8; jj++) Bs[nc * 8 + jj][k] = hv[jj];
        }
        __syncthreads();

        f16x8 af[4], bf[2];
        #pragma unroll
        for (int mf = 0; mf < 4; mf++)
            af[mf] = *(const f16x8*)&As[wm * 64 + mf * 16 + lr][lq * 8];
        #pragma unroll
        for (int nf = 0; nf < 2; nf++)
            bf[nf] = *(const f16x8*)&Bs[wn * 32 + nf * 16 + lr][lq * 8];
        #pragma unroll
        for (int mf = 0; mf < 4; mf++)
            #pragma unroll
            for (int nf = 0; nf < 2; nf++)
                acc[mf][nf] = __builtin_amdgcn_mfma_f32_16x16x32_f16(af[mf], bf[nf], acc[mf][nf], 0, 0, 0);
        __syncthreads();
    }

    #pragma unroll
    for (int mf = 0; mf < 4; mf++) {
        #pragma unroll
        for (int nf = 0; nf < 2; nf++) {
            #pragma unroll
            for (int j = 0; j < 4; j++) {
                int m = m0 + wm * 64 + mf * 16 + lq * 4 + j;
                int n = n0 + wn * 32 + nf * 16 + lr;
                float v = acc[mf][nf][j];
                if (bias) v += bias[n];
                if (d0v)  v += d0v[(long)bz * M + m] * rootv[n];
                if (act == 1)      v = tanhf(v);
                else if (act == 2) v = (m == n) ? 0.f : expf(v);
                Cg[(long)bz * sC + (long)m * ldc + n] = __float2half(v);
            }
        }
    }
}

// ============ final: out = tanh(vs@W1^T + p@W2^T + c@W3^T + br) * mask ============
__global__ __launch_bounds__(256)
void mgemm_final(const half_t* __restrict__ A0, const half_t* __restrict__ A1,
                 const half_t* __restrict__ A2, const half_t* __restrict__ Bw,
                 float* __restrict__ Cout, const float* __restrict__ bias,
                 const float* __restrict__ maskp)
{
    __shared__ __half As[128][40];
    __shared__ __half Bs[64][40];
    const int m0 = blockIdx.y * 128, n0 = blockIdx.x * 64;
    const int tid = threadIdx.x;
    const int l = tid & 63, w = tid >> 6;
    const int wm = w & 1, wn = w >> 1;
    const int lr = l & 15, lq = l >> 4;

    f32x4 acc[4][2] = {};

    for (int k0 = 0; k0 < 1536; k0 += 32) {
        const half_t* A = (k0 < 512) ? A0 : (k0 < 1024) ? A1 : A2;
        const int kk = k0 & 511;
        #pragma unroll
        for (int i = 0; i < 2; i++) {
            int ch = tid + i * 256;
            int r = ch >> 2, j = ch & 3;
            *(float4*)&As[r][j * 8] = *(const float4*)(A + (long)(m0 + r) * 512 + kk + j * 8);
        }
        {
            int r = tid >> 2, j = tid & 3;
            *(float4*)&Bs[r][j * 8] = *(const float4*)(Bw + (long)(n0 + r) * 1536 + k0 + j * 8);
        }
        __syncthreads();
        f16x8 af[4], bf[2];
        #pragma unroll
        for (int mf = 0; mf < 4; mf++)
            af[mf] = *(const f16x8*)&As[wm * 64 + mf * 16 + lr][lq * 8];
        #pragma unroll
        for (int nf = 0; nf < 2; nf++)
            bf[nf] = *(const f16x8*)&Bs[wn * 32 + nf * 16 + lr][lq * 8];
        #pragma unroll
        for (int mf = 0; mf < 4; mf++)
            #pragma unroll
            for (int nf = 0; nf < 2; nf++)
                acc[mf][nf] = __builtin_amdgcn_mfma_f32_16x16x32_f16(af[mf], bf[nf], acc[mf][nf], 0, 0, 0);
        __syncthreads();
    }

    #pragma unroll
    for (int mf = 0; mf < 4; mf++) {
        #pragma unroll
        for (int nf = 0; nf < 2; nf++) {
            #pragma unroll
            for (int j = 0; j < 4; j++) {
                int m = m0 + wm * 64 + mf * 16 + lq * 4 + j;
                int n = n0 + wn * 32 + nf * 16 + lr;
                float v = tanhf(acc[mf][nf][j] + bias[n]) * maskp[m];
                Cout[(long)m * 512 + n] = v;
            }
        }
    }
}

// ======= G[ts][d][gate][b] = Wp[gate][:]@x[b][:,t] + bp : A=Wp(M=gates), B=x(N=batch) =======
__global__ __launch_bounds__(256)
void ggemm(const float* __restrict__ x, const half_t* __restrict__ Wp,
           const float* __restrict__ bp, half_t* __restrict__ G, int chunk)
{
    __shared__ __half As[128][40];
    __shared__ __half Bs[128][40];
    const int d = blockIdx.z;
    const int ts = blockIdx.y;
    const int m0 = blockIdx.x * 128;                 // gate rows
    const int t_orig = d ? (255 - (chunk * 128 + ts)) : (chunk * 128 + ts);
    const int tid = threadIdx.x;
    const int l = tid & 63, w = tid >> 6;
    const int wm = w & 1, wn = w >> 1;
    const int lr = l & 15, lq = l >> 4;

    f32x4 acc[4][4] = {};

    for (int k0 = 0; k0 < 320; k0 += 32) {
        #pragma unroll
        for (int i = 0; i < 2; i++) {
            int e = tid + i * 256;
            int r = e >> 2, j = (e & 3) * 8;
            *(float4*)&As[r][j] = *(const float4*)(Wp + ((long)d * 1536 + m0 + r) * 320 + k0 + j);
        }
        #pragma unroll
        for (int i = 0; i < 2; i++) {
            int e = tid + i * 256;
            int r = e >> 2, j = (e & 3) * 8;          // b row, k offset
            int k = k0 + j;
            int ka = (k + 4 <= 300) ? k : 0;          // W zero-padded past 300
            int kb = (k + 8 <= 300) ? k + 4 : 0;
            const float* xp = x + ((long)r * 256 + t_orig) * 300;
            float4 va = *(const float4*)(xp + ka);
            float4 vb = *(const float4*)(xp + kb);
            __half* q = &Bs[r][j];
            q[0] = __float2half(va.x); q[1] = __float2half(va.y);
            q[2] = __float2half(va.z); q[3] = __float2half(va.w);
            q[4] = __float2half(vb.x); q[5] = __float2half(vb.y);
            q[6] = __float2half(vb.z); q[7] = __float2half(vb.w);
        }
        __syncthreads();
        f16x8 af[4], bf[4];
        #pragma unroll
        for (int gf = 0; gf < 4; gf++)
            af[gf] = *(const f16x8*)&As[wm * 64 + gf * 16 + lr][lq * 8];
        #pragma unroll
        for (int bi = 0; bi < 4; bi++)
            bf[bi] = *(const f16x8*)&Bs[wn * 64 + bi * 16 + lr][lq * 8];
        #pragma unroll
        for (int gf = 0; gf < 4; gf++)
            #pragma unroll
            for (int bi = 0; bi < 4; bi++)
                acc[gf][bi] = __builtin_amdgcn_mfma_f32_16x16x32_f16(af[gf], bf[bi], acc[gf][bi], 0, 0, 0);
        __syncthreads();
    }

    half_t* Gt = G + (long)(ts * 2 + d) * 1536 * 128;
    #pragma unroll
    for (int gf = 0; gf < 4; gf++) {
        #pragma unroll
        for (int bi = 0; bi < 4; bi++) {
            #pragma unroll
            for (int j = 0; j < 4; j++) {
                int g = m0 + wm * 64 + gf * 16 + lq * 4 + j;
                int b = wn * 64 + bi * 16 + lr;
                Gt[(long)g * 128 + b] = __float2half(acc[gf][bi][j] + bp[d * 1536 + g]);
            }
        }
    }
}

// ======= persistent BiLSTM scan: 96 WGs = d(2) x ntile(24) x btile(2); 128 steps =======
// gates[g][b] = Whh_slice(LDS) @ h ; all 4 gates of one hd land in one lane's acc regs.
__global__ __launch_bounds__(256)
void lstm_scan(const half_t* __restrict__ G, const half_t* __restrict__ Whh,
               half_t* __restrict__ Hbuf, float* __restrict__ Cbuf,
               half_t* __restrict__ vs, half_t* __restrict__ vst,
               unsigned* __restrict__ ctr, int chunk)
{
    __shared__ __half Wl[64 * 392];
    __shared__ __half Bs[2][64][40];

    const int bid = blockIdx.x;
    const int d = bid / 48, rem = bid % 48;
    const int ntile = rem >> 1, btile = rem & 1;
    const int tid = threadIdx.x;
    const int l = tid & 63, w = tid >> 6;
    const int wm = w & 1, wn = w >> 1;
    const int lr = l & 15, lq = l >> 4;
    const unsigned nwg = gridDim.x;

    // stage Whh slice once: 64 packed-gate rows x 384 (padded stride 392)
    {
        const half_t* src = Whh + ((long)d * 1536 + ntile * 64) * 384;
        for (int e = tid; e < 3072; e += 256) {
            int r = e / 48, c = (e % 48) * 8;
            *(float4*)&Wl[r * 392 + c] = *(const float4*)(src + (long)r * 384 + c);
        }
    }

    for (int s = 0; s < 128; ++s) {
        const int gstep = chunk * 128 + s;
        const int p = gstep & 1;
        const half_t* hsrc = Hbuf + (long)(p * 2 + d) * 384 * 128 + btile * 64;

        {   // prologue: stage k-rows 0..31 into Bs[0]  (transpose [hd][b] -> [b][k])
            int r = tid >> 3, c8 = (tid & 7) * 8;
            float4 v = *(const float4*)(hsrc + (long)r * 128 + c8);
            const __half* hv = (const __half*)&v;
            #pragma unroll
            for (int i2 = 0; i2 < 8; i2++) Bs[0][c8 + i2][r] = hv[i2];
        }

        f32x4 acc[2][2] = {};
        #pragma unroll 2
        for (int it = 0; it < 12; ++it) {
            __syncthreads();
            const int cur = it & 1;
            f16x8 af[2], bfr[2];
            #pragma unroll
            for (int gf = 0; gf < 2; gf++)
                af[gf] = *(const f16x8*)&Wl[(wm * 32 + gf * 16 + lr) * 392 + it * 32 + lq * 8];
            #pragma unroll
            for (int bf2 = 0; bf2 < 2; bf2++)
                bfr[bf2] = *(const f16x8*)&Bs[cur][wn * 32 + bf2 * 16 + lr][lq * 8];
            if (it < 11) {
                int r = tid >> 3, c8 = (tid & 7) * 8;
                float4 v = *(const float4*)(hsrc + (long)((it + 1) * 32 + r) * 128 + c8);
                const __half* hv = (const __half*)&v;
                #pragma unroll
                for (int i2 = 0; i2 < 8; i2++) Bs[cur ^ 1][c8 + i2][r] = hv[i2];
            }
            #pragma unroll
            for (int gf = 0; gf < 2; gf++)
                #pragma unroll
                for (int bf2 = 0; bf2 < 2; bf2++)
                    acc[gf][bf2] = __builtin_amdgcn_mfma_f32_16x16x32_f16(af[gf], bfr[bf2], acc[gf][bf2], 0, 0, 0);
        }

        // epilogue: gates q=0..3 of one hd are acc[..][..][0..3] in this lane
        const int t_orig = d ? 255 - gstep : gstep;
        const half_t* gp = G + ((long)(s * 2 + d) * 1536 + ntile * 64) * 128 + btile * 64;
        #pragma unroll
        for (int gf = 0; gf < 2; gf++) {
            #pragma unroll
            for (int bf2 = 0; bf2 < 2; bf2++) {
                const int gl_ = wm * 32 + gf * 16 + lq * 4;
                const int bl_ = wn * 32 + bf2 * 16 + lr;
                const int hd = ntile * 16 + (gl_ >> 2);
                const int bg = btile * 64 + bl_;
                float gi = acc[gf][bf2][0] + __half2float(gp[(long)(gl_ + 0) * 128 + bl_]);
                float gfo = acc[gf][bf2][1] + __half2float(gp[(long)(gl_ + 1) * 128 + bl_]);
                float gg = acc[gf][bf2][2] + __half2float(gp[(long)(gl_ + 2) * 128 + bl_]);
                float go = acc[gf][bf2][3] + __half2float(gp[(long)(gl_ + 3) * 128 + bl_]);
                long cidx = ((long)d * 384 + hd) * 128 + bg;
                float c = Cbuf[cidx];
                float si = 1.f / (1.f + expf(-gi));
                float sf = 1.f / (1.f + expf(-gfo));
                float so = 1.f / (1.f + expf(-go));
                c = sf * c + si * tanhf(gg);
                float h = so * tanhf(c);
                Cbuf[cidx] = c;
                Hbuf[((long)((p ^ 1) * 2 + d) * 384 + hd) * 128 + bg] = __float2half(h);
                long m = (long)bg * 256 + t_orig;
                if (hd < 256) vs [m * 512 + d * 256 + hd]       = __float2half(h);
                else          vst[m * 256 + d * 128 + hd - 256] = __float2half(h);
            }
        }

        if (s < 127) {   // grid barrier (device-scope, monotonic counter)
            __syncthreads();
            if (tid == 0) {
                __threadfence();
                __hip_atomic_fetch_add(ctr, 1u, __ATOMIC_ACQ_REL, __HIP_MEMORY_SCOPE_AGENT);
                unsigned tgt = nwg * (unsigned)(s + 1);
                while (__hip_atomic_load(ctr, __ATOMIC_ACQUIRE, __HIP_MEMORY_SCOPE_AGENT) < tgt)
                    __builtin_amdgcn_s_sleep(1);
                __threadfence();
            }
            __syncthreads();
        }
    }
}

// ---------------- packs / converts ----------------
__global__ void pack_wih(const float* __restrict__ wf, const float* __restrict__ wb,
                         const float* __restrict__ bfv, const float* __restrict__ bbv,
                         half_t* __restrict__ Wp, float* __restrict__ bp)
{
    int i = blockIdx.x * 256 + threadIdx.x;
    if (i < 983040) {
        int k = i % 320, pr = (i / 320) % 1536, d = i / 491520;
        int q = pr & 3, hd = pr >> 2;
        float v = (k < 300) ? (d ? wb : wf)[(q * 384 + hd) * 300 + k] : 0.f;
        Wp[i] = __float2half(v);
    }
    if (i < 3072) {
        int d = i / 1536, pr = i % 1536;
        int q = pr & 3, hd = pr >> 2;
        bp[i] = (d ? bbv : bfv)[q * 384 + hd];
    }
}
__global__ void pack_whh(const float* __restrict__ wf, const float* __restrict__ wb,
                         half_t* __restrict__ Wh)
{
    int i = blockIdx.x * 256 + threadIdx.x;
    if (i >= 1179648) return;
    int k = i % 384, pr = (i / 384) % 1536, d = i / 589824;
    int q = pr & 3, hd = pr >> 2;
    Wh[i] = __float2half((d ? wb : wf)[(q * 384 + hd) * 384 + k]);
}
__global__ void conv16(const float* __restrict__ s, half_t* __restrict__ d, long n)
{
    long i = (long)blockIdx.x * 256 + threadIdx.x;
    if (i < n) d[i] = __float2half(s[i]);
}
__global__ void convT16(const float* __restrict__ s, half_t* __restrict__ d, int R, int C)
{
    int i = blockIdx.x * 256 + threadIdx.x;
    if (i >= R * C) return;
    int r = i / C, c = i % C;
    d[(long)c * R + r] = __float2half(s[i]);
}

// ---------------- f_r = exp(vst @ w_root^T) ----------------
__global__ __launch_bounds__(256)
void frow_kernel(const half_t* __restrict__ vst, const float* __restrict__ wroot,
                 float* __restrict__ fr)
{
    int row  = blockIdx.x * 4 + (threadIdx.x >> 6);
    int lane = threadIdx.x & 63;
    const half_t* v = vst + (long)row * 256;
    float s = 0.f;
    for (int k = lane; k < 256; k += 64) s += __half2float(v[k]) * wroot[k];
    #pragma unroll
    for (int off = 32; off; off >>= 1) s += __shfl_down(s, off);
    if (lane == 0) fr[row] = expf(s);
}

// ---------------- register-resident Gauss-Jordan inverse (256x256) ----------------
__global__ __launch_bounds__(512)
void invert_gj(const half_t* __restrict__ fA, const float* __restrict__ fr,
               half_t* __restrict__ LLinv)
{
    __shared__ float colbuf[256];
    __shared__ float rowbuf[256];
    __shared__ float csum[2][256];
    const int bz = blockIdx.x;
    const half_t* A = fA + (long)bz * 65536;
    const int tid = threadIdx.x;
    const int c = tid & 255, rh = tid >> 8;
    float m[128];

    float s = 0.f;
    #pragma unroll
    for (int i = 0; i < 128; i++) {
        float v = __half2float(A[(long)(rh * 128 + i) * 256 + c]);
        m[i] = v; s += v;
    }
    csum[rh][c] = s;
    __syncthreads();
    float diag = csum[0][c] + csum[1][c];
    const float frv = fr[bz * 256 + c];
    #pragma unroll
    for (int i = 0; i < 128; i++) {
        int r = rh * 128 + i;
        float v = (r == c) ? ((diag == 0.f) ? 1.f : diag) : -m[i];
        if (i == 0 && rh == 0) {
            v = frv;
            if (c == 0 && v == 0.f) v = 1.f;
        }
        m[i] = v;
    }
    __syncthreads();

    for (int k = 0; k < 256; k++) {
        const int kh = k >> 7, kl = k & 127;
        if (c == k) {
            #pragma unroll
            for (int i = 0; i < 128; i++) colbuf[rh * 128 + i] = m[i];
        }
        if (rh == kh) {
            float pv = 0.f;
            #pragma unroll
            for (int i = 0; i < 128; i++) pv = (i == kl) ? m[i] : pv;
            rowbuf[c] = pv;
        }
        __syncthreads();
        const float p    = colbuf[k];
        const float pinv = 1.f / p;
        const float rv   = rowbuf[c] * pinv;
        if (c == k) {
            #pragma unroll
            for (int i = 0; i < 128; i++) {
                int r = rh * 128 + i;
                m[i] = (r == k) ? pinv : -colbuf[r] * pinv;
            }
        } else {
            #pragma unroll
            for (int i = 0; i < 128; i++) {
                int r = rh * 128 + i;
                float nv = m[i] - colbuf[r] * rv;
                m[i] = (r == k) ? rv : nv;
            }
        }
        __syncthreads();
    }

    #pragma unroll
    for (int i = 0; i < 128; i++)
        LLinv[(long)bz * 65536 + (long)(rh * 128 + i) * 256 + c] = __float2half(m[i]);
}

// ---------------- diag(LLinv) and d0 ----------------
__global__ void diag_d0_k(const half_t* __restrict__ LLinv, const float* __restrict__ fr,
                          float* __restrict__ diagv, float* __restrict__ d0)
{
    int i = blockIdx.x * 256 + threadIdx.x;
    if (i >= 32768) return;
    int b = i >> 8, s = i & 255;
    diagv[i] = __half2float(LLinv[(long)b * 65536 + s * 257]);
    d0[i]    = fr[i] * __half2float(LLinv[(long)b * 65536 + s * 256]);
}

// ---------------- a = A*(diag - LLinv^T), in place ----------------
__global__ __launch_bounds__(256)
void assemble_a(half_t* __restrict__ fA, const half_t* __restrict__ LLinv,
                const float* __restrict__ diagv)
{
    __shared__ float ll[32][33];
    const int bz = blockIdx.z;
    const int s0 = (blockIdx.x >> 3) * 32, t0 = (blockIdx.x & 7) * 32;
    const int tid = threadIdx.x;
    const long base = (long)bz * 65536;
    #pragma unroll
    for (int it = 0; it < 4; it++) {
        int i = (tid >> 5) + it * 8, j = tid & 31;
        ll[i][j] = __half2float(LLinv[base + (long)(t0 + i) * 256 + (s0 + j)]);
    }
    __syncthreads();
    #pragma unroll
    for (int it = 0; it < 4; it++) {
        int si = (tid >> 5) + it * 8, tj = tid & 31;
        int s = s0 + si, t = t0 + tj;
        long idx = base + (long)s * 256 + t;
        float Av = __half2float(fA[idx]);
        float t1 = (t > 0) ? diagv[(bz << 8) + t] : 0.f;
        float t2 = (s > 0) ? ll[tj][si] : 0.f;
        fA[idx] = __float2half(Av * (t1 - t2));
    }
}

// ---------------- batched 256x256 f16 transpose ----------------
__global__ __launch_bounds__(256)
void transpose256h(const half_t* __restrict__ in, half_t* __restrict__ out)
{
    __shared__ __half tb[32][33];
    const int bz = blockIdx.z;
    const half_t* ip = in  + (long)bz * 65536;
    half_t*       op = out + (long)bz * 65536;
    int x0 = blockIdx.x * 32, y0 = blockIdx.y * 32;
    int tx = threadIdx.x, ty = threadIdx.y;
    #pragma unroll
    for (int r = 0; r < 4; r++)
        tb[ty + 8 * r][tx] = ip[(long)(y0 + ty + 8 * r) * 256 + x0 + tx];
    __syncthreads();
    #pragma unroll
    for (int r = 0; r < 4; r++)
        op[(long)(x0 + ty + 8 * r) * 256 + y0 + tx] = tb[tx][ty + 8 * r];
}

// ---------------- emb = max over sequence (coalesced) ----------------
__global__ __launch_bounds__(256)
void emb_max(const float* __restrict__ outp, float* __restrict__ emb)
{
    int b = blockIdx.x;
    for (int n = threadIdx.x; n < 512; n += 256) {
        const float* p = outp + (long)b * 131072 + n;
        float mx = -3.4e38f;
        for (int t = 0; t < 256; t++) mx = fmaxf(mx, p[(long)t * 512]);
        emb[b * 512 + n] = mx;
    }
}

__global__ void diag_ws(float* out, int n, float v)
{
    int i = blockIdx.x * 256 + threadIdx.x;
    if (i < n) out[i] = v;
}

// ======================= host launch =======================
extern "C" void kernel_launch(void* const* d_in, const int* in_sizes, int n_in,
                              void* d_out, int out_size, void* d_ws, size_t ws_size,
                              hipStream_t stream)
{
    const float* x     = (const float*)d_in[0];
    const float* mask  = (const float*)d_in[1];
    const float* wihf  = (const float*)d_in[2];
    const float* whhf  = (const float*)d_in[3];
    const float* bf    = (const float*)d_in[4];
    const float* wihb  = (const float*)d_in[5];
    const float* whhb  = (const float*)d_in[6];
    const float* bb    = (const float*)d_in[7];
    const float* wtp   = (const float*)d_in[8];
    const float* btp   = (const float*)d_in[9];
    const float* wtc   = (const float*)d_in[10];
    const float* btc   = (const float*)d_in[11];
    const float* wa    = (const float*)d_in[12];
    const float* wroot = (const float*)d_in[13];
    const float* remb  = (const float*)d_in[14];
    const float* wr    = (const float*)d_in[15];
    const float* br    = (const float*)d_in[16];

    if (ws_size < 134217728ULL) {
        float enc = 100.0f + (float)((double)ws_size * 1e-9);
        diag_ws<<<dim3((out_size + 255) / 256), 256, 0, stream>>>((float*)d_out, out_size, enc);
        return;
    }

    char* ws = (char*)d_ws;
    half_t* G     = (half_t*)(ws + 0);              // 100,663,296 B per-chunk gates
    half_t* vs    = (half_t*)(ws + 100663296);      // 33,554,432 B
    half_t* tp    = (half_t*)(ws + 0 * SEG);        // post-scan overlays of G region
    half_t* tc    = (half_t*)(ws + 1 * SEG);
    half_t* tmp   = (half_t*)(ws + 2 * SEG);
    half_t* fA    = (half_t*)(ws + 3 * SEG);
    half_t* LL    = (half_t*)(ws + 4 * SEG);
    half_t* aT    = (half_t*)(ws + 5 * SEG);
    half_t* cbuf  = (half_t*)(ws + 0 * SEG);
    half_t* pbuf  = (half_t*)(ws + 2 * SEG);
    half_t* wr16  = (half_t*)(ws + 4 * SEG);

    // dead-until-final region of d_out hosts scan state + small weights
    float* ob = (float*)d_out;
    half_t*   Wp16  = (half_t*)(ob + 11000000);   // 983,040 f16
    half_t*   Whh16 = (half_t*)(ob + 11491520);   // 1,179,648 f16
    float*    bp    = ob + 12081344;
    half_t*   wtp16 = (half_t*)(ob + 12084416);
    half_t*   wtc16 = (half_t*)(ob + 12117184);
    half_t*   wa16T = (half_t*)(ob + 12149952);
    float*    fr    = ob + 12182720;
    float*    d0    = ob + 12215488;
    float*    diagv = ob + 12248256;
    float*    Cbuf  = ob + 12281024;              // [2][384][128] f32
    half_t*   Hbuf  = (half_t*)(ob + 12379328);   // [2][2][384][128] f16
    unsigned* ctrs  = (unsigned*)(ob + 12500000); // 2 barrier counters
    half_t*   vst   = (half_t*)(ob + 12648448);   // 32768 x 256 f16

    float* emb  = (float*)d_out;
    float* outp = (float*)d_out + 65536;

    // 0. init state + pack weights
    hipMemsetAsync(Cbuf, 0, 393216, stream);
    hipMemsetAsync(Hbuf, 0, 393216, stream);
    hipMemsetAsync(ctrs, 0, 8, stream);
    pack_wih<<<dim3(3840), 256, 0, stream>>>(wihf, wihb, bf, bb, Wp16, bp);
    pack_whh<<<dim3(4608), 256, 0, stream>>>(whhf, whhb, Whh16);
    conv16<<<dim3(256), 256, 0, stream>>>(wtp, wtp16, 65536);
    conv16<<<dim3(256), 256, 0, stream>>>(wtc, wtc16, 65536);
    convT16<<<dim3(256), 256, 0, stream>>>(wa, wa16T, 256, 256);

    // 1. chunked: G GEMM + persistent 128-step scan, twice
    for (int c = 0; c < 2; c++) {
        ggemm<<<dim3(12, 128, 2), 256, 0, stream>>>(x, Wp16, bp, G, c);
        lstm_scan<<<dim3(96), 256, 0, stream>>>(G, Whh16, Hbuf, Cbuf, vs, vst, ctrs + c, c);
    }

    // 2. f_r
    frow_kernel<<<dim3(8192), 256, 0, stream>>>(vst, wroot, fr);

    // 3. tp / tc = tanh(vst @ W^T + b)
    mgemm<false><<<dim3(4, 256, 1), 256, 0, stream>>>(
        vst, wtp16, tp, M_, 256, 256, 256, 256, 256, 0, 0, 0, btp, 1, nullptr, nullptr);
    mgemm<false><<<dim3(4, 256, 1), 256, 0, stream>>>(
        vst, wtc16, tc, M_, 256, 256, 256, 256, 256, 0, 0, 0, btc, 1, nullptr, nullptr);

    // 4. tmp = tp @ w_a
    mgemm<false><<<dim3(4, 256, 1), 256, 0, stream>>>(
        tp, wa16T, tmp, M_, 256, 256, 256, 256, 256, 0, 0, 0, nullptr, 0, nullptr, nullptr);

    // 5. f = exp(tmp @ tc^T), diag zeroed (batched)
    mgemm<false><<<dim3(4, 2, 128), 256, 0, stream>>>(
        tmp, tc, fA, 256, 256, 256, 256, 256, 256, 65536, 65536, 65536,
        nullptr, 2, nullptr, nullptr);

    // 6-8. inverse, diag/d0, assemble
    invert_gj<<<dim3(128), 512, 0, stream>>>(fA, fr, LL);
    diag_d0_k<<<dim3(128), 256, 0, stream>>>(LL, fr, diagv, d0);
    assemble_a<<<dim3(64, 1, 128), 256, 0, stream>>>(fA, LL, diagv);

    // 9. wr -> f16 (LL dead now)
    conv16<<<dim3(3072), 256, 0, stream>>>(wr, wr16, 786432);

    // 10. aT
    transpose256h<<<dim3(8, 8, 128), dim3(32, 8), 0, stream>>>(fA, aT);

    // 11. c = a @ vs
    mgemm<true><<<dim3(8, 2, 128), 256, 0, stream>>>(
        fA, vs, cbuf, 256, 512, 256, 256, 512, 512, 65536, 131072, 131072,
        nullptr, 0, nullptr, nullptr);

    // 12. p = aT @ vs + d0 (x) root_emb
    mgemm<true><<<dim3(8, 2, 128), 256, 0, stream>>>(
        aT, vs, pbuf, 256, 512, 256, 256, 512, 512, 65536, 131072, 131072,
        nullptr, 0, d0, remb);

    // 13. out = tanh([vs|p|c] @ wr^T + br) * mask
    mgemm_final<<<dim3(8, 256, 1), 256, 0, stream>>>(vs, pbuf, cbuf, wr16, outp, br, mask);

    // 14. emb
    emb_max<<<dim3(128), 256, 0, stream>>>(outp, emb);
}

// Round 6
// 5256.988 us; speedup vs baseline: 3.9467x; 1.4578x over previous
//
#include <hip/hip_runtime.h>
#include <hip/hip_fp16.h>
#include <math.h>

#define B_    128
#define S_    256
#define WORD_ 300
#define HD_   384
#define M_    32768
#define STRU_ 256
#define SEMA_ 512
#define SEG   16777216L

typedef __half half_t;
typedef _Float16 f16x8 __attribute__((ext_vector_type(8)));
typedef float    f32x4 __attribute__((ext_vector_type(4)));

// ================= MFMA GEMM: C(f16) = act(A @ B(.T) + bias + d0*root) =================
template<bool BNN>
__global__ __launch_bounds__(256)
void mgemm(const half_t* __restrict__ Ag, const half_t* __restrict__ Bg,
           half_t* __restrict__ Cg,
           int M, int N, int K, int lda, int ldb, int ldc,
           long sA, long sB, long sC,
           const float* __restrict__ bias, int act,
           const float* __restrict__ d0v, const float* __restrict__ rootv)
{
    __shared__ __half As[128][40];
    __shared__ __half Bs[64][40];
    const int bz = blockIdx.z;
    const half_t* A  = Ag + (long)bz * sA;
    const half_t* Bp = Bg + (long)bz * sB;
    const int m0 = blockIdx.y * 128, n0 = blockIdx.x * 64;
    const int tid = threadIdx.x;
    const int l = tid & 63, w = tid >> 6;
    const int wm = w & 1, wn = w >> 1;
    const int lr = l & 15, lq = l >> 4;

    f32x4 acc[4][2] = {};

    for (int k0 = 0; k0 < K; k0 += 32) {
        #pragma unroll
        for (int i = 0; i < 2; i++) {
            int ch = tid + i * 256;
            int r = ch >> 2, j = ch & 3;
            *(float4*)&As[r][j * 8] = *(const float4*)(A + (long)(m0 + r) * lda + k0 + j * 8);
        }
        if (!BNN) {
            int r = tid >> 2, j = tid & 3;
            *(float4*)&Bs[r][j * 8] = *(const float4*)(Bp + (long)(n0 + r) * ldb + k0 + j * 8);
        } else {
            int k = tid & 31, nc = tid >> 5;
            float4 v = *(const float4*)(Bp + (long)(k0 + k) * ldb + n0 + nc * 8);
            const __half* hv = (const __half*)&v;
            #pragma unroll
            for (int jj = 0; jj < 8; jj++) Bs[nc * 8 + jj][k] = hv[jj];
        }
        __syncthreads();

        f16x8 af[4], bf[2];
        #pragma unroll
        for (int mf = 0; mf < 4; mf++)
            af[mf] = *(const f16x8*)&As[wm * 64 + mf * 16 + lr][lq * 8];
        #pragma unroll
        for (int nf = 0; nf < 2; nf++)
            bf[nf] = *(const f16x8*)&Bs[wn * 32 + nf * 16 + lr][lq * 8];
        #pragma unroll
        for (int mf = 0; mf < 4; mf++)
            #pragma unroll
            for (int nf = 0; nf < 2; nf++)
                acc[mf][nf] = __builtin_amdgcn_mfma_f32_16x16x32_f16(af[mf], bf[nf], acc[mf][nf], 0, 0, 0);
        __syncthreads();
    }

    #pragma unroll
    for (int mf = 0; mf < 4; mf++) {
        #pragma unroll
        for (int nf = 0; nf < 2; nf++) {
            #pragma unroll
            for (int j = 0; j < 4; j++) {
                int m = m0 + wm * 64 + mf * 16 + lq * 4 + j;
                int n = n0 + wn * 32 + nf * 16 + lr;
                float v = acc[mf][nf][j];
                if (bias) v += bias[n];
                if (d0v)  v += d0v[(long)bz * M + m] * rootv[n];
                if (act == 1)      v = tanhf(v);
                else if (act == 2) v = (m == n) ? 0.f : expf(v);
                Cg[(long)bz * sC + (long)m * ldc + n] = __float2half(v);
            }
        }
    }
}

// ============ final: out = tanh(vs@W1^T + p@W2^T + c@W3^T + br) * mask ============
__global__ __launch_bounds__(256)
void mgemm_final(const half_t* __restrict__ A0, const half_t* __restrict__ A1,
                 const half_t* __restrict__ A2, const half_t* __restrict__ Bw,
                 float* __restrict__ Cout, const float* __restrict__ bias,
                 const float* __restrict__ maskp)
{
    __shared__ __half As[128][40];
    __shared__ __half Bs[64][40];
    const int m0 = blockIdx.y * 128, n0 = blockIdx.x * 64;
    const int tid = threadIdx.x;
    const int l = tid & 63, w = tid >> 6;
    const int wm = w & 1, wn = w >> 1;
    const int lr = l & 15, lq = l >> 4;

    f32x4 acc[4][2] = {};

    for (int k0 = 0; k0 < 1536; k0 += 32) {
        const half_t* A = (k0 < 512) ? A0 : (k0 < 1024) ? A1 : A2;
        const int kk = k0 & 511;
        #pragma unroll
        for (int i = 0; i < 2; i++) {
            int ch = tid + i * 256;
            int r = ch >> 2, j = ch & 3;
            *(float4*)&As[r][j * 8] = *(const float4*)(A + (long)(m0 + r) * 512 + kk + j * 8);
        }
        {
            int r = tid >> 2, j = tid & 3;
            *(float4*)&Bs[r][j * 8] = *(const float4*)(Bw + (long)(n0 + r) * 1536 + k0 + j * 8);
        }
        __syncthreads();
        f16x8 af[4], bf[2];
        #pragma unroll
        for (int mf = 0; mf < 4; mf++)
            af[mf] = *(const f16x8*)&As[wm * 64 + mf * 16 + lr][lq * 8];
        #pragma unroll
        for (int nf = 0; nf < 2; nf++)
            bf[nf] = *(const f16x8*)&Bs[wn * 32 + nf * 16 + lr][lq * 8];
        #pragma unroll
        for (int mf = 0; mf < 4; mf++)
            #pragma unroll
            for (int nf = 0; nf < 2; nf++)
                acc[mf][nf] = __builtin_amdgcn_mfma_f32_16x16x32_f16(af[mf], bf[nf], acc[mf][nf], 0, 0, 0);
        __syncthreads();
    }

    #pragma unroll
    for (int mf = 0; mf < 4; mf++) {
        #pragma unroll
        for (int nf = 0; nf < 2; nf++) {
            #pragma unroll
            for (int j = 0; j < 4; j++) {
                int m = m0 + wm * 64 + mf * 16 + lq * 4 + j;
                int n = n0 + wn * 32 + nf * 16 + lr;
                float v = tanhf(acc[mf][nf][j] + bias[n]) * maskp[m];
                Cout[(long)m * 512 + n] = v;
            }
        }
    }
}

// ======= G[ts][d][gate][b] = Wp[gate][:]@x[b][:,t] + bp : A=Wp(M=gates), B=x(N=batch) =======
__global__ __launch_bounds__(256)
void ggemm(const float* __restrict__ x, const half_t* __restrict__ Wp,
           const float* __restrict__ bp, half_t* __restrict__ G, int chunk)
{
    __shared__ __half As[128][40];
    __shared__ __half Bs[128][40];
    const int d = blockIdx.z;
    const int ts = blockIdx.y;
    const int m0 = blockIdx.x * 128;                 // gate rows
    const int t_orig = d ? (255 - (chunk * 128 + ts)) : (chunk * 128 + ts);
    const int tid = threadIdx.x;
    const int l = tid & 63, w = tid >> 6;
    const int wm = w & 1, wn = w >> 1;
    const int lr = l & 15, lq = l >> 4;

    f32x4 acc[4][4] = {};

    for (int k0 = 0; k0 < 320; k0 += 32) {
        #pragma unroll
        for (int i = 0; i < 2; i++) {
            int e = tid + i * 256;
            int r = e >> 2, j = (e & 3) * 8;
            *(float4*)&As[r][j] = *(const float4*)(Wp + ((long)d * 1536 + m0 + r) * 320 + k0 + j);
        }
        #pragma unroll
        for (int i = 0; i < 2; i++) {
            int e = tid + i * 256;
            int r = e >> 2, j = (e & 3) * 8;          // b row, k offset
            int k = k0 + j;
            int ka = (k + 4 <= 300) ? k : 0;          // W zero-padded past 300
            int kb = (k + 8 <= 300) ? k + 4 : 0;
            const float* xp = x + ((long)r * 256 + t_orig) * 300;
            float4 va = *(const float4*)(xp + ka);
            float4 vb = *(const float4*)(xp + kb);
            __half* q = &Bs[r][j];
            q[0] = __float2half(va.x); q[1] = __float2half(va.y);
            q[2] = __float2half(va.z); q[3] = __float2half(va.w);
            q[4] = __float2half(vb.x); q[5] = __float2half(vb.y);
            q[6] = __float2half(vb.z); q[7] = __float2half(vb.w);
        }
        __syncthreads();
        f16x8 af[4], bf[4];
        #pragma unroll
        for (int gf = 0; gf < 4; gf++)
            af[gf] = *(const f16x8*)&As[wm * 64 + gf * 16 + lr][lq * 8];
        #pragma unroll
        for (int bi = 0; bi < 4; bi++)
            bf[bi] = *(const f16x8*)&Bs[wn * 64 + bi * 16 + lr][lq * 8];
        #pragma unroll
        for (int gf = 0; gf < 4; gf++)
            #pragma unroll
            for (int bi = 0; bi < 4; bi++)
                acc[gf][bi] = __builtin_amdgcn_mfma_f32_16x16x32_f16(af[gf], bf[bi], acc[gf][bi], 0, 0, 0);
        __syncthreads();
    }

    half_t* Gt = G + (long)(ts * 2 + d) * 1536 * 128;
    #pragma unroll
    for (int gf = 0; gf < 4; gf++) {
        #pragma unroll
        for (int bi = 0; bi < 4; bi++) {
            #pragma unroll
            for (int j = 0; j < 4; j++) {
                int g = m0 + wm * 64 + gf * 16 + lq * 4 + j;
                int b = wn * 64 + bi * 16 + lr;
                Gt[(long)g * 128 + b] = __float2half(acc[gf][bi][j] + bp[d * 1536 + g]);
            }
        }
    }
}

// ======= persistent BiLSTM scan: 96 WGs = d(2) x ntile(24) x btile(2); 128 steps =======
__global__ __launch_bounds__(256)
void lstm_scan(const half_t* __restrict__ G, const half_t* __restrict__ Whh,
               half_t* __restrict__ Hbuf, float* __restrict__ Cbuf,
               half_t* __restrict__ vs, half_t* __restrict__ vst,
               unsigned* __restrict__ ctr, int chunk)
{
    __shared__ __half Wl[64 * 392];
    __shared__ __half Bs[2][64][40];

    const int bid = blockIdx.x;
    const int d = bid / 48, rem = bid % 48;
    const int ntile = rem >> 1, btile = rem & 1;
    const int tid = threadIdx.x;
    const int l = tid & 63, w = tid >> 6;
    const int wm = w & 1, wn = w >> 1;
    const int lr = l & 15, lq = l >> 4;
    const unsigned nwg = gridDim.x;

    // stage Whh slice once: 64 packed-gate rows x 384 (padded stride 392)
    {
        const half_t* src = Whh + ((long)d * 1536 + ntile * 64) * 384;
        for (int e = tid; e < 3072; e += 256) {
            int r = e / 48, c = (e % 48) * 8;
            *(float4*)&Wl[r * 392 + c] = *(const float4*)(src + (long)r * 384 + c);
        }
    }

    for (int s = 0; s < 128; ++s) {
        const int gstep = chunk * 128 + s;
        const int p = gstep & 1;
        const half_t* hsrc = Hbuf + (long)(p * 2 + d) * 384 * 128 + btile * 64;

        {   // prologue: stage k-rows 0..31 into Bs[0]  (transpose [hd][b] -> [b][k])
            int r = tid >> 3, c8 = (tid & 7) * 8;
            float4 v = *(const float4*)(hsrc + (long)r * 128 + c8);
            const __half* hv = (const __half*)&v;
            #pragma unroll
            for (int i2 = 0; i2 < 8; i2++) Bs[0][c8 + i2][r] = hv[i2];
        }

        f32x4 acc[2][2] = {};
        #pragma unroll 2
        for (int it = 0; it < 12; ++it) {
            __syncthreads();
            const int cur = it & 1;
            f16x8 af[2], bfr[2];
            #pragma unroll
            for (int gf = 0; gf < 2; gf++)
                af[gf] = *(const f16x8*)&Wl[(wm * 32 + gf * 16 + lr) * 392 + it * 32 + lq * 8];
            #pragma unroll
            for (int bf2 = 0; bf2 < 2; bf2++)
                bfr[bf2] = *(const f16x8*)&Bs[cur][wn * 32 + bf2 * 16 + lr][lq * 8];
            if (it < 11) {
                int r = tid >> 3, c8 = (tid & 7) * 8;
                float4 v = *(const float4*)(hsrc + (long)((it + 1) * 32 + r) * 128 + c8);
                const __half* hv = (const __half*)&v;
                #pragma unroll
                for (int i2 = 0; i2 < 8; i2++) Bs[cur ^ 1][c8 + i2][r] = hv[i2];
            }
            #pragma unroll
            for (int gf = 0; gf < 2; gf++)
                #pragma unroll
                for (int bf2 = 0; bf2 < 2; bf2++)
                    acc[gf][bf2] = __builtin_amdgcn_mfma_f32_16x16x32_f16(af[gf], bfr[bf2], acc[gf][bf2], 0, 0, 0);
        }

        // epilogue: gates q=0..3 of one hd are acc[..][..][0..3] in this lane
        const int t_orig = d ? 255 - gstep : gstep;
        const half_t* gp = G + ((long)(s * 2 + d) * 1536 + ntile * 64) * 128 + btile * 64;
        #pragma unroll
        for (int gf = 0; gf < 2; gf++) {
            #pragma unroll
            for (int bf2 = 0; bf2 < 2; bf2++) {
                const int gl_ = wm * 32 + gf * 16 + lq * 4;
                const int bl_ = wn * 32 + bf2 * 16 + lr;
                const int hd = ntile * 16 + (gl_ >> 2);
                const int bg = btile * 64 + bl_;
                float gi = acc[gf][bf2][0] + __half2float(gp[(long)(gl_ + 0) * 128 + bl_]);
                float gfo = acc[gf][bf2][1] + __half2float(gp[(long)(gl_ + 1) * 128 + bl_]);
                float gg = acc[gf][bf2][2] + __half2float(gp[(long)(gl_ + 2) * 128 + bl_]);
                float go = acc[gf][bf2][3] + __half2float(gp[(long)(gl_ + 3) * 128 + bl_]);
                long cidx = ((long)d * 384 + hd) * 128 + bg;
                float c = Cbuf[cidx];
                float si = 1.f / (1.f + expf(-gi));
                float sf = 1.f / (1.f + expf(-gfo));
                float so = 1.f / (1.f + expf(-go));
                c = sf * c + si * tanhf(gg);
                float h = so * tanhf(c);
                Cbuf[cidx] = c;
                Hbuf[((long)((p ^ 1) * 2 + d) * 384 + hd) * 128 + bg] = __float2half(h);
                long m = (long)bg * 256 + t_orig;
                if (hd < 256) vs [m * 512 + d * 256 + hd]       = __float2half(h);
                else          vst[m * 256 + d * 128 + hd - 256] = __float2half(h);
            }
        }

        if (s < 127) {   // grid barrier (device-scope, monotonic counter)
            __syncthreads();
            if (tid == 0) {
                __threadfence();
                __hip_atomic_fetch_add(ctr, 1u, __ATOMIC_ACQ_REL, __HIP_MEMORY_SCOPE_AGENT);
                unsigned tgt = nwg * (unsigned)(s + 1);
                while (__hip_atomic_load(ctr, __ATOMIC_ACQUIRE, __HIP_MEMORY_SCOPE_AGENT) < tgt)
                    __builtin_amdgcn_s_sleep(1);
                __threadfence();
            }
            __syncthreads();
        }
    }
}

// ---------------- packs / converts ----------------
__global__ void pack_wih(const float* __restrict__ wf, const float* __restrict__ wb,
                         const float* __restrict__ bfv, const float* __restrict__ bbv,
                         half_t* __restrict__ Wp, float* __restrict__ bp)
{
    int i = blockIdx.x * 256 + threadIdx.x;
    if (i < 983040) {
        int k = i % 320, pr = (i / 320) % 1536, d = i / 491520;
        int q = pr & 3, hd = pr >> 2;
        float v = (k < 300) ? (d ? wb : wf)[(q * 384 + hd) * 300 + k] : 0.f;
        Wp[i] = __float2half(v);
    }
    if (i < 3072) {
        int d = i / 1536, pr = i % 1536;
        int q = pr & 3, hd = pr >> 2;
        bp[i] = (d ? bbv : bfv)[q * 384 + hd];
    }
}
__global__ void pack_whh(const float* __restrict__ wf, const float* __restrict__ wb,
                         half_t* __restrict__ Wh)
{
    int i = blockIdx.x * 256 + threadIdx.x;
    if (i >= 1179648) return;
    int k = i % 384, pr = (i / 384) % 1536, d = i / 589824;
    int q = pr & 3, hd = pr >> 2;
    Wh[i] = __float2half((d ? wb : wf)[(q * 384 + hd) * 384 + k]);
}
__global__ void conv16(const float* __restrict__ s, half_t* __restrict__ d, long n)
{
    long i = (long)blockIdx.x * 256 + threadIdx.x;
    if (i < n) d[i] = __float2half(s[i]);
}
__global__ void convT16(const float* __restrict__ s, half_t* __restrict__ d, int R, int C)
{
    int i = blockIdx.x * 256 + threadIdx.x;
    if (i >= R * C) return;
    int r = i / C, c = i % C;
    d[(long)c * R + r] = __float2half(s[i]);
}

// ---------------- f_r = exp(vst @ w_root^T) ----------------
__global__ __launch_bounds__(256)
void frow_kernel(const half_t* __restrict__ vst, const float* __restrict__ wroot,
                 float* __restrict__ fr)
{
    int row  = blockIdx.x * 4 + (threadIdx.x >> 6);
    int lane = threadIdx.x & 63;
    const half_t* v = vst + (long)row * 256;
    float s = 0.f;
    for (int k = lane; k < 256; k += 64) s += __half2float(v[k]) * wroot[k];
    #pragma unroll
    for (int off = 32; off; off >>= 1) s += __shfl_down(s, off);
    if (lane == 0) fr[row] = expf(s);
}

// ======= register-resident Gauss-Jordan inverse, 1024 threads: c=tid&255, rh=tid>>8 =======
// Each thread holds m[64] = rows rh*64..rh*64+63 of column c. No spill (~90 VGPR).
// Single barrier per iteration via parity-double-buffered col/row broadcasts.
__global__ __launch_bounds__(1024)
void invert_gj(const half_t* __restrict__ fA, const float* __restrict__ fr,
               half_t* __restrict__ LLinv)
{
    __shared__ float colbuf[2][256];
    __shared__ float rowbuf[2][256];
    __shared__ float csum[4][256];
    const int bz = blockIdx.x;
    const half_t* A = fA + (long)bz * 65536;
    const int tid = threadIdx.x;
    const int c = tid & 255, rh = tid >> 8;
    float m[64];

    float s = 0.f;
    #pragma unroll
    for (int i = 0; i < 64; i++) {
        float v = __half2float(A[(long)(rh * 64 + i) * 256 + c]);
        m[i] = v; s += v;
    }
    csum[rh][c] = s;
    __syncthreads();
    float diag = csum[0][c] + csum[1][c] + csum[2][c] + csum[3][c];
    const float frv = fr[bz * 256 + c];
    #pragma unroll
    for (int i = 0; i < 64; i++) {
        int r = rh * 64 + i;
        float v = (r == c) ? ((diag == 0.f) ? 1.f : diag) : -m[i];
        if (rh == 0 && i == 0) {               // row 0 replaced by root scores
            v = frv;
            if (c == 0 && v == 0.f) v = 1.f;
        }
        m[i] = v;
    }
    __syncthreads();

    for (int k = 0; k < 256; k++) {
        const int p = k & 1;
        const int kh = k >> 6, kl = k & 63;
        if (c == k) {
            #pragma unroll
            for (int i = 0; i < 64; i++) colbuf[p][rh * 64 + i] = m[i];
        }
        if (rh == kh) {
            float pv = 0.f;
            #pragma unroll
            for (int i = 0; i < 64; i++) pv = (i == kl) ? m[i] : pv;
            rowbuf[p][c] = pv;
        }
        __syncthreads();
        const float piv  = colbuf[p][k];
        const float pinv = 1.f / piv;
        const float rv   = rowbuf[p][c] * pinv;
        if (c == k) {
            #pragma unroll
            for (int i = 0; i < 64; i++) m[i] = -colbuf[p][rh * 64 + i] * pinv;
        } else {
            #pragma unroll
            for (int i = 0; i < 64; i++) m[i] -= colbuf[p][rh * 64 + i] * rv;
        }
        if (rh == kh) {
            const float dv = (c == k) ? pinv : rv;
            #pragma unroll
            for (int i = 0; i < 64; i++) m[i] = (i == kl) ? dv : m[i];
        }
        // no second barrier: iteration k+1 writes buffers [p^1]
    }

    #pragma unroll
    for (int i = 0; i < 64; i++)
        LLinv[(long)bz * 65536 + (long)(rh * 64 + i) * 256 + c] = __float2half(m[i]);
}

// ---------------- diag(LLinv) and d0 ----------------
__global__ void diag_d0_k(const half_t* __restrict__ LLinv, const float* __restrict__ fr,
                          float* __restrict__ diagv, float* __restrict__ d0)
{
    int i = blockIdx.x * 256 + threadIdx.x;
    if (i >= 32768) return;
    int b = i >> 8, s = i & 255;
    diagv[i] = __half2float(LLinv[(long)b * 65536 + s * 257]);
    d0[i]    = fr[i] * __half2float(LLinv[(long)b * 65536 + s * 256]);
}

// ---------------- a = A*(diag - LLinv^T), in place ----------------
__global__ __launch_bounds__(256)
void assemble_a(half_t* __restrict__ fA, const half_t* __restrict__ LLinv,
                const float* __restrict__ diagv)
{
    __shared__ float ll[32][33];
    const int bz = blockIdx.z;
    const int s0 = (blockIdx.x >> 3) * 32, t0 = (blockIdx.x & 7) * 32;
    const int tid = threadIdx.x;
    const long base = (long)bz * 65536;
    #pragma unroll
    for (int it = 0; it < 4; it++) {
        int i = (tid >> 5) + it * 8, j = tid & 31;
        ll[i][j] = __half2float(LLinv[base + (long)(t0 + i) * 256 + (s0 + j)]);
    }
    __syncthreads();
    #pragma unroll
    for (int it = 0; it < 4; it++) {
        int si = (tid >> 5) + it * 8, tj = tid & 31;
        int s = s0 + si, t = t0 + tj;
        long idx = base + (long)s * 256 + t;
        float Av = __half2float(fA[idx]);
        float t1 = (t > 0) ? diagv[(bz << 8) + t] : 0.f;
        float t2 = (s > 0) ? ll[tj][si] : 0.f;
        fA[idx] = __float2half(Av * (t1 - t2));
    }
}

// ---------------- batched 256x256 f16 transpose ----------------
__global__ __launch_bounds__(256)
void transpose256h(const half_t* __restrict__ in, half_t* __restrict__ out)
{
    __shared__ __half tb[32][33];
    const int bz = blockIdx.z;
    const half_t* ip = in  + (long)bz * 65536;
    half_t*       op = out + (long)bz * 65536;
    int x0 = blockIdx.x * 32, y0 = blockIdx.y * 32;
    int tx = threadIdx.x, ty = threadIdx.y;
    #pragma unroll
    for (int r = 0; r < 4; r++)
        tb[ty + 8 * r][tx] = ip[(long)(y0 + ty + 8 * r) * 256 + x0 + tx];
    __syncthreads();
    #pragma unroll
    for (int r = 0; r < 4; r++)
        op[(long)(x0 + ty + 8 * r) * 256 + y0 + tx] = tb[tx][ty + 8 * r];
}

// ---------------- emb = max over sequence (coalesced) ----------------
__global__ __launch_bounds__(256)
void emb_max(const float* __restrict__ outp, float* __restrict__ emb)
{
    int b = blockIdx.x;
    for (int n = threadIdx.x; n < 512; n += 256) {
        const float* p = outp + (long)b * 131072 + n;
        float mx = -3.4e38f;
        for (int t = 0; t < 256; t++) mx = fmaxf(mx, p[(long)t * 512]);
        emb[b * 512 + n] = mx;
    }
}

__global__ void diag_ws(float* out, int n, float v)
{
    int i = blockIdx.x * 256 + threadIdx.x;
    if (i < n) out[i] = v;
}

// ======================= host launch =======================
extern "C" void kernel_launch(void* const* d_in, const int* in_sizes, int n_in,
                              void* d_out, int out_size, void* d_ws, size_t ws_size,
                              hipStream_t stream)
{
    const float* x     = (const float*)d_in[0];
    const float* mask  = (const float*)d_in[1];
    const float* wihf  = (const float*)d_in[2];
    const float* whhf  = (const float*)d_in[3];
    const float* bf    = (const float*)d_in[4];
    const float* wihb  = (const float*)d_in[5];
    const float* whhb  = (const float*)d_in[6];
    const float* bb    = (const float*)d_in[7];
    const float* wtp   = (const float*)d_in[8];
    const float* btp   = (const float*)d_in[9];
    const float* wtc   = (const float*)d_in[10];
    const float* btc   = (const float*)d_in[11];
    const float* wa    = (const float*)d_in[12];
    const float* wroot = (const float*)d_in[13];
    const float* remb  = (const float*)d_in[14];
    const float* wr    = (const float*)d_in[15];
    const float* br    = (const float*)d_in[16];

    if (ws_size < 134217728ULL) {
        float enc = 100.0f + (float)((double)ws_size * 1e-9);
        diag_ws<<<dim3((out_size + 255) / 256), 256, 0, stream>>>((float*)d_out, out_size, enc);
        return;
    }

    char* ws = (char*)d_ws;
    half_t* G     = (half_t*)(ws + 0);              // 100,663,296 B per-chunk gates
    half_t* vs    = (half_t*)(ws + 100663296);      // 33,554,432 B
    half_t* tp    = (half_t*)(ws + 0 * SEG);        // post-scan overlays of G region
    half_t* tc    = (half_t*)(ws + 1 * SEG);
    half_t* tmp   = (half_t*)(ws + 2 * SEG);
    half_t* fA    = (half_t*)(ws + 3 * SEG);
    half_t* LL    = (half_t*)(ws + 4 * SEG);
    half_t* aT    = (half_t*)(ws + 5 * SEG);
    half_t* cbuf  = (half_t*)(ws + 0 * SEG);
    half_t* pbuf  = (half_t*)(ws + 2 * SEG);
    half_t* wr16  = (half_t*)(ws + 4 * SEG);

    // dead-until-final region of d_out hosts scan state + small weights
    float* ob = (float*)d_out;
    half_t*   Wp16  = (half_t*)(ob + 11000000);   // 983,040 f16
    half_t*   Whh16 = (half_t*)(ob + 11491520);   // 1,179,648 f16
    float*    bp    = ob + 12081344;
    half_t*   wtp16 = (half_t*)(ob + 12084416);
    half_t*   wtc16 = (half_t*)(ob + 12117184);
    half_t*   wa16T = (half_t*)(ob + 12149952);
    float*    fr    = ob + 12182720;
    float*    d0    = ob + 12215488;
    float*    diagv = ob + 12248256;
    float*    Cbuf  = ob + 12281024;              // [2][384][128] f32
    half_t*   Hbuf  = (half_t*)(ob + 12379328);   // [2][2][384][128] f16
    unsigned* ctrs  = (unsigned*)(ob + 12500000); // 2 barrier counters
    half_t*   vst   = (half_t*)(ob + 12648448);   // 32768 x 256 f16

    float* emb  = (float*)d_out;
    float* outp = (float*)d_out + 65536;

    // 0. init state + pack weights
    hipMemsetAsync(Cbuf, 0, 393216, stream);
    hipMemsetAsync(Hbuf, 0, 393216, stream);
    hipMemsetAsync(ctrs, 0, 8, stream);
    pack_wih<<<dim3(3840), 256, 0, stream>>>(wihf, wihb, bf, bb, Wp16, bp);
    pack_whh<<<dim3(4608), 256, 0, stream>>>(whhf, whhb, Whh16);
    conv16<<<dim3(256), 256, 0, stream>>>(wtp, wtp16, 65536);
    conv16<<<dim3(256), 256, 0, stream>>>(wtc, wtc16, 65536);
    convT16<<<dim3(256), 256, 0, stream>>>(wa, wa16T, 256, 256);

    // 1. chunked: G GEMM + persistent 128-step scan, twice
    for (int c = 0; c < 2; c++) {
        ggemm<<<dim3(12, 128, 2), 256, 0, stream>>>(x, Wp16, bp, G, c);
        lstm_scan<<<dim3(96), 256, 0, stream>>>(G, Whh16, Hbuf, Cbuf, vs, vst, ctrs + c, c);
    }

    // 2. f_r
    frow_kernel<<<dim3(8192), 256, 0, stream>>>(vst, wroot, fr);

    // 3. tp / tc = tanh(vst @ W^T + b)
    mgemm<false><<<dim3(4, 256, 1), 256, 0, stream>>>(
        vst, wtp16, tp, M_, 256, 256, 256, 256, 256, 0, 0, 0, btp, 1, nullptr, nullptr);
    mgemm<false><<<dim3(4, 256, 1), 256, 0, stream>>>(
        vst, wtc16, tc, M_, 256, 256, 256, 256, 256, 0, 0, 0, btc, 1, nullptr, nullptr);

    // 4. tmp = tp @ w_a
    mgemm<false><<<dim3(4, 256, 1), 256, 0, stream>>>(
        tp, wa16T, tmp, M_, 256, 256, 256, 256, 256, 0, 0, 0, nullptr, 0, nullptr, nullptr);

    // 5. f = exp(tmp @ tc^T), diag zeroed (batched)
    mgemm<false><<<dim3(4, 2, 128), 256, 0, stream>>>(
        tmp, tc, fA, 256, 256, 256, 256, 256, 256, 65536, 65536, 65536,
        nullptr, 2, nullptr, nullptr);

    // 6-8. inverse, diag/d0, assemble
    invert_gj<<<dim3(128), 1024, 0, stream>>>(fA, fr, LL);
    diag_d0_k<<<dim3(128), 256, 0, stream>>>(LL, fr, diagv, d0);
    assemble_a<<<dim3(64, 1, 128), 256, 0, stream>>>(fA, LL, diagv);

    // 9. wr -> f16 (LL dead now)
    conv16<<<dim3(3072), 256, 0, stream>>>(wr, wr16, 786432);

    // 10. aT
    transpose256h<<<dim3(8, 8, 128), dim3(32, 8), 0, stream>>>(fA, aT);

    // 11. c = a @ vs
    mgemm<true><<<dim3(8, 2, 128), 256, 0, stream>>>(
        fA, vs, cbuf, 256, 512, 256, 256, 512, 512, 65536, 131072, 131072,
        nullptr, 0, nullptr, nullptr);

    // 12. p = aT @ vs + d0 (x) root_emb
    mgemm<true><<<dim3(8, 2, 128), 256, 0, stream>>>(
        aT, vs, pbuf, 256, 512, 256, 256, 512, 512, 65536, 131072, 131072,
        nullptr, 0, d0, remb);

    // 13. out = tanh([vs|p|c] @ wr^T + br) * mask
    mgemm_final<<<dim3(8, 256, 1), 256, 0, stream>>>(vs, pbuf, cbuf, wr16, outp, br, mask);

    // 14. emb
    emb_max<<<dim3(128), 256, 0, stream>>>(outp, emb);
}

// Round 7
// 4979.668 us; speedup vs baseline: 4.1665x; 1.0557x over previous
//
#include <hip/hip_runtime.h>
#include <hip/hip_fp16.h>
#include <math.h>

#define B_    128
#define S_    256
#define WORD_ 300
#define HD_   384
#define M_    32768
#define STRU_ 256
#define SEMA_ 512
#define SEG   16777216L

typedef __half half_t;
typedef _Float16 f16x8 __attribute__((ext_vector_type(8)));
typedef float    f32x4 __attribute__((ext_vector_type(4)));

// ================= MFMA GEMM: C(f16) = act(A @ B(.T) + bias + d0*root) =================
template<bool BNN>
__global__ __launch_bounds__(256)
void mgemm(const half_t* __restrict__ Ag, const half_t* __restrict__ Bg,
           half_t* __restrict__ Cg,
           int M, int N, int K, int lda, int ldb, int ldc,
           long sA, long sB, long sC,
           const float* __restrict__ bias, int act,
           const float* __restrict__ d0v, const float* __restrict__ rootv)
{
    __shared__ __half As[128][40];
    __shared__ __half Bs[64][40];
    const int bz = blockIdx.z;
    const half_t* A  = Ag + (long)bz * sA;
    const half_t* Bp = Bg + (long)bz * sB;
    const int m0 = blockIdx.y * 128, n0 = blockIdx.x * 64;
    const int tid = threadIdx.x;
    const int l = tid & 63, w = tid >> 6;
    const int wm = w & 1, wn = w >> 1;
    const int lr = l & 15, lq = l >> 4;

    f32x4 acc[4][2] = {};

    for (int k0 = 0; k0 < K; k0 += 32) {
        #pragma unroll
        for (int i = 0; i < 2; i++) {
            int ch = tid + i * 256;
            int r = ch >> 2, j = ch & 3;
            *(float4*)&As[r][j * 8] = *(const float4*)(A + (long)(m0 + r) * lda + k0 + j * 8);
        }
        if (!BNN) {
            int r = tid >> 2, j = tid & 3;
            *(float4*)&Bs[r][j * 8] = *(const float4*)(Bp + (long)(n0 + r) * ldb + k0 + j * 8);
        } else {
            int k = tid & 31, nc = tid >> 5;
            float4 v = *(const float4*)(Bp + (long)(k0 + k) * ldb + n0 + nc * 8);
            const __half* hv = (const __half*)&v;
            #pragma unroll
            for (int jj = 0; jj < 8; jj++) Bs[nc * 8 + jj][k] = hv[jj];
        }
        __syncthreads();

        f16x8 af[4], bf[2];
        #pragma unroll
        for (int mf = 0; mf < 4; mf++)
            af[mf] = *(const f16x8*)&As[wm * 64 + mf * 16 + lr][lq * 8];
        #pragma unroll
        for (int nf = 0; nf < 2; nf++)
            bf[nf] = *(const f16x8*)&Bs[wn * 32 + nf * 16 + lr][lq * 8];
        #pragma unroll
        for (int mf = 0; mf < 4; mf++)
            #pragma unroll
            for (int nf = 0; nf < 2; nf++)
                acc[mf][nf] = __builtin_amdgcn_mfma_f32_16x16x32_f16(af[mf], bf[nf], acc[mf][nf], 0, 0, 0);
        __syncthreads();
    }

    #pragma unroll
    for (int mf = 0; mf < 4; mf++) {
        #pragma unroll
        for (int nf = 0; nf < 2; nf++) {
            #pragma unroll
            for (int j = 0; j < 4; j++) {
                int m = m0 + wm * 64 + mf * 16 + lq * 4 + j;
                int n = n0 + wn * 32 + nf * 16 + lr;
                float v = acc[mf][nf][j];
                if (bias) v += bias[n];
                if (d0v)  v += d0v[(long)bz * M + m] * rootv[n];
                if (act == 1)      v = tanhf(v);
                else if (act == 2) v = (m == n) ? 0.f : expf(v);
                Cg[(long)bz * sC + (long)m * ldc + n] = __float2half(v);
            }
        }
    }
}

// ============ final: out = tanh(vs@W1^T + p@W2^T + c@W3^T + br) * mask ============
__global__ __launch_bounds__(256)
void mgemm_final(const half_t* __restrict__ A0, const half_t* __restrict__ A1,
                 const half_t* __restrict__ A2, const half_t* __restrict__ Bw,
                 float* __restrict__ Cout, const float* __restrict__ bias,
                 const float* __restrict__ maskp)
{
    __shared__ __half As[128][40];
    __shared__ __half Bs[64][40];
    const int m0 = blockIdx.y * 128, n0 = blockIdx.x * 64;
    const int tid = threadIdx.x;
    const int l = tid & 63, w = tid >> 6;
    const int wm = w & 1, wn = w >> 1;
    const int lr = l & 15, lq = l >> 4;

    f32x4 acc[4][2] = {};

    for (int k0 = 0; k0 < 1536; k0 += 32) {
        const half_t* A = (k0 < 512) ? A0 : (k0 < 1024) ? A1 : A2;
        const int kk = k0 & 511;
        #pragma unroll
        for (int i = 0; i < 2; i++) {
            int ch = tid + i * 256;
            int r = ch >> 2, j = ch & 3;
            *(float4*)&As[r][j * 8] = *(const float4*)(A + (long)(m0 + r) * 512 + kk + j * 8);
        }
        {
            int r = tid >> 2, j = tid & 3;
            *(float4*)&Bs[r][j * 8] = *(const float4*)(Bw + (long)(n0 + r) * 1536 + k0 + j * 8);
        }
        __syncthreads();
        f16x8 af[4], bf[2];
        #pragma unroll
        for (int mf = 0; mf < 4; mf++)
            af[mf] = *(const f16x8*)&As[wm * 64 + mf * 16 + lr][lq * 8];
        #pragma unroll
        for (int nf = 0; nf < 2; nf++)
            bf[nf] = *(const f16x8*)&Bs[wn * 32 + nf * 16 + lr][lq * 8];
        #pragma unroll
        for (int mf = 0; mf < 4; mf++)
            #pragma unroll
            for (int nf = 0; nf < 2; nf++)
                acc[mf][nf] = __builtin_amdgcn_mfma_f32_16x16x32_f16(af[mf], bf[nf], acc[mf][nf], 0, 0, 0);
        __syncthreads();
    }

    #pragma unroll
    for (int mf = 0; mf < 4; mf++) {
        #pragma unroll
        for (int nf = 0; nf < 2; nf++) {
            #pragma unroll
            for (int j = 0; j < 4; j++) {
                int m = m0 + wm * 64 + mf * 16 + lq * 4 + j;
                int n = n0 + wn * 32 + nf * 16 + lr;
                float v = tanhf(acc[mf][nf][j] + bias[n]) * maskp[m];
                Cout[(long)m * 512 + n] = v;
            }
        }
    }
}

// ======= G[ts][d][hd][b][q] = Wp@x + bp : 4 gates of one hd contiguous (8B) =======
__global__ __launch_bounds__(256)
void ggemm(const float* __restrict__ x, const half_t* __restrict__ Wp,
           const float* __restrict__ bp, half_t* __restrict__ G, int chunk)
{
    __shared__ __half As[128][40];
    __shared__ __half Bs[128][40];
    const int d = blockIdx.z;
    const int ts = blockIdx.y;
    const int m0 = blockIdx.x * 128;                 // packed gate rows
    const int t_orig = d ? (255 - (chunk * 128 + ts)) : (chunk * 128 + ts);
    const int tid = threadIdx.x;
    const int l = tid & 63, w = tid >> 6;
    const int wm = w & 1, wn = w >> 1;
    const int lr = l & 15, lq = l >> 4;

    f32x4 acc[4][4] = {};

    for (int k0 = 0; k0 < 320; k0 += 32) {
        #pragma unroll
        for (int i = 0; i < 2; i++) {
            int e = tid + i * 256;
            int r = e >> 2, j = (e & 3) * 8;
            *(float4*)&As[r][j] = *(const float4*)(Wp + ((long)d * 1536 + m0 + r) * 320 + k0 + j);
        }
        #pragma unroll
        for (int i = 0; i < 2; i++) {
            int e = tid + i * 256;
            int r = e >> 2, j = (e & 3) * 8;
            int k = k0 + j;
            int ka = (k + 4 <= 300) ? k : 0;
            int kb = (k + 8 <= 300) ? k + 4 : 0;
            const float* xp = x + ((long)r * 256 + t_orig) * 300;
            float4 va = *(const float4*)(xp + ka);
            float4 vb = *(const float4*)(xp + kb);
            __half* q = &Bs[r][j];
            q[0] = __float2half(va.x); q[1] = __float2half(va.y);
            q[2] = __float2half(va.z); q[3] = __float2half(va.w);
            q[4] = __float2half(vb.x); q[5] = __float2half(vb.y);
            q[6] = __float2half(vb.z); q[7] = __float2half(vb.w);
        }
        __syncthreads();
        f16x8 af[4], bf[4];
        #pragma unroll
        for (int gf = 0; gf < 4; gf++)
            af[gf] = *(const f16x8*)&As[wm * 64 + gf * 16 + lr][lq * 8];
        #pragma unroll
        for (int bi = 0; bi < 4; bi++)
            bf[bi] = *(const f16x8*)&Bs[wn * 64 + bi * 16 + lr][lq * 8];
        #pragma unroll
        for (int gf = 0; gf < 4; gf++)
            #pragma unroll
            for (int bi = 0; bi < 4; bi++)
                acc[gf][bi] = __builtin_amdgcn_mfma_f32_16x16x32_f16(af[gf], bf[bi], acc[gf][bi], 0, 0, 0);
        __syncthreads();
    }

    half_t* Gt = G + (long)(ts * 2 + d) * 196608;    // [hd 384][b 128][q 4]
    #pragma unroll
    for (int gf = 0; gf < 4; gf++) {
        #pragma unroll
        for (int bi = 0; bi < 4; bi++) {
            int g = m0 + wm * 64 + gf * 16 + lq * 4;  // first of 4 consecutive packed rows
            int b = wn * 64 + bi * 16 + lr;
            union { __half h[4]; float2 f; } u;
            #pragma unroll
            for (int j = 0; j < 4; j++)
                u.h[j] = __float2half(acc[gf][bi][j] + bp[d * 1536 + g + j]);
            *(float2*)(Gt + ((long)(g >> 2) * 128 + b) * 4) = u.f;
        }
    }
}

// ======= persistent BiLSTM scan: 96 WGs = d(2) x ntile(24) x btile(2); 128 steps =======
// h layout [p][d][b][hd] -> MFMA B-frags load DIRECT from global (no LDS staging).
// c-state in registers; h/vs/vst written via 2KB LDS bounce as 16B stores.
// Barrier: 4 independent (d,btile) groups of 24 WGs.
__global__ __launch_bounds__(256)
void lstm_scan(const half_t* __restrict__ G, const half_t* __restrict__ Whh,
               half_t* __restrict__ Hbuf, float* __restrict__ Cst,
               half_t* __restrict__ vs, half_t* __restrict__ vst,
               unsigned* __restrict__ ctrs, int chunk)
{
    __shared__ __half Wl[64 * 392];
    __shared__ __half hlo[16][68];

    const int bid = blockIdx.x;
    const int d = bid / 48, rem = bid % 48;
    const int ntile = rem >> 1, btile = rem & 1;
    const int tid = threadIdx.x;
    const int l = tid & 63, w = tid >> 6;
    const int wm = w & 1, wn = w >> 1;
    const int lr = l & 15, lq = l >> 4;
    unsigned* ctr = ctrs + (d * 2 + btile);

    // stage Whh slice once: 64 packed-gate rows x 384 (padded stride 392)
    {
        const half_t* src = Whh + ((long)d * 1536 + ntile * 64) * 384;
        for (int e = tid; e < 3072; e += 256) {
            int r = e / 48, c = (e % 48) * 8;
            *(float4*)&Wl[r * 392 + c] = *(const float4*)(src + (long)r * 384 + c);
        }
    }
    // c-state in registers (4 per lane), persisted across chunks via Cst
    float creg[4];
    if (chunk == 0) {
        creg[0] = creg[1] = creg[2] = creg[3] = 0.f;
    } else {
        #pragma unroll
        for (int i = 0; i < 4; i++) creg[i] = Cst[((long)bid * 256 + tid) * 4 + i];
    }
    __syncthreads();

    for (int s = 0; s < 128; ++s) {
        const int gstep = chunk * 128 + s;
        const int p = gstep & 1;
        const half_t* hin = Hbuf + (long)(p * 2 + d) * 128 * 384;   // [b][hd]

        f32x4 acc[2][2] = {};
        #pragma unroll
        for (int it = 0; it < 12; ++it) {
            f16x8 af[2], bf[2];
            #pragma unroll
            for (int gf = 0; gf < 2; gf++)
                af[gf] = *(const f16x8*)&Wl[(wm * 32 + gf * 16 + lr) * 392 + it * 32 + lq * 8];
            #pragma unroll
            for (int bf2 = 0; bf2 < 2; bf2++) {
                int bg = btile * 64 + wn * 32 + bf2 * 16 + lr;
                bf[bf2] = *(const f16x8*)(hin + (long)bg * 384 + it * 32 + lq * 8);
            }
            #pragma unroll
            for (int gf = 0; gf < 2; gf++)
                #pragma unroll
                for (int bf2 = 0; bf2 < 2; bf2++)
                    acc[gf][bf2] = __builtin_amdgcn_mfma_f32_16x16x32_f16(af[gf], bf[bf2], acc[gf][bf2], 0, 0, 0);
        }

        // epilogue: 4 gates of one hd are this lane's 4 acc regs; G gives 8B per value-set
        const half_t* gpd = G + (long)(s * 2 + d) * 196608;
        #pragma unroll
        for (int gf = 0; gf < 2; gf++) {
            #pragma unroll
            for (int bf2 = 0; bf2 < 2; bf2++) {
                const int hd_l = wm * 8 + gf * 4 + lq;          // 0..15
                const int bl_  = wn * 32 + bf2 * 16 + lr;       // 0..63
                const int hdg  = ntile * 16 + hd_l;
                const int bg   = btile * 64 + bl_;
                union { float2 f; __half h[4]; } gu;
                gu.f = *(const float2*)(gpd + ((long)hdg * 128 + bg) * 4);
                float gi  = acc[gf][bf2][0] + __half2float(gu.h[0]);
                float gfo = acc[gf][bf2][1] + __half2float(gu.h[1]);
                float gg  = acc[gf][bf2][2] + __half2float(gu.h[2]);
                float go  = acc[gf][bf2][3] + __half2float(gu.h[3]);
                const int ci = gf * 2 + bf2;
                float c = creg[ci];
                float si = 1.f / (1.f + expf(-gi));
                float sf = 1.f / (1.f + expf(-gfo));
                float so = 1.f / (1.f + expf(-go));
                c = sf * c + si * tanhf(gg);
                creg[ci] = c;
                hlo[hd_l][bl_] = __float2half(so * tanhf(c));
            }
        }
        __syncthreads();

        // repack: 128 threads write 16B-vector h / vs / vst
        if (tid < 128) {
            const int b_l = tid & 63, h8 = tid >> 6;            // h8: 0..1
            f16x8 v;
            #pragma unroll
            for (int j = 0; j < 8; j++) v[j] = (_Float16)hlo[h8 * 8 + j][b_l];
            const int bg  = btile * 64 + b_l;
            const int hd0 = ntile * 16 + h8 * 8;
            *(f16x8*)(Hbuf + ((long)((p ^ 1) * 2 + d) * 128 + bg) * 384 + hd0) = v;
            const int t_orig = d ? 255 - gstep : gstep;
            const long m = (long)bg * 256 + t_orig;
            if (hd0 < 256) *(f16x8*)(vs  + m * 512 + d * 256 + hd0)         = v;
            else           *(f16x8*)(vst + m * 256 + d * 128 + (hd0 - 256)) = v;
        }

        if (s < 127) {   // group barrier: 24 WGs of (d,btile)
            __syncthreads();
            if (tid == 0) {
                __threadfence();
                __hip_atomic_fetch_add(ctr, 1u, __ATOMIC_ACQ_REL, __HIP_MEMORY_SCOPE_AGENT);
                unsigned tgt = 24u * (unsigned)(s + 1);
                while (__hip_atomic_load(ctr, __ATOMIC_ACQUIRE, __HIP_MEMORY_SCOPE_AGENT) < tgt)
                    __builtin_amdgcn_s_sleep(1);
                __threadfence();
            }
            __syncthreads();
        }
    }

    #pragma unroll
    for (int i = 0; i < 4; i++) Cst[((long)bid * 256 + tid) * 4 + i] = creg[i];
}

// ---------------- packs / converts ----------------
__global__ void pack_wih(const float* __restrict__ wf, const float* __restrict__ wb,
                         const float* __restrict__ bfv, const float* __restrict__ bbv,
                         half_t* __restrict__ Wp, float* __restrict__ bp)
{
    int i = blockIdx.x * 256 + threadIdx.x;
    if (i < 983040) {
        int k = i % 320, pr = (i / 320) % 1536, d = i / 491520;
        int q = pr & 3, hd = pr >> 2;
        float v = (k < 300) ? (d ? wb : wf)[(q * 384 + hd) * 300 + k] : 0.f;
        Wp[i] = __float2half(v);
    }
    if (i < 3072) {
        int d = i / 1536, pr = i % 1536;
        int q = pr & 3, hd = pr >> 2;
        bp[i] = (d ? bbv : bfv)[q * 384 + hd];
    }
}
__global__ void pack_whh(const float* __restrict__ wf, const float* __restrict__ wb,
                         half_t* __restrict__ Wh)
{
    int i = blockIdx.x * 256 + threadIdx.x;
    if (i >= 1179648) return;
    int k = i % 384, pr = (i / 384) % 1536, d = i / 589824;
    int q = pr & 3, hd = pr >> 2;
    Wh[i] = __float2half((d ? wb : wf)[(q * 384 + hd) * 384 + k]);
}
__global__ void conv16(const float* __restrict__ s, half_t* __restrict__ d, long n)
{
    long i = (long)blockIdx.x * 256 + threadIdx.x;
    if (i < n) d[i] = __float2half(s[i]);
}
__global__ void convT16(const float* __restrict__ s, half_t* __restrict__ d, int R, int C)
{
    int i = blockIdx.x * 256 + threadIdx.x;
    if (i >= R * C) return;
    int r = i / C, c = i % C;
    d[(long)c * R + r] = __float2half(s[i]);
}

// ---------------- f_r = exp(vst @ w_root^T) ----------------
__global__ __launch_bounds__(256)
void frow_kernel(const half_t* __restrict__ vst, const float* __restrict__ wroot,
                 float* __restrict__ fr)
{
    int row  = blockIdx.x * 4 + (threadIdx.x >> 6);
    int lane = threadIdx.x & 63;
    const half_t* v = vst + (long)row * 256;
    float s = 0.f;
    for (int k = lane; k < 256; k += 64) s += __half2float(v[k]) * wroot[k];
    #pragma unroll
    for (int off = 32; off; off >>= 1) s += __shfl_down(s, off);
    if (lane == 0) fr[row] = expf(s);
}

// ======= register-resident Gauss-Jordan inverse, 1024 threads =======
__global__ __launch_bounds__(1024)
void invert_gj(const half_t* __restrict__ fA, const float* __restrict__ fr,
               half_t* __restrict__ LLinv)
{
    __shared__ float colbuf[2][256];
    __shared__ float rowbuf[2][256];
    __shared__ float csum[4][256];
    const int bz = blockIdx.x;
    const half_t* A = fA + (long)bz * 65536;
    const int tid = threadIdx.x;
    const int c = tid & 255, rh = tid >> 8;
    float m[64];

    float s = 0.f;
    #pragma unroll
    for (int i = 0; i < 64; i++) {
        float v = __half2float(A[(long)(rh * 64 + i) * 256 + c]);
        m[i] = v; s += v;
    }
    csum[rh][c] = s;
    __syncthreads();
    float diag = csum[0][c] + csum[1][c] + csum[2][c] + csum[3][c];
    const float frv = fr[bz * 256 + c];
    #pragma unroll
    for (int i = 0; i < 64; i++) {
        int r = rh * 64 + i;
        float v = (r == c) ? ((diag == 0.f) ? 1.f : diag) : -m[i];
        if (rh == 0 && i == 0) {
            v = frv;
            if (c == 0 && v == 0.f) v = 1.f;
        }
        m[i] = v;
    }
    __syncthreads();

    for (int k = 0; k < 256; k++) {
        const int p = k & 1;
        const int kh = k >> 6, kl = k & 63;
        if (c == k) {
            #pragma unroll
            for (int i = 0; i < 64; i++) colbuf[p][rh * 64 + i] = m[i];
        }
        if (rh == kh) {
            float pv = 0.f;
            #pragma unroll
            for (int i = 0; i < 64; i++) pv = (i == kl) ? m[i] : pv;
            rowbuf[p][c] = pv;
        }
        __syncthreads();
        const float piv  = colbuf[p][k];
        const float pinv = 1.f / piv;
        const float rv   = rowbuf[p][c] * pinv;
        if (c == k) {
            #pragma unroll
            for (int i = 0; i < 64; i++) m[i] = -colbuf[p][rh * 64 + i] * pinv;
        } else {
            #pragma unroll
            for (int i = 0; i < 64; i++) m[i] -= colbuf[p][rh * 64 + i] * rv;
        }
        if (rh == kh) {
            const float dv = (c == k) ? pinv : rv;
            #pragma unroll
            for (int i = 0; i < 64; i++) m[i] = (i == kl) ? dv : m[i];
        }
    }

    #pragma unroll
    for (int i = 0; i < 64; i++)
        LLinv[(long)bz * 65536 + (long)(rh * 64 + i) * 256 + c] = __float2half(m[i]);
}

// ---------------- diag(LLinv) and d0 ----------------
__global__ void diag_d0_k(const half_t* __restrict__ LLinv, const float* __restrict__ fr,
                          float* __restrict__ diagv, float* __restrict__ d0)
{
    int i = blockIdx.x * 256 + threadIdx.x;
    if (i >= 32768) return;
    int b = i >> 8, s = i & 255;
    diagv[i] = __half2float(LLinv[(long)b * 65536 + s * 257]);
    d0[i]    = fr[i] * __half2float(LLinv[(long)b * 65536 + s * 256]);
}

// ---------------- a = A*(diag - LLinv^T), in place ----------------
__global__ __launch_bounds__(256)
void assemble_a(half_t* __restrict__ fA, const half_t* __restrict__ LLinv,
                const float* __restrict__ diagv)
{
    __shared__ float ll[32][33];
    const int bz = blockIdx.z;
    const int s0 = (blockIdx.x >> 3) * 32, t0 = (blockIdx.x & 7) * 32;
    const int tid = threadIdx.x;
    const long base = (long)bz * 65536;
    #pragma unroll
    for (int it = 0; it < 4; it++) {
        int i = (tid >> 5) + it * 8, j = tid & 31;
        ll[i][j] = __half2float(LLinv[base + (long)(t0 + i) * 256 + (s0 + j)]);
    }
    __syncthreads();
    #pragma unroll
    for (int it = 0; it < 4; it++) {
        int si = (tid >> 5) + it * 8, tj = tid & 31;
        int s = s0 + si, t = t0 + tj;
        long idx = base + (long)s * 256 + t;
        float Av = __half2float(fA[idx]);
        float t1 = (t > 0) ? diagv[(bz << 8) + t] : 0.f;
        float t2 = (s > 0) ? ll[tj][si] : 0.f;
        fA[idx] = __float2half(Av * (t1 - t2));
    }
}

// ---------------- batched 256x256 f16 transpose ----------------
__global__ __launch_bounds__(256)
void transpose256h(const half_t* __restrict__ in, half_t* __restrict__ out)
{
    __shared__ __half tb[32][33];
    const int bz = blockIdx.z;
    const half_t* ip = in  + (long)bz * 65536;
    half_t*       op = out + (long)bz * 65536;
    int x0 = blockIdx.x * 32, y0 = blockIdx.y * 32;
    int tx = threadIdx.x, ty = threadIdx.y;
    #pragma unroll
    for (int r = 0; r < 4; r++)
        tb[ty + 8 * r][tx] = ip[(long)(y0 + ty + 8 * r) * 256 + x0 + tx];
    __syncthreads();
    #pragma unroll
    for (int r = 0; r < 4; r++)
        op[(long)(x0 + ty + 8 * r) * 256 + y0 + tx] = tb[tx][ty + 8 * r];
}

// ---------------- emb = max over sequence (coalesced) ----------------
__global__ __launch_bounds__(256)
void emb_max(const float* __restrict__ outp, float* __restrict__ emb)
{
    int b = blockIdx.x;
    for (int n = threadIdx.x; n < 512; n += 256) {
        const float* p = outp + (long)b * 131072 + n;
        float mx = -3.4e38f;
        for (int t = 0; t < 256; t++) mx = fmaxf(mx, p[(long)t * 512]);
        emb[b * 512 + n] = mx;
    }
}

__global__ void diag_ws(float* out, int n, float v)
{
    int i = blockIdx.x * 256 + threadIdx.x;
    if (i < n) out[i] = v;
}

// ======================= host launch =======================
extern "C" void kernel_launch(void* const* d_in, const int* in_sizes, int n_in,
                              void* d_out, int out_size, void* d_ws, size_t ws_size,
                              hipStream_t stream)
{
    const float* x     = (const float*)d_in[0];
    const float* mask  = (const float*)d_in[1];
    const float* wihf  = (const float*)d_in[2];
    const float* whhf  = (const float*)d_in[3];
    const float* bf    = (const float*)d_in[4];
    const float* wihb  = (const float*)d_in[5];
    const float* whhb  = (const float*)d_in[6];
    const float* bb    = (const float*)d_in[7];
    const float* wtp   = (const float*)d_in[8];
    const float* btp   = (const float*)d_in[9];
    const float* wtc   = (const float*)d_in[10];
    const float* btc   = (const float*)d_in[11];
    const float* wa    = (const float*)d_in[12];
    const float* wroot = (const float*)d_in[13];
    const float* remb  = (const float*)d_in[14];
    const float* wr    = (const float*)d_in[15];
    const float* br    = (const float*)d_in[16];

    if (ws_size < 134217728ULL) {
        float enc = 100.0f + (float)((double)ws_size * 1e-9);
        diag_ws<<<dim3((out_size + 255) / 256), 256, 0, stream>>>((float*)d_out, out_size, enc);
        return;
    }

    char* ws = (char*)d_ws;
    half_t* G     = (half_t*)(ws + 0);              // 100,663,296 B per-chunk gates
    half_t* vs    = (half_t*)(ws + 100663296);      // 33,554,432 B
    half_t* tp    = (half_t*)(ws + 0 * SEG);        // post-scan overlays of G region
    half_t* tc    = (half_t*)(ws + 1 * SEG);
    half_t* tmp   = (half_t*)(ws + 2 * SEG);
    half_t* fA    = (half_t*)(ws + 3 * SEG);
    half_t* LL    = (half_t*)(ws + 4 * SEG);
    half_t* aT    = (half_t*)(ws + 5 * SEG);
    half_t* cbuf  = (half_t*)(ws + 0 * SEG);
    half_t* pbuf  = (half_t*)(ws + 2 * SEG);
    half_t* wr16  = (half_t*)(ws + 4 * SEG);

    // dead-until-final region of d_out hosts scan state + small weights
    float* ob = (float*)d_out;
    half_t*   Wp16  = (half_t*)(ob + 11000000);   // 983,040 f16
    half_t*   Whh16 = (half_t*)(ob + 11491520);   // 1,179,648 f16
    float*    bp    = ob + 12081344;
    half_t*   wtp16 = (half_t*)(ob + 12084416);
    half_t*   wtc16 = (half_t*)(ob + 12117184);
    half_t*   wa16T = (half_t*)(ob + 12149952);
    float*    fr    = ob + 12182720;
    float*    d0    = ob + 12215488;
    float*    diagv = ob + 12248256;
    float*    Cst   = ob + 12281024;              // 96*256*4 f32 = 393,216 B
    half_t*   Hbuf  = (half_t*)(ob + 12379328);   // [2 p][2 d][128 b][384 hd] f16
    unsigned* ctrs  = (unsigned*)(ob + 12500000); // 8 barrier counters
    half_t*   vst   = (half_t*)(ob + 12648448);   // 32768 x 256 f16

    float* emb  = (float*)d_out;
    float* outp = (float*)d_out + 65536;

    // 0. init state + pack weights
    hipMemsetAsync(Hbuf, 0, 393216, stream);
    hipMemsetAsync(ctrs, 0, 32, stream);
    pack_wih<<<dim3(3840), 256, 0, stream>>>(wihf, wihb, bf, bb, Wp16, bp);
    pack_whh<<<dim3(4608), 256, 0, stream>>>(whhf, whhb, Whh16);
    conv16<<<dim3(256), 256, 0, stream>>>(wtp, wtp16, 65536);
    conv16<<<dim3(256), 256, 0, stream>>>(wtc, wtc16, 65536);
    convT16<<<dim3(256), 256, 0, stream>>>(wa, wa16T, 256, 256);

    // 1. chunked: G GEMM + persistent 128-step scan, twice
    for (int c = 0; c < 2; c++) {
        ggemm<<<dim3(12, 128, 2), 256, 0, stream>>>(x, Wp16, bp, G, c);
        lstm_scan<<<dim3(96), 256, 0, stream>>>(G, Whh16, Hbuf, Cst, vs, vst, ctrs + c * 4, c);
    }

    // 2. f_r
    frow_kernel<<<dim3(8192), 256, 0, stream>>>(vst, wroot, fr);

    // 3. tp / tc = tanh(vst @ W^T + b)
    mgemm<false><<<dim3(4, 256, 1), 256, 0, stream>>>(
        vst, wtp16, tp, M_, 256, 256, 256, 256, 256, 0, 0, 0, btp, 1, nullptr, nullptr);
    mgemm<false><<<dim3(4, 256, 1), 256, 0, stream>>>(
        vst, wtc16, tc, M_, 256, 256, 256, 256, 256, 0, 0, 0, btc, 1, nullptr, nullptr);

    // 4. tmp = tp @ w_a
    mgemm<false><<<dim3(4, 256, 1), 256, 0, stream>>>(
        tp, wa16T, tmp, M_, 256, 256, 256, 256, 256, 0, 0, 0, nullptr, 0, nullptr, nullptr);

    // 5. f = exp(tmp @ tc^T), diag zeroed (batched)
    mgemm<false><<<dim3(4, 2, 128), 256, 0, stream>>>(
        tmp, tc, fA, 256, 256, 256, 256, 256, 256, 65536, 65536, 65536,
        nullptr, 2, nullptr, nullptr);

    // 6-8. inverse, diag/d0, assemble
    invert_gj<<<dim3(128), 1024, 0, stream>>>(fA, fr, LL);
    diag_d0_k<<<dim3(128), 256, 0, stream>>>(LL, fr, diagv, d0);
    assemble_a<<<dim3(64, 1, 128), 256, 0, stream>>>(fA, LL, diagv);

    // 9. wr -> f16 (LL dead now)
    conv16<<<dim3(3072), 256, 0, stream>>>(wr, wr16, 786432);

    // 10. aT
    transpose256h<<<dim3(8, 8, 128), dim3(32, 8), 0, stream>>>(fA, aT);

    // 11. c = a @ vs
    mgemm<true><<<dim3(8, 2, 128), 256, 0, stream>>>(
        fA, vs, cbuf, 256, 512, 256, 256, 512, 512, 65536, 131072, 131072,
        nullptr, 0, nullptr, nullptr);

    // 12. p = aT @ vs + d0 (x) root_emb
    mgemm<true><<<dim3(8, 2, 128), 256, 0, stream>>>(
        aT, vs, pbuf, 256, 512, 256, 256, 512, 512, 65536, 131072, 131072,
        nullptr, 0, d0, remb);

    // 13. out = tanh([vs|p|c] @ wr^T + br) * mask
    mgemm_final<<<dim3(8, 256, 1), 256, 0, stream>>>(vs, pbuf, cbuf, wr16, outp, br, mask);

    // 14. emb
    emb_max<<<dim3(128), 256, 0, stream>>>(outp, emb);
}

// Round 8
// 4879.791 us; speedup vs baseline: 4.2518x; 1.0205x over previous
//
#include <hip/hip_runtime.h>
#include <hip/hip_fp16.h>
#include <math.h>

#define B_    128
#define S_    256
#define WORD_ 300
#define HD_   384
#define M_    32768
#define STRU_ 256
#define SEMA_ 512
#define SEG   16777216L

typedef __half half_t;
typedef _Float16 f16x8 __attribute__((ext_vector_type(8)));
typedef float    f32x4 __attribute__((ext_vector_type(4)));

// ================= MFMA GEMM: C(f16) = act(A @ B(.T) + bias + d0*root) =================
template<bool BNN>
__global__ __launch_bounds__(256)
void mgemm(const half_t* __restrict__ Ag, const half_t* __restrict__ Bg,
           half_t* __restrict__ Cg,
           int M, int N, int K, int lda, int ldb, int ldc,
           long sA, long sB, long sC,
           const float* __restrict__ bias, int act,
           const float* __restrict__ d0v, const float* __restrict__ rootv)
{
    __shared__ __half As[128][40];
    __shared__ __half Bs[64][40];
    const int bz = blockIdx.z;
    const half_t* A  = Ag + (long)bz * sA;
    const half_t* Bp = Bg + (long)bz * sB;
    const int m0 = blockIdx.y * 128, n0 = blockIdx.x * 64;
    const int tid = threadIdx.x;
    const int l = tid & 63, w = tid >> 6;
    const int wm = w & 1, wn = w >> 1;
    const int lr = l & 15, lq = l >> 4;

    f32x4 acc[4][2] = {};

    for (int k0 = 0; k0 < K; k0 += 32) {
        #pragma unroll
        for (int i = 0; i < 2; i++) {
            int ch = tid + i * 256;
            int r = ch >> 2, j = ch & 3;
            *(float4*)&As[r][j * 8] = *(const float4*)(A + (long)(m0 + r) * lda + k0 + j * 8);
        }
        if (!BNN) {
            int r = tid >> 2, j = tid & 3;
            *(float4*)&Bs[r][j * 8] = *(const float4*)(Bp + (long)(n0 + r) * ldb + k0 + j * 8);
        } else {
            int k = tid & 31, nc = tid >> 5;
            float4 v = *(const float4*)(Bp + (long)(k0 + k) * ldb + n0 + nc * 8);
            const __half* hv = (const __half*)&v;
            #pragma unroll
            for (int jj = 0; jj < 8; jj++) Bs[nc * 8 + jj][k] = hv[jj];
        }
        __syncthreads();

        f16x8 af[4], bf[2];
        #pragma unroll
        for (int mf = 0; mf < 4; mf++)
            af[mf] = *(const f16x8*)&As[wm * 64 + mf * 16 + lr][lq * 8];
        #pragma unroll
        for (int nf = 0; nf < 2; nf++)
            bf[nf] = *(const f16x8*)&Bs[wn * 32 + nf * 16 + lr][lq * 8];
        #pragma unroll
        for (int mf = 0; mf < 4; mf++)
            #pragma unroll
            for (int nf = 0; nf < 2; nf++)
                acc[mf][nf] = __builtin_amdgcn_mfma_f32_16x16x32_f16(af[mf], bf[nf], acc[mf][nf], 0, 0, 0);
        __syncthreads();
    }

    #pragma unroll
    for (int mf = 0; mf < 4; mf++) {
        #pragma unroll
        for (int nf = 0; nf < 2; nf++) {
            #pragma unroll
            for (int j = 0; j < 4; j++) {
                int m = m0 + wm * 64 + mf * 16 + lq * 4 + j;
                int n = n0 + wn * 32 + nf * 16 + lr;
                float v = acc[mf][nf][j];
                if (bias) v += bias[n];
                if (d0v)  v += d0v[(long)bz * M + m] * rootv[n];
                if (act == 1)      v = tanhf(v);
                else if (act == 2) v = (m == n) ? 0.f : expf(v);
                Cg[(long)bz * sC + (long)m * ldc + n] = __float2half(v);
            }
        }
    }
}

// ============ final: out = tanh(vs@W1^T + p@W2^T + c@W3^T + br) * mask ============
__global__ __launch_bounds__(256)
void mgemm_final(const half_t* __restrict__ A0, const half_t* __restrict__ A1,
                 const half_t* __restrict__ A2, const half_t* __restrict__ Bw,
                 float* __restrict__ Cout, const float* __restrict__ bias,
                 const float* __restrict__ maskp)
{
    __shared__ __half As[128][40];
    __shared__ __half Bs[64][40];
    const int m0 = blockIdx.y * 128, n0 = blockIdx.x * 64;
    const int tid = threadIdx.x;
    const int l = tid & 63, w = tid >> 6;
    const int wm = w & 1, wn = w >> 1;
    const int lr = l & 15, lq = l >> 4;

    f32x4 acc[4][2] = {};

    for (int k0 = 0; k0 < 1536; k0 += 32) {
        const half_t* A = (k0 < 512) ? A0 : (k0 < 1024) ? A1 : A2;
        const int kk = k0 & 511;
        #pragma unroll
        for (int i = 0; i < 2; i++) {
            int ch = tid + i * 256;
            int r = ch >> 2, j = ch & 3;
            *(float4*)&As[r][j * 8] = *(const float4*)(A + (long)(m0 + r) * 512 + kk + j * 8);
        }
        {
            int r = tid >> 2, j = tid & 3;
            *(float4*)&Bs[r][j * 8] = *(const float4*)(Bw + (long)(n0 + r) * 1536 + k0 + j * 8);
        }
        __syncthreads();
        f16x8 af[4], bf[2];
        #pragma unroll
        for (int mf = 0; mf < 4; mf++)
            af[mf] = *(const f16x8*)&As[wm * 64 + mf * 16 + lr][lq * 8];
        #pragma unroll
        for (int nf = 0; nf < 2; nf++)
            bf[nf] = *(const f16x8*)&Bs[wn * 32 + nf * 16 + lr][lq * 8];
        #pragma unroll
        for (int mf = 0; mf < 4; mf++)
            #pragma unroll
            for (int nf = 0; nf < 2; nf++)
                acc[mf][nf] = __builtin_amdgcn_mfma_f32_16x16x32_f16(af[mf], bf[nf], acc[mf][nf], 0, 0, 0);
        __syncthreads();
    }

    #pragma unroll
    for (int mf = 0; mf < 4; mf++) {
        #pragma unroll
        for (int nf = 0; nf < 2; nf++) {
            #pragma unroll
            for (int j = 0; j < 4; j++) {
                int m = m0 + wm * 64 + mf * 16 + lq * 4 + j;
                int n = n0 + wn * 32 + nf * 16 + lr;
                float v = tanhf(acc[mf][nf][j] + bias[n]) * maskp[m];
                Cout[(long)m * 512 + n] = v;
            }
        }
    }
}

// ======= G[ts][d][hd][b][q] = Wp@x + bp : 4 gates of one hd contiguous (8B) =======
__global__ __launch_bounds__(256)
void ggemm(const float* __restrict__ x, const half_t* __restrict__ Wp,
           const float* __restrict__ bp, half_t* __restrict__ G, int chunk)
{
    __shared__ __half As[128][40];
    __shared__ __half Bs[128][40];
    const int d = blockIdx.z;
    const int ts = blockIdx.y;
    const int m0 = blockIdx.x * 128;                 // packed gate rows
    const int t_orig = d ? (255 - (chunk * 128 + ts)) : (chunk * 128 + ts);
    const int tid = threadIdx.x;
    const int l = tid & 63, w = tid >> 6;
    const int wm = w & 1, wn = w >> 1;
    const int lr = l & 15, lq = l >> 4;

    f32x4 acc[4][4] = {};

    for (int k0 = 0; k0 < 320; k0 += 32) {
        #pragma unroll
        for (int i = 0; i < 2; i++) {
            int e = tid + i * 256;
            int r = e >> 2, j = (e & 3) * 8;
            *(float4*)&As[r][j] = *(const float4*)(Wp + ((long)d * 1536 + m0 + r) * 320 + k0 + j);
        }
        #pragma unroll
        for (int i = 0; i < 2; i++) {
            int e = tid + i * 256;
            int r = e >> 2, j = (e & 3) * 8;
            int k = k0 + j;
            int ka = (k + 4 <= 300) ? k : 0;
            int kb = (k + 8 <= 300) ? k + 4 : 0;
            const float* xp = x + ((long)r * 256 + t_orig) * 300;
            float4 va = *(const float4*)(xp + ka);
            float4 vb = *(const float4*)(xp + kb);
            __half* q = &Bs[r][j];
            q[0] = __float2half(va.x); q[1] = __float2half(va.y);
            q[2] = __float2half(va.z); q[3] = __float2half(va.w);
            q[4] = __float2half(vb.x); q[5] = __float2half(vb.y);
            q[6] = __float2half(vb.z); q[7] = __float2half(vb.w);
        }
        __syncthreads();
        f16x8 af[4], bf[4];
        #pragma unroll
        for (int gf = 0; gf < 4; gf++)
            af[gf] = *(const f16x8*)&As[wm * 64 + gf * 16 + lr][lq * 8];
        #pragma unroll
        for (int bi = 0; bi < 4; bi++)
            bf[bi] = *(const f16x8*)&Bs[wn * 64 + bi * 16 + lr][lq * 8];
        #pragma unroll
        for (int gf = 0; gf < 4; gf++)
            #pragma unroll
            for (int bi = 0; bi < 4; bi++)
                acc[gf][bi] = __builtin_amdgcn_mfma_f32_16x16x32_f16(af[gf], bf[bi], acc[gf][bi], 0, 0, 0);
        __syncthreads();
    }

    half_t* Gt = G + (long)(ts * 2 + d) * 196608;    // [hd 384][b 128][q 4]
    #pragma unroll
    for (int gf = 0; gf < 4; gf++) {
        #pragma unroll
        for (int bi = 0; bi < 4; bi++) {
            int g = m0 + wm * 64 + gf * 16 + lq * 4;  // first of 4 consecutive packed rows
            int b = wn * 64 + bi * 16 + lr;
            union { __half h[4]; float2 f; } u;
            #pragma unroll
            for (int j = 0; j < 4; j++)
                u.h[j] = __float2half(acc[gf][bi][j] + bp[d * 1536 + g + j]);
            *(float2*)(Gt + ((long)(g >> 2) * 128 + b) * 4) = u.f;
        }
    }
}

// ======= persistent BiLSTM scan: 96 WGs = d(2) x ntile(24) x btile(2); 128 steps =======
// h layout [p][d][b][hd]: MFMA B-frags direct from global. c-state in registers.
// Parallel flag barrier (per-WG cachelines) + G register prefetch across the barrier.
__global__ __launch_bounds__(256)
void lstm_scan(const half_t* __restrict__ G, const half_t* __restrict__ Whh,
               half_t* __restrict__ Hbuf, float* __restrict__ Cst,
               half_t* __restrict__ vs, half_t* __restrict__ vst,
               unsigned* __restrict__ flags, int chunk)
{
    __shared__ __half Wl[64 * 392];
    __shared__ __half hlo[16][68];

    const int bid = blockIdx.x;
    const int d = bid / 48, rem = bid % 48;
    const int ntile = rem >> 1, btile = rem & 1;
    const int grp = d * 2 + btile;                     // barrier group: 24 WGs
    const int tid = threadIdx.x;
    const int l = tid & 63, w = tid >> 6;
    const int wm = w & 1, wn = w >> 1;
    const int lr = l & 15, lq = l >> 4;

    // stage Whh slice once
    {
        const half_t* src = Whh + ((long)d * 1536 + ntile * 64) * 384;
        for (int e = tid; e < 3072; e += 256) {
            int r = e / 48, c = (e % 48) * 8;
            *(float4*)&Wl[r * 392 + c] = *(const float4*)(src + (long)r * 384 + c);
        }
    }
    // c-state in registers (4 per lane)
    float creg[4];
    if (chunk == 0) {
        creg[0] = creg[1] = creg[2] = creg[3] = 0.f;
    } else {
        #pragma unroll
        for (int i = 0; i < 4; i++) creg[i] = Cst[((long)bid * 256 + tid) * 4 + i];
    }

    // per-lane G offsets (element index within a step-slab)
    long goff[4];
    #pragma unroll
    for (int gf = 0; gf < 2; gf++)
        #pragma unroll
        for (int bf2 = 0; bf2 < 2; bf2++) {
            const int hdg = ntile * 16 + wm * 8 + gf * 4 + lq;
            const int bg  = btile * 64 + wn * 32 + bf2 * 16 + lr;
            goff[gf * 2 + bf2] = ((long)hdg * 128 + bg) * 4;
        }
    // preload G for step 0
    float2 gc0, gc1, gc2, gc3;
    {
        const half_t* gp0 = G + (long)(0 * 2 + d) * 196608;
        gc0 = *(const float2*)(gp0 + goff[0]);
        gc1 = *(const float2*)(gp0 + goff[1]);
        gc2 = *(const float2*)(gp0 + goff[2]);
        gc3 = *(const float2*)(gp0 + goff[3]);
    }
    __syncthreads();

    for (int s = 0; s < 128; ++s) {
        const int gstep = chunk * 128 + s;
        const int p = gstep & 1;
        const half_t* hin = Hbuf + (long)(p * 2 + d) * 128 * 384;   // [b][hd]

        // prefetch G for next step (independent of barrier/fence: G is immutable)
        float2 gn0, gn1, gn2, gn3;
        {
            const int sn = (s < 127) ? s + 1 : 127;
            const half_t* gpn = G + (long)(sn * 2 + d) * 196608;
            gn0 = *(const float2*)(gpn + goff[0]);
            gn1 = *(const float2*)(gpn + goff[1]);
            gn2 = *(const float2*)(gpn + goff[2]);
            gn3 = *(const float2*)(gpn + goff[3]);
        }

        f32x4 acc[2][2] = {};
        #pragma unroll
        for (int it = 0; it < 12; ++it) {
            f16x8 af[2], bf[2];
            #pragma unroll
            for (int gf = 0; gf < 2; gf++)
                af[gf] = *(const f16x8*)&Wl[(wm * 32 + gf * 16 + lr) * 392 + it * 32 + lq * 8];
            #pragma unroll
            for (int bf2 = 0; bf2 < 2; bf2++) {
                int bg = btile * 64 + wn * 32 + bf2 * 16 + lr;
                bf[bf2] = *(const f16x8*)(hin + (long)bg * 384 + it * 32 + lq * 8);
            }
            #pragma unroll
            for (int gf = 0; gf < 2; gf++)
                #pragma unroll
                for (int bf2 = 0; bf2 < 2; bf2++)
                    acc[gf][bf2] = __builtin_amdgcn_mfma_f32_16x16x32_f16(af[gf], bf[bf2], acc[gf][bf2], 0, 0, 0);
        }

        // epilogue: 4 gates of one hd are this lane's 4 acc regs
        #pragma unroll
        for (int gf = 0; gf < 2; gf++) {
            #pragma unroll
            for (int bf2 = 0; bf2 < 2; bf2++) {
                const int hd_l = wm * 8 + gf * 4 + lq;          // 0..15
                const int bl_  = wn * 32 + bf2 * 16 + lr;       // 0..63
                union { float2 f; __half h[4]; } gu;
                const int ci = gf * 2 + bf2;
                gu.f = (ci == 0) ? gc0 : (ci == 1) ? gc1 : (ci == 2) ? gc2 : gc3;
                float gi  = acc[gf][bf2][0] + __half2float(gu.h[0]);
                float gfo = acc[gf][bf2][1] + __half2float(gu.h[1]);
                float gg  = acc[gf][bf2][2] + __half2float(gu.h[2]);
                float go  = acc[gf][bf2][3] + __half2float(gu.h[3]);
                float c = creg[ci];
                float si = 1.f / (1.f + expf(-gi));
                float sf = 1.f / (1.f + expf(-gfo));
                float so = 1.f / (1.f + expf(-go));
                c = sf * c + si * tanhf(gg);
                creg[ci] = c;
                hlo[hd_l][bl_] = __float2half(so * tanhf(c));
            }
        }
        __syncthreads();

        // repack: 128 threads write 16B-vector h / vs / vst
        if (tid < 128) {
            const int b_l = tid & 63, h8 = tid >> 6;            // h8: 0..1
            f16x8 v;
            #pragma unroll
            for (int j = 0; j < 8; j++) v[j] = (_Float16)hlo[h8 * 8 + j][b_l];
            const int bg  = btile * 64 + b_l;
            const int hd0 = ntile * 16 + h8 * 8;
            *(f16x8*)(Hbuf + ((long)((p ^ 1) * 2 + d) * 128 + bg) * 384 + hd0) = v;
            const int t_orig = d ? 255 - gstep : gstep;
            const long m = (long)bg * 256 + t_orig;
            if (hd0 < 256) *(f16x8*)(vs  + m * 512 + d * 256 + hd0)         = v;
            else           *(f16x8*)(vst + m * 256 + d * 128 + (hd0 - 256)) = v;
        }

        if (s < 127) {   // parallel flag barrier over the 24-WG group
            __syncthreads();                                   // drains vmcnt (h stores in L2)
            if (tid == 0) {
                __threadfence();                               // L2 writeback to coherence point
                __hip_atomic_store(&flags[(grp * 24 + ntile) * 16], (unsigned)(gstep + 1),
                                   __ATOMIC_RELAXED, __HIP_MEMORY_SCOPE_AGENT);
            }
            const unsigned tgt = (unsigned)(gstep + 1);
            const unsigned fidx = (grp * 24 + (l % 24)) * 16;
            while (true) {
                unsigned v = __hip_atomic_load(&flags[fidx], __ATOMIC_ACQUIRE,
                                               __HIP_MEMORY_SCOPE_AGENT);
                if (__all(v >= tgt)) break;
                __builtin_amdgcn_s_sleep(1);
            }
        }
        gc0 = gn0; gc1 = gn1; gc2 = gn2; gc3 = gn3;
    }

    #pragma unroll
    for (int i = 0; i < 4; i++) Cst[((long)bid * 256 + tid) * 4 + i] = creg[i];
}

// ---------------- packs / converts ----------------
__global__ void pack_wih(const float* __restrict__ wf, const float* __restrict__ wb,
                         const float* __restrict__ bfv, const float* __restrict__ bbv,
                         half_t* __restrict__ Wp, float* __restrict__ bp)
{
    int i = blockIdx.x * 256 + threadIdx.x;
    if (i < 983040) {
        int k = i % 320, pr = (i / 320) % 1536, d = i / 491520;
        int q = pr & 3, hd = pr >> 2;
        float v = (k < 300) ? (d ? wb : wf)[(q * 384 + hd) * 300 + k] : 0.f;
        Wp[i] = __float2half(v);
    }
    if (i < 3072) {
        int d = i / 1536, pr = i % 1536;
        int q = pr & 3, hd = pr >> 2;
        bp[i] = (d ? bbv : bfv)[q * 384 + hd];
    }
}
__global__ void pack_whh(const float* __restrict__ wf, const float* __restrict__ wb,
                         half_t* __restrict__ Wh)
{
    int i = blockIdx.x * 256 + threadIdx.x;
    if (i >= 1179648) return;
    int k = i % 384, pr = (i / 384) % 1536, d = i / 589824;
    int q = pr & 3, hd = pr >> 2;
    Wh[i] = __float2half((d ? wb : wf)[(q * 384 + hd) * 384 + k]);
}
__global__ void conv16(const float* __restrict__ s, half_t* __restrict__ d, long n)
{
    long i = (long)blockIdx.x * 256 + threadIdx.x;
    if (i < n) d[i] = __float2half(s[i]);
}
__global__ void convT16(const float* __restrict__ s, half_t* __restrict__ d, int R, int C)
{
    int i = blockIdx.x * 256 + threadIdx.x;
    if (i >= R * C) return;
    int r = i / C, c = i % C;
    d[(long)c * R + r] = __float2half(s[i]);
}

// ---------------- f_r = exp(vst @ w_root^T) ----------------
__global__ __launch_bounds__(256)
void frow_kernel(const half_t* __restrict__ vst, const float* __restrict__ wroot,
                 float* __restrict__ fr)
{
    int row  = blockIdx.x * 4 + (threadIdx.x >> 6);
    int lane = threadIdx.x & 63;
    const half_t* v = vst + (long)row * 256;
    float s = 0.f;
    for (int k = lane; k < 256; k += 64) s += __half2float(v[k]) * wroot[k];
    #pragma unroll
    for (int off = 32; off; off >>= 1) s += __shfl_down(s, off);
    if (lane == 0) fr[row] = expf(s);
}

// ======= register-resident Gauss-Jordan inverse, 1024 threads =======
__global__ __launch_bounds__(1024)
void invert_gj(const half_t* __restrict__ fA, const float* __restrict__ fr,
               half_t* __restrict__ LLinv)
{
    __shared__ float colbuf[2][256];
    __shared__ float rowbuf[2][256];
    __shared__ float csum[4][256];
    const int bz = blockIdx.x;
    const half_t* A = fA + (long)bz * 65536;
    const int tid = threadIdx.x;
    const int c = tid & 255, rh = tid >> 8;
    float m[64];

    float s = 0.f;
    #pragma unroll
    for (int i = 0; i < 64; i++) {
        float v = __half2float(A[(long)(rh * 64 + i) * 256 + c]);
        m[i] = v; s += v;
    }
    csum[rh][c] = s;
    __syncthreads();
    float diag = csum[0][c] + csum[1][c] + csum[2][c] + csum[3][c];
    const float frv = fr[bz * 256 + c];
    #pragma unroll
    for (int i = 0; i < 64; i++) {
        int r = rh * 64 + i;
        float v = (r == c) ? ((diag == 0.f) ? 1.f : diag) : -m[i];
        if (rh == 0 && i == 0) {
            v = frv;
            if (c == 0 && v == 0.f) v = 1.f;
        }
        m[i] = v;
    }
    __syncthreads();

    for (int k = 0; k < 256; k++) {
        const int p = k & 1;
        const int kh = k >> 6, kl = k & 63;
        if (c == k) {
            #pragma unroll
            for (int i = 0; i < 64; i++) colbuf[p][rh * 64 + i] = m[i];
        }
        if (rh == kh) {
            float pv = 0.f;
            #pragma unroll
            for (int i = 0; i < 64; i++) pv = (i == kl) ? m[i] : pv;
            rowbuf[p][c] = pv;
        }
        __syncthreads();
        const float piv  = colbuf[p][k];
        const float pinv = 1.f / piv;
        const float rv   = rowbuf[p][c] * pinv;
        if (c == k) {
            #pragma unroll
            for (int i = 0; i < 64; i++) m[i] = -colbuf[p][rh * 64 + i] * pinv;
        } else {
            #pragma unroll
            for (int i = 0; i < 64; i++) m[i] -= colbuf[p][rh * 64 + i] * rv;
        }
        if (rh == kh) {
            const float dv = (c == k) ? pinv : rv;
            #pragma unroll
            for (int i = 0; i < 64; i++) m[i] = (i == kl) ? dv : m[i];
        }
    }

    #pragma unroll
    for (int i = 0; i < 64; i++)
        LLinv[(long)bz * 65536 + (long)(rh * 64 + i) * 256 + c] = __float2half(m[i]);
}

// ---------------- diag(LLinv) and d0 ----------------
__global__ void diag_d0_k(const half_t* __restrict__ LLinv, const float* __restrict__ fr,
                          float* __restrict__ diagv, float* __restrict__ d0)
{
    int i = blockIdx.x * 256 + threadIdx.x;
    if (i >= 32768) return;
    int b = i >> 8, s = i & 255;
    diagv[i] = __half2float(LLinv[(long)b * 65536 + s * 257]);
    d0[i]    = fr[i] * __half2float(LLinv[(long)b * 65536 + s * 256]);
}

// ---------------- a = A*(diag - LLinv^T), in place ----------------
__global__ __launch_bounds__(256)
void assemble_a(half_t* __restrict__ fA, const half_t* __restrict__ LLinv,
                const float* __restrict__ diagv)
{
    __shared__ float ll[32][33];
    const int bz = blockIdx.z;
    const int s0 = (blockIdx.x >> 3) * 32, t0 = (blockIdx.x & 7) * 32;
    const int tid = threadIdx.x;
    const long base = (long)bz * 65536;
    #pragma unroll
    for (int it = 0; it < 4; it++) {
        int i = (tid >> 5) + it * 8, j = tid & 31;
        ll[i][j] = __half2float(LLinv[base + (long)(t0 + i) * 256 + (s0 + j)]);
    }
    __syncthreads();
    #pragma unroll
    for (int it = 0; it < 4; it++) {
        int si = (tid >> 5) + it * 8, tj = tid & 31;
        int s = s0 + si, t = t0 + tj;
        long idx = base + (long)s * 256 + t;
        float Av = __half2float(fA[idx]);
        float t1 = (t > 0) ? diagv[(bz << 8) + t] : 0.f;
        float t2 = (s > 0) ? ll[tj][si] : 0.f;
        fA[idx] = __float2half(Av * (t1 - t2));
    }
}

// ---------------- batched 256x256 f16 transpose ----------------
__global__ __launch_bounds__(256)
void transpose256h(const half_t* __restrict__ in, half_t* __restrict__ out)
{
    __shared__ __half tb[32][33];
    const int bz = blockIdx.z;
    const half_t* ip = in  + (long)bz * 65536;
    half_t*       op = out + (long)bz * 65536;
    int x0 = blockIdx.x * 32, y0 = blockIdx.y * 32;
    int tx = threadIdx.x, ty = threadIdx.y;
    #pragma unroll
    for (int r = 0; r < 4; r++)
        tb[ty + 8 * r][tx] = ip[(long)(y0 + ty + 8 * r) * 256 + x0 + tx];
    __syncthreads();
    #pragma unroll
    for (int r = 0; r < 4; r++)
        op[(long)(x0 + ty + 8 * r) * 256 + y0 + tx] = tb[tx][ty + 8 * r];
}

// ---------------- emb = max over sequence (coalesced) ----------------
__global__ __launch_bounds__(256)
void emb_max(const float* __restrict__ outp, float* __restrict__ emb)
{
    int b = blockIdx.x;
    for (int n = threadIdx.x; n < 512; n += 256) {
        const float* p = outp + (long)b * 131072 + n;
        float mx = -3.4e38f;
        for (int t = 0; t < 256; t++) mx = fmaxf(mx, p[(long)t * 512]);
        emb[b * 512 + n] = mx;
    }
}

__global__ void diag_ws(float* out, int n, float v)
{
    int i = blockIdx.x * 256 + threadIdx.x;
    if (i < n) out[i] = v;
}

// ======================= host launch =======================
extern "C" void kernel_launch(void* const* d_in, const int* in_sizes, int n_in,
                              void* d_out, int out_size, void* d_ws, size_t ws_size,
                              hipStream_t stream)
{
    const float* x     = (const float*)d_in[0];
    const float* mask  = (const float*)d_in[1];
    const float* wihf  = (const float*)d_in[2];
    const float* whhf  = (const float*)d_in[3];
    const float* bf    = (const float*)d_in[4];
    const float* wihb  = (const float*)d_in[5];
    const float* whhb  = (const float*)d_in[6];
    const float* bb    = (const float*)d_in[7];
    const float* wtp   = (const float*)d_in[8];
    const float* btp   = (const float*)d_in[9];
    const float* wtc   = (const float*)d_in[10];
    const float* btc   = (const float*)d_in[11];
    const float* wa    = (const float*)d_in[12];
    const float* wroot = (const float*)d_in[13];
    const float* remb  = (const float*)d_in[14];
    const float* wr    = (const float*)d_in[15];
    const float* br    = (const float*)d_in[16];

    if (ws_size < 134217728ULL) {
        float enc = 100.0f + (float)((double)ws_size * 1e-9);
        diag_ws<<<dim3((out_size + 255) / 256), 256, 0, stream>>>((float*)d_out, out_size, enc);
        return;
    }

    char* ws = (char*)d_ws;
    half_t* G     = (half_t*)(ws + 0);              // 100,663,296 B per-chunk gates
    half_t* vs    = (half_t*)(ws + 100663296);      // 33,554,432 B
    half_t* tp    = (half_t*)(ws + 0 * SEG);        // post-scan overlays of G region
    half_t* tc    = (half_t*)(ws + 1 * SEG);
    half_t* tmp   = (half_t*)(ws + 2 * SEG);
    half_t* fA    = (half_t*)(ws + 3 * SEG);
    half_t* LL    = (half_t*)(ws + 4 * SEG);
    half_t* aT    = (half_t*)(ws + 5 * SEG);
    half_t* cbuf  = (half_t*)(ws + 0 * SEG);
    half_t* pbuf  = (half_t*)(ws + 2 * SEG);
    half_t* wr16  = (half_t*)(ws + 4 * SEG);

    // dead-until-final region of d_out hosts scan state + small weights
    float* ob = (float*)d_out;
    half_t*   Wp16  = (half_t*)(ob + 11000000);   // 983,040 f16
    half_t*   Whh16 = (half_t*)(ob + 11491520);   // 1,179,648 f16
    float*    bp    = ob + 12081344;
    half_t*   wtp16 = (half_t*)(ob + 12084416);
    half_t*   wtc16 = (half_t*)(ob + 12117184);
    half_t*   wa16T = (half_t*)(ob + 12149952);
    float*    fr    = ob + 12182720;
    float*    d0    = ob + 12215488;
    float*    diagv = ob + 12248256;
    float*    Cst   = ob + 12281024;              // 96*256*4 f32 = 393,216 B
    half_t*   Hbuf  = (half_t*)(ob + 12379328);   // [2 p][2 d][128 b][384 hd] f16
    unsigned* flags = (unsigned*)(ob + 12500000); // 96 x 64B flag lines = 6144 B
    half_t*   vst   = (half_t*)(ob + 12648448);   // 32768 x 256 f16

    float* emb  = (float*)d_out;
    float* outp = (float*)d_out + 65536;

    // 0. init state + pack weights
    hipMemsetAsync(Hbuf, 0, 393216, stream);
    hipMemsetAsync(flags, 0, 6144, stream);
    pack_wih<<<dim3(3840), 256, 0, stream>>>(wihf, wihb, bf, bb, Wp16, bp);
    pack_whh<<<dim3(4608), 256, 0, stream>>>(whhf, whhb, Whh16);
    conv16<<<dim3(256), 256, 0, stream>>>(wtp, wtp16, 65536);
    conv16<<<dim3(256), 256, 0, stream>>>(wtc, wtc16, 65536);
    convT16<<<dim3(256), 256, 0, stream>>>(wa, wa16T, 256, 256);

    // 1. chunked: G GEMM + persistent 128-step scan, twice (flags monotonic via gstep)
    for (int c = 0; c < 2; c++) {
        ggemm<<<dim3(12, 128, 2), 256, 0, stream>>>(x, Wp16, bp, G, c);
        lstm_scan<<<dim3(96), 256, 0, stream>>>(G, Whh16, Hbuf, Cst, vs, vst, flags, c);
    }

    // 2. f_r
    frow_kernel<<<dim3(8192), 256, 0, stream>>>(vst, wroot, fr);

    // 3. tp / tc = tanh(vst @ W^T + b)
    mgemm<false><<<dim3(4, 256, 1), 256, 0, stream>>>(
        vst, wtp16, tp, M_, 256, 256, 256, 256, 256, 0, 0, 0, btp, 1, nullptr, nullptr);
    mgemm<false><<<dim3(4, 256, 1), 256, 0, stream>>>(
        vst, wtc16, tc, M_, 256, 256, 256, 256, 256, 0, 0, 0, btc, 1, nullptr, nullptr);

    // 4. tmp = tp @ w_a
    mgemm<false><<<dim3(4, 256, 1), 256, 0, stream>>>(
        tp, wa16T, tmp, M_, 256, 256, 256, 256, 256, 0, 0, 0, nullptr, 0, nullptr, nullptr);

    // 5. f = exp(tmp @ tc^T), diag zeroed (batched)
    mgemm<false><<<dim3(4, 2, 128), 256, 0, stream>>>(
        tmp, tc, fA, 256, 256, 256, 256, 256, 256, 65536, 65536, 65536,
        nullptr, 2, nullptr, nullptr);

    // 6-8. inverse, diag/d0, assemble
    invert_gj<<<dim3(128), 1024, 0, stream>>>(fA, fr, LL);
    diag_d0_k<<<dim3(128), 256, 0, stream>>>(LL, fr, diagv, d0);
    assemble_a<<<dim3(64, 1, 128), 256, 0, stream>>>(fA, LL, diagv);

    // 9. wr -> f16 (LL dead now)
    conv16<<<dim3(3072), 256, 0, stream>>>(wr, wr16, 786432);

    // 10. aT
    transpose256h<<<dim3(8, 8, 128), dim3(32, 8), 0, stream>>>(fA, aT);

    // 11. c = a @ vs
    mgemm<true><<<dim3(8, 2, 128), 256, 0, stream>>>(
        fA, vs, cbuf, 256, 512, 256, 256, 512, 512, 65536, 131072, 131072,
        nullptr, 0, nullptr, nullptr);

    // 12. p = aT @ vs + d0 (x) root_emb
    mgemm<true><<<dim3(8, 2, 128), 256, 0, stream>>>(
        aT, vs, pbuf, 256, 512, 256, 256, 512, 512, 65536, 131072, 131072,
        nullptr, 0, d0, remb);

    // 13. out = tanh([vs|p|c] @ wr^T + br) * mask
    mgemm_final<<<dim3(8, 256, 1), 256, 0, stream>>>(vs, pbuf, cbuf, wr16, outp, br, mask);

    // 14. emb
    emb_max<<<dim3(128), 256, 0, stream>>>(outp, emb);
}

// Round 9
// 4759.864 us; speedup vs baseline: 4.3589x; 1.0252x over previous
//
#include <hip/hip_runtime.h>
#include <hip/hip_fp16.h>
#include <math.h>

#define B_    128
#define S_    256
#define WORD_ 300
#define HD_   384
#define M_    32768
#define STRU_ 256
#define SEMA_ 512
#define SEG   16777216L

typedef __half half_t;
typedef _Float16 f16x8 __attribute__((ext_vector_type(8)));
typedef float    f32x4 __attribute__((ext_vector_type(4)));

// ================= MFMA GEMM: C(f16) = act(A @ B(.T) + bias + d0*root) =================
template<bool BNN>
__global__ __launch_bounds__(256)
void mgemm(const half_t* __restrict__ Ag, const half_t* __restrict__ Bg,
           half_t* __restrict__ Cg,
           int M, int N, int K, int lda, int ldb, int ldc,
           long sA, long sB, long sC,
           const float* __restrict__ bias, int act,
           const float* __restrict__ d0v, const float* __restrict__ rootv)
{
    __shared__ __half As[128][40];
    __shared__ __half Bs[64][40];
    const int bz = blockIdx.z;
    const half_t* A  = Ag + (long)bz * sA;
    const half_t* Bp = Bg + (long)bz * sB;
    const int m0 = blockIdx.y * 128, n0 = blockIdx.x * 64;
    const int tid = threadIdx.x;
    const int l = tid & 63, w = tid >> 6;
    const int wm = w & 1, wn = w >> 1;
    const int lr = l & 15, lq = l >> 4;

    f32x4 acc[4][2] = {};

    for (int k0 = 0; k0 < K; k0 += 32) {
        #pragma unroll
        for (int i = 0; i < 2; i++) {
            int ch = tid + i * 256;
            int r = ch >> 2, j = ch & 3;
            *(float4*)&As[r][j * 8] = *(const float4*)(A + (long)(m0 + r) * lda + k0 + j * 8);
        }
        if (!BNN) {
            int r = tid >> 2, j = tid & 3;
            *(float4*)&Bs[r][j * 8] = *(const float4*)(Bp + (long)(n0 + r) * ldb + k0 + j * 8);
        } else {
            int k = tid & 31, nc = tid >> 5;
            float4 v = *(const float4*)(Bp + (long)(k0 + k) * ldb + n0 + nc * 8);
            const __half* hv = (const __half*)&v;
            #pragma unroll
            for (int jj = 0; jj < 8; jj++) Bs[nc * 8 + jj][k] = hv[jj];
        }
        __syncthreads();

        f16x8 af[4], bf[2];
        #pragma unroll
        for (int mf = 0; mf < 4; mf++)
            af[mf] = *(const f16x8*)&As[wm * 64 + mf * 16 + lr][lq * 8];
        #pragma unroll
        for (int nf = 0; nf < 2; nf++)
            bf[nf] = *(const f16x8*)&Bs[wn * 32 + nf * 16 + lr][lq * 8];
        #pragma unroll
        for (int mf = 0; mf < 4; mf++)
            #pragma unroll
            for (int nf = 0; nf < 2; nf++)
                acc[mf][nf] = __builtin_amdgcn_mfma_f32_16x16x32_f16(af[mf], bf[nf], acc[mf][nf], 0, 0, 0);
        __syncthreads();
    }

    #pragma unroll
    for (int mf = 0; mf < 4; mf++) {
        #pragma unroll
        for (int nf = 0; nf < 2; nf++) {
            #pragma unroll
            for (int j = 0; j < 4; j++) {
                int m = m0 + wm * 64 + mf * 16 + lq * 4 + j;
                int n = n0 + wn * 32 + nf * 16 + lr;
                float v = acc[mf][nf][j];
                if (bias) v += bias[n];
                if (d0v)  v += d0v[(long)bz * M + m] * rootv[n];
                if (act == 1)      v = tanhf(v);
                else if (act == 2) v = (m == n) ? 0.f : expf(v);
                Cg[(long)bz * sC + (long)m * ldc + n] = __float2half(v);
            }
        }
    }
}

// ============ final: out = tanh(vs@W1^T + p@W2^T + c@W3^T + br) * mask ============
__global__ __launch_bounds__(256)
void mgemm_final(const half_t* __restrict__ A0, const half_t* __restrict__ A1,
                 const half_t* __restrict__ A2, const half_t* __restrict__ Bw,
                 float* __restrict__ Cout, const float* __restrict__ bias,
                 const float* __restrict__ maskp)
{
    __shared__ __half As[128][40];
    __shared__ __half Bs[64][40];
    const int m0 = blockIdx.y * 128, n0 = blockIdx.x * 64;
    const int tid = threadIdx.x;
    const int l = tid & 63, w = tid >> 6;
    const int wm = w & 1, wn = w >> 1;
    const int lr = l & 15, lq = l >> 4;

    f32x4 acc[4][2] = {};

    for (int k0 = 0; k0 < 1536; k0 += 32) {
        const half_t* A = (k0 < 512) ? A0 : (k0 < 1024) ? A1 : A2;
        const int kk = k0 & 511;
        #pragma unroll
        for (int i = 0; i < 2; i++) {
            int ch = tid + i * 256;
            int r = ch >> 2, j = ch & 3;
            *(float4*)&As[r][j * 8] = *(const float4*)(A + (long)(m0 + r) * 512 + kk + j * 8);
        }
        {
            int r = tid >> 2, j = tid & 3;
            *(float4*)&Bs[r][j * 8] = *(const float4*)(Bw + (long)(n0 + r) * 1536 + k0 + j * 8);
        }
        __syncthreads();
        f16x8 af[4], bf[2];
        #pragma unroll
        for (int mf = 0; mf < 4; mf++)
            af[mf] = *(const f16x8*)&As[wm * 64 + mf * 16 + lr][lq * 8];
        #pragma unroll
        for (int nf = 0; nf < 2; nf++)
            bf[nf] = *(const f16x8*)&Bs[wn * 32 + nf * 16 + lr][lq * 8];
        #pragma unroll
        for (int mf = 0; mf < 4; mf++)
            #pragma unroll
            for (int nf = 0; nf < 2; nf++)
                acc[mf][nf] = __builtin_amdgcn_mfma_f32_16x16x32_f16(af[mf], bf[nf], acc[mf][nf], 0, 0, 0);
        __syncthreads();
    }

    #pragma unroll
    for (int mf = 0; mf < 4; mf++) {
        #pragma unroll
        for (int nf = 0; nf < 2; nf++) {
            #pragma unroll
            for (int j = 0; j < 4; j++) {
                int m = m0 + wm * 64 + mf * 16 + lq * 4 + j;
                int n = n0 + wn * 32 + nf * 16 + lr;
                float v = tanhf(acc[mf][nf][j] + bias[n]) * maskp[m];
                Cout[(long)m * 512 + n] = v;
            }
        }
    }
}

// ======= G[ts][d][hd][b][q] = Wp@x + bp : 4 gates of one hd contiguous (8B) =======
__global__ __launch_bounds__(256)
void ggemm(const float* __restrict__ x, const half_t* __restrict__ Wp,
           const float* __restrict__ bp, half_t* __restrict__ G, int chunk)
{
    __shared__ __half As[128][40];
    __shared__ __half Bs[128][40];
    const int d = blockIdx.z;
    const int ts = blockIdx.y;
    const int m0 = blockIdx.x * 128;                 // packed gate rows
    const int t_orig = d ? (255 - (chunk * 128 + ts)) : (chunk * 128 + ts);
    const int tid = threadIdx.x;
    const int l = tid & 63, w = tid >> 6;
    const int wm = w & 1, wn = w >> 1;
    const int lr = l & 15, lq = l >> 4;

    f32x4 acc[4][4] = {};

    for (int k0 = 0; k0 < 320; k0 += 32) {
        #pragma unroll
        for (int i = 0; i < 2; i++) {
            int e = tid + i * 256;
            int r = e >> 2, j = (e & 3) * 8;
            *(float4*)&As[r][j] = *(const float4*)(Wp + ((long)d * 1536 + m0 + r) * 320 + k0 + j);
        }
        #pragma unroll
        for (int i = 0; i < 2; i++) {
            int e = tid + i * 256;
            int r = e >> 2, j = (e & 3) * 8;
            int k = k0 + j;
            int ka = (k + 4 <= 300) ? k : 0;
            int kb = (k + 8 <= 300) ? k + 4 : 0;
            const float* xp = x + ((long)r * 256 + t_orig) * 300;
            float4 va = *(const float4*)(xp + ka);
            float4 vb = *(const float4*)(xp + kb);
            __half* q = &Bs[r][j];
            q[0] = __float2half(va.x); q[1] = __float2half(va.y);
            q[2] = __float2half(va.z); q[3] = __float2half(va.w);
            q[4] = __float2half(vb.x); q[5] = __float2half(vb.y);
            q[6] = __float2half(vb.z); q[7] = __float2half(vb.w);
        }
        __syncthreads();
        f16x8 af[4], bf[4];
        #pragma unroll
        for (int gf = 0; gf < 4; gf++)
            af[gf] = *(const f16x8*)&As[wm * 64 + gf * 16 + lr][lq * 8];
        #pragma unroll
        for (int bi = 0; bi < 4; bi++)
            bf[bi] = *(const f16x8*)&Bs[wn * 64 + bi * 16 + lr][lq * 8];
        #pragma unroll
        for (int gf = 0; gf < 4; gf++)
            #pragma unroll
            for (int bi = 0; bi < 4; bi++)
                acc[gf][bi] = __builtin_amdgcn_mfma_f32_16x16x32_f16(af[gf], bf[bi], acc[gf][bi], 0, 0, 0);
        __syncthreads();
    }

    half_t* Gt = G + (long)(ts * 2 + d) * 196608;    // [hd 384][b 128][q 4]
    #pragma unroll
    for (int gf = 0; gf < 4; gf++) {
        #pragma unroll
        for (int bi = 0; bi < 4; bi++) {
            int g = m0 + wm * 64 + gf * 16 + lq * 4;  // first of 4 consecutive packed rows
            int b = wn * 64 + bi * 16 + lr;
            union { __half h[4]; float2 f; } u;
            #pragma unroll
            for (int j = 0; j < 4; j++)
                u.h[j] = __float2half(acc[gf][bi][j] + bp[d * 1536 + g + j]);
            *(float2*)(Gt + ((long)(g >> 2) * 128 + b) * 4) = u.f;
        }
    }
}

// ======= persistent BiLSTM scan: 96 WGs = d(2) x ntile(24) x btile(2); 128 steps =======
// h layout [p][d][b][hd]: MFMA B-frags direct from global. c-state in registers.
// vs/vst via NON-TEMPORAL stores (keeps L2 clean -> cheap release writeback).
// Barrier: release-store flag; RELAXED polls (no per-poll L2 invalidate);
// single acquire fence after the poll succeeds.
__global__ __launch_bounds__(256)
void lstm_scan(const half_t* __restrict__ G, const half_t* __restrict__ Whh,
               half_t* __restrict__ Hbuf, float* __restrict__ Cst,
               half_t* __restrict__ vs, half_t* __restrict__ vst,
               unsigned* __restrict__ flags, int chunk)
{
    __shared__ __half Wl[64 * 392];
    __shared__ __half hlo[16][68];

    const int bid = blockIdx.x;
    const int d = bid / 48, rem = bid % 48;
    const int ntile = rem >> 1, btile = rem & 1;
    const int grp = d * 2 + btile;                     // barrier group: 24 WGs
    const int tid = threadIdx.x;
    const int l = tid & 63, w = tid >> 6;
    const int wm = w & 1, wn = w >> 1;
    const int lr = l & 15, lq = l >> 4;

    // stage Whh slice once
    {
        const half_t* src = Whh + ((long)d * 1536 + ntile * 64) * 384;
        for (int e = tid; e < 3072; e += 256) {
            int r = e / 48, c = (e % 48) * 8;
            *(float4*)&Wl[r * 392 + c] = *(const float4*)(src + (long)r * 384 + c);
        }
    }
    // c-state in registers (4 per lane)
    float creg[4];
    if (chunk == 0) {
        creg[0] = creg[1] = creg[2] = creg[3] = 0.f;
    } else {
        #pragma unroll
        for (int i = 0; i < 4; i++) creg[i] = Cst[((long)bid * 256 + tid) * 4 + i];
    }

    // per-lane G offsets (element index within a step-slab)
    long goff[4];
    #pragma unroll
    for (int gf = 0; gf < 2; gf++)
        #pragma unroll
        for (int bf2 = 0; bf2 < 2; bf2++) {
            const int hdg = ntile * 16 + wm * 8 + gf * 4 + lq;
            const int bg  = btile * 64 + wn * 32 + bf2 * 16 + lr;
            goff[gf * 2 + bf2] = ((long)hdg * 128 + bg) * 4;
        }
    // preload G for step 0
    float2 gc0, gc1, gc2, gc3;
    {
        const half_t* gp0 = G + (long)(0 * 2 + d) * 196608;
        gc0 = *(const float2*)(gp0 + goff[0]);
        gc1 = *(const float2*)(gp0 + goff[1]);
        gc2 = *(const float2*)(gp0 + goff[2]);
        gc3 = *(const float2*)(gp0 + goff[3]);
    }
    __syncthreads();

    for (int s = 0; s < 128; ++s) {
        const int gstep = chunk * 128 + s;
        const int p = gstep & 1;
        const half_t* hin = Hbuf + (long)(p * 2 + d) * 128 * 384;   // [b][hd]

        // prefetch G for next step (G immutable during scan)
        float2 gn0, gn1, gn2, gn3;
        {
            const int sn = (s < 127) ? s + 1 : 127;
            const half_t* gpn = G + (long)(sn * 2 + d) * 196608;
            gn0 = *(const float2*)(gpn + goff[0]);
            gn1 = *(const float2*)(gpn + goff[1]);
            gn2 = *(const float2*)(gpn + goff[2]);
            gn3 = *(const float2*)(gpn + goff[3]);
        }

        f32x4 acc[2][2] = {};
        #pragma unroll
        for (int it = 0; it < 12; ++it) {
            f16x8 af[2], bf[2];
            #pragma unroll
            for (int gf = 0; gf < 2; gf++)
                af[gf] = *(const f16x8*)&Wl[(wm * 32 + gf * 16 + lr) * 392 + it * 32 + lq * 8];
            #pragma unroll
            for (int bf2 = 0; bf2 < 2; bf2++) {
                int bg = btile * 64 + wn * 32 + bf2 * 16 + lr;
                bf[bf2] = *(const f16x8*)(hin + (long)bg * 384 + it * 32 + lq * 8);
            }
            #pragma unroll
            for (int gf = 0; gf < 2; gf++)
                #pragma unroll
                for (int bf2 = 0; bf2 < 2; bf2++)
                    acc[gf][bf2] = __builtin_amdgcn_mfma_f32_16x16x32_f16(af[gf], bf[bf2], acc[gf][bf2], 0, 0, 0);
        }

        // epilogue: 4 gates of one hd are this lane's 4 acc regs
        #pragma unroll
        for (int gf = 0; gf < 2; gf++) {
            #pragma unroll
            for (int bf2 = 0; bf2 < 2; bf2++) {
                const int hd_l = wm * 8 + gf * 4 + lq;          // 0..15
                const int bl_  = wn * 32 + bf2 * 16 + lr;       // 0..63
                union { float2 f; __half h[4]; } gu;
                const int ci = gf * 2 + bf2;
                gu.f = (ci == 0) ? gc0 : (ci == 1) ? gc1 : (ci == 2) ? gc2 : gc3;
                float gi  = acc[gf][bf2][0] + __half2float(gu.h[0]);
                float gfo = acc[gf][bf2][1] + __half2float(gu.h[1]);
                float gg  = acc[gf][bf2][2] + __half2float(gu.h[2]);
                float go  = acc[gf][bf2][3] + __half2float(gu.h[3]);
                float c = creg[ci];
                float si = 1.f / (1.f + expf(-gi));
                float sf = 1.f / (1.f + expf(-gfo));
                float so = 1.f / (1.f + expf(-go));
                c = sf * c + si * tanhf(gg);
                creg[ci] = c;
                hlo[hd_l][bl_] = __float2half(so * tanhf(c));
            }
        }
        __syncthreads();

        // repack: 128 threads write 16B-vector h (normal) / vs / vst (non-temporal)
        if (tid < 128) {
            const int b_l = tid & 63, h8 = tid >> 6;            // h8: 0..1
            f16x8 v;
            #pragma unroll
            for (int j = 0; j < 8; j++) v[j] = (_Float16)hlo[h8 * 8 + j][b_l];
            const int bg  = btile * 64 + b_l;
            const int hd0 = ntile * 16 + h8 * 8;
            *(f16x8*)(Hbuf + ((long)((p ^ 1) * 2 + d) * 128 + bg) * 384 + hd0) = v;
            const int t_orig = d ? 255 - gstep : gstep;
            const long m = (long)bg * 256 + t_orig;
            if (hd0 < 256)
                __builtin_nontemporal_store(v, (f16x8*)(vs + m * 512 + d * 256 + hd0));
            else
                __builtin_nontemporal_store(v, (f16x8*)(vst + m * 256 + d * 128 + (hd0 - 256)));
        }

        if (s < 127) {   // flag barrier over the 24-WG group
            __syncthreads();                                   // drains vmcnt (h stores issued)
            if (tid == 0)
                __hip_atomic_store(&flags[(grp * 24 + ntile) * 16], (unsigned)(gstep + 1),
                                   __ATOMIC_RELEASE, __HIP_MEMORY_SCOPE_AGENT);
            const unsigned tgt = (unsigned)(gstep + 1);
            const unsigned fidx = (grp * 24 + (l % 24)) * 16;
            while (true) {
                unsigned v = __hip_atomic_load(&flags[fidx], __ATOMIC_RELAXED,
                                               __HIP_MEMORY_SCOPE_AGENT);
                if (__all(v >= tgt)) break;
                __builtin_amdgcn_s_sleep(1);
            }
            __threadfence();                                   // one acquire fence per step
        }
        gc0 = gn0; gc1 = gn1; gc2 = gn2; gc3 = gn3;
    }

    #pragma unroll
    for (int i = 0; i < 4; i++) Cst[((long)bid * 256 + tid) * 4 + i] = creg[i];
}

// ---------------- packs / converts ----------------
__global__ void pack_wih(const float* __restrict__ wf, const float* __restrict__ wb,
                         const float* __restrict__ bfv, const float* __restrict__ bbv,
                         half_t* __restrict__ Wp, float* __restrict__ bp)
{
    int i = blockIdx.x * 256 + threadIdx.x;
    if (i < 983040) {
        int k = i % 320, pr = (i / 320) % 1536, d = i / 491520;
        int q = pr & 3, hd = pr >> 2;
        float v = (k < 300) ? (d ? wb : wf)[(q * 384 + hd) * 300 + k] : 0.f;
        Wp[i] = __float2half(v);
    }
    if (i < 3072) {
        int d = i / 1536, pr = i % 1536;
        int q = pr & 3, hd = pr >> 2;
        bp[i] = (d ? bbv : bfv)[q * 384 + hd];
    }
}
__global__ void pack_whh(const float* __restrict__ wf, const float* __restrict__ wb,
                         half_t* __restrict__ Wh)
{
    int i = blockIdx.x * 256 + threadIdx.x;
    if (i >= 1179648) return;
    int k = i % 384, pr = (i / 384) % 1536, d = i / 589824;
    int q = pr & 3, hd = pr >> 2;
    Wh[i] = __float2half((d ? wb : wf)[(q * 384 + hd) * 384 + k]);
}
__global__ void conv16(const float* __restrict__ s, half_t* __restrict__ d, long n)
{
    long i = (long)blockIdx.x * 256 + threadIdx.x;
    if (i < n) d[i] = __float2half(s[i]);
}
__global__ void convT16(const float* __restrict__ s, half_t* __restrict__ d, int R, int C)
{
    int i = blockIdx.x * 256 + threadIdx.x;
    if (i >= R * C) return;
    int r = i / C, c = i % C;
    d[(long)c * R + r] = __float2half(s[i]);
}

// ---------------- f_r = exp(vst @ w_root^T) ----------------
__global__ __launch_bounds__(256)
void frow_kernel(const half_t* __restrict__ vst, const float* __restrict__ wroot,
                 float* __restrict__ fr)
{
    int row  = blockIdx.x * 4 + (threadIdx.x >> 6);
    int lane = threadIdx.x & 63;
    const half_t* v = vst + (long)row * 256;
    float s = 0.f;
    for (int k = lane; k < 256; k += 64) s += __half2float(v[k]) * wroot[k];
    #pragma unroll
    for (int off = 32; off; off >>= 1) s += __shfl_down(s, off);
    if (lane == 0) fr[row] = expf(s);
}

// ======= register-resident Gauss-Jordan inverse, 1024 threads =======
__global__ __launch_bounds__(1024)
void invert_gj(const half_t* __restrict__ fA, const float* __restrict__ fr,
               half_t* __restrict__ LLinv)
{
    __shared__ float colbuf[2][256];
    __shared__ float rowbuf[2][256];
    __shared__ float csum[4][256];
    const int bz = blockIdx.x;
    const half_t* A = fA + (long)bz * 65536;
    const int tid = threadIdx.x;
    const int c = tid & 255, rh = tid >> 8;
    float m[64];

    float s = 0.f;
    #pragma unroll
    for (int i = 0; i < 64; i++) {
        float v = __half2float(A[(long)(rh * 64 + i) * 256 + c]);
        m[i] = v; s += v;
    }
    csum[rh][c] = s;
    __syncthreads();
    float diag = csum[0][c] + csum[1][c] + csum[2][c] + csum[3][c];
    const float frv = fr[bz * 256 + c];
    #pragma unroll
    for (int i = 0; i < 64; i++) {
        int r = rh * 64 + i;
        float v = (r == c) ? ((diag == 0.f) ? 1.f : diag) : -m[i];
        if (rh == 0 && i == 0) {
            v = frv;
            if (c == 0 && v == 0.f) v = 1.f;
        }
        m[i] = v;
    }
    __syncthreads();

    for (int k = 0; k < 256; k++) {
        const int p = k & 1;
        const int kh = k >> 6, kl = k & 63;
        if (c == k) {
            #pragma unroll
            for (int i = 0; i < 64; i++) colbuf[p][rh * 64 + i] = m[i];
        }
        if (rh == kh) {
            float pv = 0.f;
            #pragma unroll
            for (int i = 0; i < 64; i++) pv = (i == kl) ? m[i] : pv;
            rowbuf[p][c] = pv;
        }
        __syncthreads();
        const float piv  = colbuf[p][k];
        const float pinv = 1.f / piv;
        const float rv   = rowbuf[p][c] * pinv;
        if (c == k) {
            #pragma unroll
            for (int i = 0; i < 64; i++) m[i] = -colbuf[p][rh * 64 + i] * pinv;
        } else {
            #pragma unroll
            for (int i = 0; i < 64; i++) m[i] -= colbuf[p][rh * 64 + i] * rv;
        }
        if (rh == kh) {
            const float dv = (c == k) ? pinv : rv;
            #pragma unroll
            for (int i = 0; i < 64; i++) m[i] = (i == kl) ? dv : m[i];
        }
    }

    #pragma unroll
    for (int i = 0; i < 64; i++)
        LLinv[(long)bz * 65536 + (long)(rh * 64 + i) * 256 + c] = __float2half(m[i]);
}

// ---------------- diag(LLinv) and d0 ----------------
__global__ void diag_d0_k(const half_t* __restrict__ LLinv, const float* __restrict__ fr,
                          float* __restrict__ diagv, float* __restrict__ d0)
{
    int i = blockIdx.x * 256 + threadIdx.x;
    if (i >= 32768) return;
    int b = i >> 8, s = i & 255;
    diagv[i] = __half2float(LLinv[(long)b * 65536 + s * 257]);
    d0[i]    = fr[i] * __half2float(LLinv[(long)b * 65536 + s * 256]);
}

// ---------------- a = A*(diag - LLinv^T), in place ----------------
__global__ __launch_bounds__(256)
void assemble_a(half_t* __restrict__ fA, const half_t* __restrict__ LLinv,
                const float* __restrict__ diagv)
{
    __shared__ float ll[32][33];
    const int bz = blockIdx.z;
    const int s0 = (blockIdx.x >> 3) * 32, t0 = (blockIdx.x & 7) * 32;
    const int tid = threadIdx.x;
    const long base = (long)bz * 65536;
    #pragma unroll
    for (int it = 0; it < 4; it++) {
        int i = (tid >> 5) + it * 8, j = tid & 31;
        ll[i][j] = __half2float(LLinv[base + (long)(t0 + i) * 256 + (s0 + j)]);
    }
    __syncthreads();
    #pragma unroll
    for (int it = 0; it < 4; it++) {
        int si = (tid >> 5) + it * 8, tj = tid & 31;
        int s = s0 + si, t = t0 + tj;
        long idx = base + (long)s * 256 + t;
        float Av = __half2float(fA[idx]);
        float t1 = (t > 0) ? diagv[(bz << 8) + t] : 0.f;
        float t2 = (s > 0) ? ll[tj][si] : 0.f;
        fA[idx] = __float2half(Av * (t1 - t2));
    }
}

// ---------------- batched 256x256 f16 transpose ----------------
__global__ __launch_bounds__(256)
void transpose256h(const half_t* __restrict__ in, half_t* __restrict__ out)
{
    __shared__ __half tb[32][33];
    const int bz = blockIdx.z;
    const half_t* ip = in  + (long)bz * 65536;
    half_t*       op = out + (long)bz * 65536;
    int x0 = blockIdx.x * 32, y0 = blockIdx.y * 32;
    int tx = threadIdx.x, ty = threadIdx.y;
    #pragma unroll
    for (int r = 0; r < 4; r++)
        tb[ty + 8 * r][tx] = ip[(long)(y0 + ty + 8 * r) * 256 + x0 + tx];
    __syncthreads();
    #pragma unroll
    for (int r = 0; r < 4; r++)
        op[(long)(x0 + ty + 8 * r) * 256 + y0 + tx] = tb[tx][ty + 8 * r];
}

// ---------------- emb = max over sequence (coalesced) ----------------
__global__ __launch_bounds__(256)
void emb_max(const float* __restrict__ outp, float* __restrict__ emb)
{
    int b = blockIdx.x;
    for (int n = threadIdx.x; n < 512; n += 256) {
        const float* p = outp + (long)b * 131072 + n;
        float mx = -3.4e38f;
        for (int t = 0; t < 256; t++) mx = fmaxf(mx, p[(long)t * 512]);
        emb[b * 512 + n] = mx;
    }
}

__global__ void diag_ws(float* out, int n, float v)
{
    int i = blockIdx.x * 256 + threadIdx.x;
    if (i < n) out[i] = v;
}

// ======================= host launch =======================
extern "C" void kernel_launch(void* const* d_in, const int* in_sizes, int n_in,
                              void* d_out, int out_size, void* d_ws, size_t ws_size,
                              hipStream_t stream)
{
    const float* x     = (const float*)d_in[0];
    const float* mask  = (const float*)d_in[1];
    const float* wihf  = (const float*)d_in[2];
    const float* whhf  = (const float*)d_in[3];
    const float* bf    = (const float*)d_in[4];
    const float* wihb  = (const float*)d_in[5];
    const float* whhb  = (const float*)d_in[6];
    const float* bb    = (const float*)d_in[7];
    const float* wtp   = (const float*)d_in[8];
    const float* btp   = (const float*)d_in[9];
    const float* wtc   = (const float*)d_in[10];
    const float* btc   = (const float*)d_in[11];
    const float* wa    = (const float*)d_in[12];
    const float* wroot = (const float*)d_in[13];
    const float* remb  = (const float*)d_in[14];
    const float* wr    = (const float*)d_in[15];
    const float* br    = (const float*)d_in[16];

    if (ws_size < 134217728ULL) {
        float enc = 100.0f + (float)((double)ws_size * 1e-9);
        diag_ws<<<dim3((out_size + 255) / 256), 256, 0, stream>>>((float*)d_out, out_size, enc);
        return;
    }

    char* ws = (char*)d_ws;
    half_t* G     = (half_t*)(ws + 0);              // 100,663,296 B per-chunk gates
    half_t* vs    = (half_t*)(ws + 100663296);      // 33,554,432 B
    half_t* tp    = (half_t*)(ws + 0 * SEG);        // post-scan overlays of G region
    half_t* tc    = (half_t*)(ws + 1 * SEG);
    half_t* tmp   = (half_t*)(ws + 2 * SEG);
    half_t* fA    = (half_t*)(ws + 3 * SEG);
    half_t* LL    = (half_t*)(ws + 4 * SEG);
    half_t* aT    = (half_t*)(ws + 5 * SEG);
    half_t* cbuf  = (half_t*)(ws + 0 * SEG);
    half_t* pbuf  = (half_t*)(ws + 2 * SEG);
    half_t* wr16  = (half_t*)(ws + 4 * SEG);

    // dead-until-final region of d_out hosts scan state + small weights
    float* ob = (float*)d_out;
    half_t*   Wp16  = (half_t*)(ob + 11000000);   // 983,040 f16
    half_t*   Whh16 = (half_t*)(ob + 11491520);   // 1,179,648 f16
    float*    bp    = ob + 12081344;
    half_t*   wtp16 = (half_t*)(ob + 12084416);
    half_t*   wtc16 = (half_t*)(ob + 12117184);
    half_t*   wa16T = (half_t*)(ob + 12149952);
    float*    fr    = ob + 12182720;
    float*    d0    = ob + 12215488;
    float*    diagv = ob + 12248256;
    float*    Cst   = ob + 12281024;              // 96*256*4 f32 = 393,216 B
    half_t*   Hbuf  = (half_t*)(ob + 12379328);   // [2 p][2 d][128 b][384 hd] f16
    unsigned* flags = (unsigned*)(ob + 12500000); // 96 x 64B flag lines = 6144 B
    half_t*   vst   = (half_t*)(ob + 12648448);   // 32768 x 256 f16

    float* emb  = (float*)d_out;
    float* outp = (float*)d_out + 65536;

    // 0. init state + pack weights
    hipMemsetAsync(Hbuf, 0, 393216, stream);
    hipMemsetAsync(flags, 0, 6144, stream);
    pack_wih<<<dim3(3840), 256, 0, stream>>>(wihf, wihb, bf, bb, Wp16, bp);
    pack_whh<<<dim3(4608), 256, 0, stream>>>(whhf, whhb, Whh16);
    conv16<<<dim3(256), 256, 0, stream>>>(wtp, wtp16, 65536);
    conv16<<<dim3(256), 256, 0, stream>>>(wtc, wtc16, 65536);
    convT16<<<dim3(256), 256, 0, stream>>>(wa, wa16T, 256, 256);

    // 1. chunked: G GEMM + persistent 128-step scan, twice (flags monotonic via gstep)
    for (int c = 0; c < 2; c++) {
        ggemm<<<dim3(12, 128, 2), 256, 0, stream>>>(x, Wp16, bp, G, c);
        lstm_scan<<<dim3(96), 256, 0, stream>>>(G, Whh16, Hbuf, Cst, vs, vst, flags, c);
    }

    // 2. f_r
    frow_kernel<<<dim3(8192), 256, 0, stream>>>(vst, wroot, fr);

    // 3. tp / tc = tanh(vst @ W^T + b)
    mgemm<false><<<dim3(4, 256, 1), 256, 0, stream>>>(
        vst, wtp16, tp, M_, 256, 256, 256, 256, 256, 0, 0, 0, btp, 1, nullptr, nullptr);
    mgemm<false><<<dim3(4, 256, 1), 256, 0, stream>>>(
        vst, wtc16, tc, M_, 256, 256, 256, 256, 256, 0, 0, 0, btc, 1, nullptr, nullptr);

    // 4. tmp = tp @ w_a
    mgemm<false><<<dim3(4, 256, 1), 256, 0, stream>>>(
        tp, wa16T, tmp, M_, 256, 256, 256, 256, 256, 0, 0, 0, nullptr, 0, nullptr, nullptr);

    // 5. f = exp(tmp @ tc^T), diag zeroed (batched)
    mgemm<false><<<dim3(4, 2, 128), 256, 0, stream>>>(
        tmp, tc, fA, 256, 256, 256, 256, 256, 256, 65536, 65536, 65536,
        nullptr, 2, nullptr, nullptr);

    // 6-8. inverse, diag/d0, assemble
    invert_gj<<<dim3(128), 1024, 0, stream>>>(fA, fr, LL);
    diag_d0_k<<<dim3(128), 256, 0, stream>>>(LL, fr, diagv, d0);
    assemble_a<<<dim3(64, 1, 128), 256, 0, stream>>>(fA, LL, diagv);

    // 9. wr -> f16 (LL dead now)
    conv16<<<dim3(3072), 256, 0, stream>>>(wr, wr16, 786432);

    // 10. aT
    transpose256h<<<dim3(8, 8, 128), dim3(32, 8), 0, stream>>>(fA, aT);

    // 11. c = a @ vs
    mgemm<true><<<dim3(8, 2, 128), 256, 0, stream>>>(
        fA, vs, cbuf, 256, 512, 256, 256, 512, 512, 65536, 131072, 131072,
        nullptr, 0, nullptr, nullptr);

    // 12. p = aT @ vs + d0 (x) root_emb
    mgemm<true><<<dim3(8, 2, 128), 256, 0, stream>>>(
        aT, vs, pbuf, 256, 512, 256, 256, 512, 512, 65536, 131072, 131072,
        nullptr, 0, d0, remb);

    // 13. out = tanh([vs|p|c] @ wr^T + br) * mask
    mgemm_final<<<dim3(8, 256, 1), 256, 0, stream>>>(vs, pbuf, cbuf, wr16, outp, br, mask);

    // 14. emb
    emb_max<<<dim3(128), 256, 0, stream>>>(outp, emb);
}